// Round 6
// baseline (817.391 us; speedup 1.0000x reference)
//
#include <hip/hip_runtime.h>
#include <hip/hip_bf16.h>
#include <math.h>

#define N_PANO 50000
#define N_FP   10000
#define HID    128
#define OUT_C  64
#define E_PP   800000
#define E_PF   50000
#define NBKT   196   // cdiv(N_PANO, 256) coarse buckets for the pp scatter

typedef unsigned short ushort_t;
typedef unsigned int uint_t;
typedef __attribute__((ext_vector_type(8))) short short8;
typedef __attribute__((ext_vector_type(4))) float f32x4;

static inline int cdiv(int a, int b) { return (a + b - 1) / b; }

__device__ inline ushort_t f2bf(float x) {
    __hip_bfloat16 h = __float2bfloat16(x);   // RNE
    return *reinterpret_cast<ushort_t*>(&h);
}
__device__ inline float bfu2f(ushort_t u) {
    return __uint_as_float(((uint_t)u) << 16);
}
__device__ inline uint_t pack2bf(float a, float b) {
    return (uint_t)f2bf(a) | ((uint_t)f2bf(b) << 16);
}
__device__ inline f32x4 mfma16(short8 a, short8 b, f32x4 c) {
    return __builtin_amdgcn_mfma_f32_16x16x32_bf16(a, b, c, 0, 0, 0);
}

// ---------------- CSR build ----------------
__global__ __launch_bounds__(256) void zero_i32(int* p, int n) {
    int i = blockIdx.x * 256 + threadIdx.x;
    if (i < n) p[i] = 0;
}

__global__ __launch_bounds__(256) void count_k(const int* __restrict__ dst, int E, int* __restrict__ cnt) {
    int i = blockIdx.x * 256 + threadIdx.x;
    if (i < E) atomicAdd(&cnt[dst[i]], 1);
}

__global__ __launch_bounds__(1024) void scan_local(const int* __restrict__ cnt, int* __restrict__ ptr,
                                                   int* __restrict__ bsum, int n) {
    __shared__ int wsum[16];
    int tid = threadIdx.x, lane = tid & 63, wid = tid >> 6;
    int i = blockIdx.x * 1024 + tid;
    int v = (i < n) ? cnt[i] : 0;
    int incl = v;
    #pragma unroll
    for (int off = 1; off < 64; off <<= 1) {
        int t = __shfl_up(incl, off, 64);
        if (lane >= off) incl += t;
    }
    if (lane == 63) wsum[wid] = incl;
    __syncthreads();
    if (tid == 0) {
        int run = 0;
        #pragma unroll
        for (int w = 0; w < 16; ++w) { int t = wsum[w]; wsum[w] = run; run += t; }
        bsum[blockIdx.x] = run;
    }
    __syncthreads();
    int excl = wsum[wid] + incl - v;
    if (i < n) ptr[i] = excl;
}

__global__ __launch_bounds__(64) void scan_bsum(int* __restrict__ bsum, int nb, int* __restrict__ total_out) {
    int lane = threadIdx.x;
    int v = (lane < nb) ? bsum[lane] : 0;
    int incl = v;
    #pragma unroll
    for (int off = 1; off < 64; off <<= 1) {
        int t = __shfl_up(incl, off, 64);
        if (lane >= off) incl += t;
    }
    if (lane < nb) bsum[lane] = incl - v;
    if (lane == 63) *total_out = incl;
}

__global__ __launch_bounds__(1024) void scan_add(int* __restrict__ ptr, int* __restrict__ cur,
                                                 const int* __restrict__ bsum, int n) {
    int i = blockIdx.x * 1024 + threadIdx.x;
    if (i < n) {
        int v = ptr[i] + bsum[blockIdx.x];
        ptr[i] = v;
        cur[i] = v;
    }
}

// simple scatter (used for the small pf edge set only)
__global__ __launch_bounds__(256) void scatter_k(const int* __restrict__ src, const int* __restrict__ dst,
                                                 int E, int* __restrict__ cur, int* __restrict__ col) {
    int i = blockIdx.x * 256 + threadIdx.x;
    if (i < E) {
        int p = atomicAdd(&cur[dst[i]], 1);
        col[p] = src[i];
    }
}

// ---- bucketed scatter for pp: coarse (256-dst buckets) then fine, both L2-local ----
__global__ __launch_bounds__(256) void bucket_init(const int* __restrict__ ptr, int* __restrict__ bcur, int n) {
    int b = blockIdx.x * 256 + threadIdx.x;
    if (b < NBKT) bcur[b] = ptr[b << 8];
}

__global__ __launch_bounds__(256) void bucket_scatter(const int* __restrict__ src, const int* __restrict__ dst,
                                                      int E, int* __restrict__ bcur, int2* __restrict__ tmp) {
    int i = blockIdx.x * 256 + threadIdx.x;
    if (i < E) {
        int d = dst[i];
        int p = atomicAdd(&bcur[d >> 8], 1);
        tmp[p] = make_int2(src[i], d);   // 8B write into the bucket's ~32KB hot window
    }
}

__global__ __launch_bounds__(256) void fine_scatter(const int2* __restrict__ tmp, int E,
                                                    int* __restrict__ cur, int* __restrict__ col) {
    int i = blockIdx.x * 256 + threadIdx.x;
    if (i < E) {
        int2 e = tmp[i];
        int p = atomicAdd(&cur[e.y], 1);
        col[p] = e.x;                    // p lies in the same bucket window as i
    }
}

// ---------------- wed[i] = sum_j W[i][j]*a[j] for all three layers, one launch ----------------
__global__ __launch_bounds__(64) void wed_all(const float* __restrict__ Wd0, const float* __restrict__ ad0,
                                              const float* __restrict__ Wd1, const float* __restrict__ ad1,
                                              const float* __restrict__ Wtd, const float* __restrict__ atd,
                                              float* __restrict__ o0, float* __restrict__ o1,
                                              float* __restrict__ ot) {
    int bid = blockIdx.x, lane = threadIdx.x;
    const float* W; const float* a; float* o; int r, C;
    if (bid < 128)      { W = Wd0; a = ad0; o = o0; r = bid;       C = 128; }
    else if (bid < 256) { W = Wd1; a = ad1; o = o1; r = bid - 128; C = 128; }
    else                { W = Wtd; a = atd; o = ot; r = bid - 256; C = 64;  }
    float s = 0.f;
    for (int j = lane; j < C; j += 64) s += W[r * C + j] * a[j];
    #pragma unroll
    for (int off = 32; off; off >>= 1) s += __shfl_down(s, off, 64);
    if (lane == 0) o[r] = s;
}

// ---------------- weight -> bf16 hi/lo split, permuted to MFMA B-fragment order ----
__global__ __launch_bounds__(256) void wconv(const float* __restrict__ Ws0, const float* __restrict__ Lw0,
                                             const float* __restrict__ Ws1, const float* __restrict__ Lw1,
                                             const float* __restrict__ Wts,
                                             ushort_t* s0h, ushort_t* s0l, ushort_t* l0h, ushort_t* l0l,
                                             ushort_t* s1h, ushort_t* s1l, ushort_t* l1h, ushort_t* l1l,
                                             ushort_t* tsh, ushort_t* tsl) {
    int i = blockIdx.x * 256 + threadIdx.x;
    const float* W; ushort_t* oh; ushort_t* ol;
    int d, NIc, Cc;
    if (i < 65536) {
        int m = i >> 14; d = i & 16383;
        W = (m == 0) ? Ws0 : (m == 1) ? Lw0 : (m == 2) ? Ws1 : Lw1;
        oh = (m == 0) ? s0h : (m == 1) ? l0h : (m == 2) ? s1h : l1h;
        ol = (m == 0) ? s0l : (m == 1) ? l0l : (m == 2) ? s1l : l1l;
        NIc = 8; Cc = 128;
    } else if (i < 73728) {
        d = i - 65536; W = Wts; oh = tsh; ol = tsl;
        NIc = 4; Cc = 64;
    } else return;
    int j = d & 7, l = (d >> 3) & 63;
    int kcl = (d >> 9) & 1;
    int ni = (d >> 10) & (NIc - 1);
    int p = d >> (10 + (NIc == 8 ? 3 : 2));
    int kc = p * 2 + kcl;
    int n = ni * 16 + (l & 15);
    int k = kc * 32 + (l >> 4) * 8 + j;
    float v = W[k * Cc + n];
    ushort_t hi = f2bf(v);
    ushort_t lo = f2bf(v - bfu2f(hi));
    oh[d] = hi;
    ol[d] = lo;
}

// ---------------- MFMA GEMM with LDS-staged fragment-order weights ----------------
template <int CN, bool DUAL, bool FP32IN>
__global__ __launch_bounds__(256, 2) void gemm_mfma(const float* __restrict__ Xf,
                                                 const ushort_t* __restrict__ Xh, const ushort_t* __restrict__ Xl,
                                                 const ushort_t* __restrict__ W1h, const ushort_t* __restrict__ W1l,
                                                 const ushort_t* __restrict__ W2h, const ushort_t* __restrict__ W2l,
                                                 ushort_t* __restrict__ Y1, float* __restrict__ Y2,
                                                 const float* __restrict__ avec, float* __restrict__ evec,
                                                 const float* __restrict__ wed, float* __restrict__ edv,
                                                 int N) {
    constexpr int NI = CN / 16;
    constexpr int NMAT = DUAL ? 4 : 2;
    constexpr int SLAB = NI * 1024;          // ushorts per matrix per phase
    __shared__ ushort_t Bsh[NMAT * SLAB];    // 64 KB dual / 16 KB single
    const int tid = threadIdx.x;
    const int w = tid >> 6, l = tid & 63;
    const int col = l & 15, q = l >> 4;
    const int row0 = blockIdx.x * 128 + w * 32;
    f32x4 acc1[2][NI];
    f32x4 acc2[2][DUAL ? NI : 1];
    #pragma unroll
    for (int m = 0; m < 2; ++m)
        #pragma unroll
        for (int ni = 0; ni < NI; ++ni)
            #pragma unroll
            for (int r = 0; r < 4; ++r) acc1[m][ni][r] = 0.f;
    if (DUAL) {
        #pragma unroll
        for (int m = 0; m < 2; ++m)
            #pragma unroll
            for (int ni = 0; ni < NI; ++ni)
                #pragma unroll
                for (int r = 0; r < 4; ++r) acc2[m][ni][r] = 0.f;
    }
    float ped[2] = {0.f, 0.f};

    const ushort_t* Wp[NMAT];
    Wp[0] = W1h; Wp[1] = W1l;
    if (DUAL) { Wp[2] = W2h; Wp[3] = W2l; }

    #pragma unroll
    for (int p = 0; p < 2; ++p) {
        if (p) __syncthreads();
        #pragma unroll
        for (int m = 0; m < NMAT; ++m) {
            const uint4* src = (const uint4*)Wp[m] + p * (SLAB / 8);
            uint4* dst = (uint4*)&Bsh[m * SLAB];
            #pragma unroll
            for (int f = tid; f < SLAB / 8; f += 256) dst[f] = src[f];
        }
        __syncthreads();
        #pragma unroll
        for (int kcl = 0; kcl < 2; ++kcl) {
            const int kc = p * 2 + kcl;
            const int k0 = kc * 32 + q * 8;
            short8 Ah[2], Al[2];
            #pragma unroll
            for (int m = 0; m < 2; ++m) {
                const int arow = row0 + m * 16 + col;
                if (FP32IN) {
                    float xv[8];
                    if (arow < N) {
                        float4 a0 = *(const float4*)&Xf[(size_t)arow * 128 + k0];
                        float4 a1 = *(const float4*)&Xf[(size_t)arow * 128 + k0 + 4];
                        xv[0] = a0.x; xv[1] = a0.y; xv[2] = a0.z; xv[3] = a0.w;
                        xv[4] = a1.x; xv[5] = a1.y; xv[6] = a1.z; xv[7] = a1.w;
                    } else {
                        #pragma unroll
                        for (int j = 0; j < 8; ++j) xv[j] = 0.f;
                    }
                    #pragma unroll
                    for (int j = 0; j < 8; ++j) {
                        ushort_t hi = f2bf(xv[j]);
                        ushort_t lo = f2bf(xv[j] - bfu2f(hi));
                        Ah[m][j] = (short)hi;
                        Al[m][j] = (short)lo;
                    }
                    if (wed) {
                        float4 w0 = *(const float4*)&wed[k0];
                        float4 w1 = *(const float4*)&wed[k0 + 4];
                        ped[m] += xv[0] * w0.x + xv[1] * w0.y + xv[2] * w0.z + xv[3] * w0.w
                                + xv[4] * w1.x + xv[5] * w1.y + xv[6] * w1.z + xv[7] * w1.w;
                    }
                } else {
                    if (arow < N) {
                        Ah[m] = *(const short8*)&Xh[(size_t)arow * 128 + k0];
                        Al[m] = *(const short8*)&Xl[(size_t)arow * 128 + k0];
                    } else {
                        #pragma unroll
                        for (int j = 0; j < 8; ++j) { Ah[m][j] = 0; Al[m][j] = 0; }
                    }
                    if (wed) {
                        float4 w0 = *(const float4*)&wed[k0];
                        float4 w1 = *(const float4*)&wed[k0 + 4];
                        float wv[8] = {w0.x, w0.y, w0.z, w0.w, w1.x, w1.y, w1.z, w1.w};
                        #pragma unroll
                        for (int j = 0; j < 8; ++j)
                            ped[m] += (bfu2f((ushort_t)Ah[m][j]) + bfu2f((ushort_t)Al[m][j])) * wv[j];
                    }
                }
            }
            #pragma unroll
            for (int ni = 0; ni < NI; ++ni) {
                const int lb = ((ni * 2 + kcl) * 64 + l) * 8;
                short8 B1h = *(const short8*)&Bsh[0 * SLAB + lb];
                short8 B1l = *(const short8*)&Bsh[1 * SLAB + lb];
                #pragma unroll
                for (int m = 0; m < 2; ++m) {
                    acc1[m][ni] = mfma16(Ah[m], B1h, acc1[m][ni]);
                    acc1[m][ni] = mfma16(Al[m], B1h, acc1[m][ni]);
                    acc1[m][ni] = mfma16(Ah[m], B1l, acc1[m][ni]);
                }
                if (DUAL) {
                    short8 B2h = *(const short8*)&Bsh[2 * SLAB + lb];
                    short8 B2l = *(const short8*)&Bsh[3 * SLAB + lb];
                    #pragma unroll
                    for (int m = 0; m < 2; ++m) {
                        acc2[m][ni] = mfma16(Ah[m], B2h, acc2[m][ni]);
                        acc2[m][ni] = mfma16(Al[m], B2h, acc2[m][ni]);
                        acc2[m][ni] = mfma16(Ah[m], B2l, acc2[m][ni]);
                    }
                }
            }
        }
    }

    #pragma unroll
    for (int m = 0; m < 2; ++m) {
        #pragma unroll
        for (int ni = 0; ni < NI; ++ni) {
            #pragma unroll
            for (int r = 0; r < 4; ++r) {
                int mrow = row0 + m * 16 + q * 4 + r;
                if (mrow < N) {
                    Y1[(size_t)mrow * CN + ni * 16 + col] = f2bf(acc1[m][ni][r]);
                    if (DUAL) Y2[(size_t)mrow * CN + ni * 16 + col] = acc2[m][ni][r];
                }
            }
        }
    }
    float av[NI];
    #pragma unroll
    for (int ni = 0; ni < NI; ++ni) av[ni] = avec[ni * 16 + col];
    #pragma unroll
    for (int m = 0; m < 2; ++m) {
        #pragma unroll
        for (int r = 0; r < 4; ++r) {
            float pp = 0.f;
            #pragma unroll
            for (int ni = 0; ni < NI; ++ni) pp += acc1[m][ni][r] * av[ni];
            pp += __shfl_xor(pp, 1, 64);
            pp += __shfl_xor(pp, 2, 64);
            pp += __shfl_xor(pp, 4, 64);
            pp += __shfl_xor(pp, 8, 64);
            int mrow = row0 + m * 16 + q * 4 + r;
            if (col == 0 && mrow < N) evec[mrow] = pp;
        }
    }
    if (wed) {
        #pragma unroll
        for (int m = 0; m < 2; ++m) {
            ped[m] += __shfl_xor(ped[m], 16, 64);
            ped[m] += __shfl_xor(ped[m], 32, 64);
            int arow = row0 + m * 16 + col;
            if (q == 0 && arow < N) edv[arow] = ped[m];
        }
    }
}

// ---------------- matvec (x_fp @ wedt), one wave per row ----------------
template <int K>
__global__ __launch_bounds__(256) void matvec_k(const float* __restrict__ X, const float* __restrict__ v,
                                                float* __restrict__ y, int N) {
    int lane = threadIdx.x & 63, wid = threadIdx.x >> 6;
    int node = blockIdx.x * 4 + wid;
    if (node >= N) return;
    float s = X[node * K + lane] * v[lane];
    if (K > 64) s += X[node * K + 64 + lane] * v[64 + lane];
    #pragma unroll
    for (int off = 32; off; off >>= 1) s += __shfl_down(s, off, 64);
    if (lane == 0) y[node] = s;
}

// ---------------- GAT aggregate (pano, C=128, bf16 hs gather) -> h as bf16 hi/lo ----------------
__global__ __launch_bounds__(256) void agg_pano4(const int* __restrict__ ptr, const int* __restrict__ col,
                                                 const float* __restrict__ es, const float* __restrict__ ed,
                                                 const ushort_t* __restrict__ hsb, const float* __restrict__ lin,
                                                 const float* __restrict__ b, const float* __restrict__ Lb,
                                                 uint_t* __restrict__ hh, uint_t* __restrict__ hl, int N) {
    int lane = threadIdx.x & 63, wid = threadIdx.x >> 6;
    int node = blockIdx.x * 4 + wid;
    if (node >= N) return;
    int beg = ptr[node], end = ptr[node + 1];
    float edn = ed[node];
    int ch = lane * 2;
    float ax = 0.f, ay = 0.f, den = 0.f;
    int i = beg;
    for (; i + 8 <= end; i += 8) {
        int s[8];
        #pragma unroll
        for (int u = 0; u < 8; ++u) s[u] = col[i + u];
        float w[8];
        #pragma unroll
        for (int u = 0; u < 8; ++u) {
            float e = es[s[u]] + edn;
            e = fmaxf(e, 0.2f * e);
            w[u] = __expf(e);
        }
        uint_t hv[8];
        #pragma unroll
        for (int u = 0; u < 8; ++u) hv[u] = *(const uint_t*)&hsb[(size_t)s[u] * 128 + ch];
        #pragma unroll
        for (int u = 0; u < 8; ++u) {
            float hx = __uint_as_float((hv[u] & 0xffffu) << 16);
            float hy = __uint_as_float(hv[u] & 0xffff0000u);
            den += w[u];
            ax += w[u] * hx;
            ay += w[u] * hy;
        }
    }
    for (; i < end; ++i) {
        int s = col[i];
        float e = es[s] + edn;
        e = fmaxf(e, 0.2f * e);
        float wgt = __expf(e);
        uint_t hv = *(const uint_t*)&hsb[(size_t)s * 128 + ch];
        float hx = __uint_as_float((hv & 0xffffu) << 16);
        float hy = __uint_as_float(hv & 0xffff0000u);
        den += wgt;
        ax += wgt * hx;
        ay += wgt * hy;
    }
    float inv = (end > beg) ? (1.f / den) : 0.f;
    float2 l2 = *(const float2*)&lin[(size_t)node * 128 + ch];
    float2 bb = *(const float2*)&b[ch];
    float2 lb = *(const float2*)&Lb[ch];
    float ox = fmaxf(ax * inv + bb.x + l2.x + lb.x, 0.f);
    float oy = fmaxf(ay * inv + bb.y + l2.y + lb.y, 0.f);
    ushort_t hx = f2bf(ox), hy = f2bf(oy);
    hh[(size_t)node * 64 + lane] = (uint_t)hx | ((uint_t)hy << 16);
    hl[(size_t)node * 64 + lane] = pack2bf(ox - bfu2f(hx), oy - bfu2f(hy));
}

// ---------------- translate aggregate (C=64, bf16 hs gather) ----------------
__global__ __launch_bounds__(256) void agg_fp3(const int* __restrict__ ptr, const int* __restrict__ col,
                                               const float* __restrict__ es, const float* __restrict__ ed,
                                               const ushort_t* __restrict__ hsb, const float* __restrict__ bt,
                                               float* __restrict__ out, int N) {
    int lane = threadIdx.x & 63, wid = threadIdx.x >> 6;
    int node = blockIdx.x * 4 + wid;
    if (node >= N) return;
    int beg = ptr[node], end = ptr[node + 1];
    float edn = ed[node];
    float acc = 0.f, den = 0.f;
    int i = beg;
    for (; i + 8 <= end; i += 8) {
        int s[8];
        #pragma unroll
        for (int u = 0; u < 8; ++u) s[u] = col[i + u];
        float w[8];
        #pragma unroll
        for (int u = 0; u < 8; ++u) {
            float e = es[s[u]] + edn;
            e = fmaxf(e, 0.2f * e);
            w[u] = __expf(e);
        }
        ushort_t hv[8];
        #pragma unroll
        for (int u = 0; u < 8; ++u) hv[u] = hsb[(size_t)s[u] * 64 + lane];
        #pragma unroll
        for (int u = 0; u < 8; ++u) {
            den += w[u];
            acc += w[u] * bfu2f(hv[u]);
        }
    }
    for (; i < end; ++i) {
        int s = col[i];
        float e = es[s] + edn;
        e = fmaxf(e, 0.2f * e);
        float wgt = __expf(e);
        den += wgt;
        acc += wgt * bfu2f(hsb[(size_t)s * 64 + lane]);
    }
    float inv = (end > beg) ? (1.f / den) : 0.f;
    out[(size_t)node * 64 + lane] = acc * inv + bt[lane];
}

extern "C" void kernel_launch(void* const* d_in, const int* in_sizes, int n_in,
                              void* d_out, int out_size, void* d_ws, size_t ws_size,
                              hipStream_t stream) {
    const float* x_pano = (const float*)d_in[0];
    const float* x_fp   = (const float*)d_in[1];
    const float* Ws0 = (const float*)d_in[2];
    const float* Wd0 = (const float*)d_in[3];
    const float* as0 = (const float*)d_in[4];
    const float* ad0 = (const float*)d_in[5];
    const float* b0  = (const float*)d_in[6];
    const float* Lw0 = (const float*)d_in[7];
    const float* Lb0 = (const float*)d_in[8];
    const float* Ws1 = (const float*)d_in[9];
    const float* Wd1 = (const float*)d_in[10];
    const float* as1 = (const float*)d_in[11];
    const float* ad1 = (const float*)d_in[12];
    const float* b1  = (const float*)d_in[13];
    const float* Lw1 = (const float*)d_in[14];
    const float* Lb1 = (const float*)d_in[15];
    const float* Wts = (const float*)d_in[16];
    const float* Wtd = (const float*)d_in[17];
    const float* ats = (const float*)d_in[18];
    const float* atd = (const float*)d_in[19];
    const float* bt  = (const float*)d_in[20];
    const int* edge_pp = (const int*)d_in[21];
    const int* pf_src  = (const int*)d_in[22];
    const int* pf_dst  = (const int*)d_in[23];
    float* out = (float*)d_out;

    char* wsp = (char*)d_ws;
    size_t off = 0;
    auto alloc = [&](size_t bytes) -> char* {
        char* p = wsp + off;
        off += (bytes + 255) & ~(size_t)255;
        return p;
    };
    ushort_t* hsb  = (ushort_t*)alloc(sizeof(ushort_t) * N_PANO * HID);   // 12.8 MB
    float* lin     = (float*)alloc(sizeof(float) * N_PANO * HID);         // 25.6 MB
    uint_t* hh     = (uint_t*)alloc(sizeof(uint_t) * N_PANO * 64);        // 12.8 MB
    uint_t* hl     = (uint_t*)alloc(sizeof(uint_t) * N_PANO * 64);        // 12.8 MB
    ushort_t* hstb = (ushort_t*)alloc(sizeof(ushort_t) * N_PANO * OUT_C); // 6.4 MB
    int2* tmp_pp   = (int2*)alloc(sizeof(int2) * E_PP);                   // 6.4 MB
    float* es   = (float*)alloc(sizeof(float) * N_PANO);
    float* ed   = (float*)alloc(sizeof(float) * N_PANO);
    float* edt  = (float*)alloc(sizeof(float) * N_FP);
    float* wed0 = (float*)alloc(sizeof(float) * HID);
    float* wed1 = (float*)alloc(sizeof(float) * HID);
    float* wedt = (float*)alloc(sizeof(float) * OUT_C);
    ushort_t* s0h = (ushort_t*)alloc(sizeof(ushort_t) * 128 * 128);
    ushort_t* s0l = (ushort_t*)alloc(sizeof(ushort_t) * 128 * 128);
    ushort_t* l0h = (ushort_t*)alloc(sizeof(ushort_t) * 128 * 128);
    ushort_t* l0l = (ushort_t*)alloc(sizeof(ushort_t) * 128 * 128);
    ushort_t* s1h = (ushort_t*)alloc(sizeof(ushort_t) * 128 * 128);
    ushort_t* s1l = (ushort_t*)alloc(sizeof(ushort_t) * 128 * 128);
    ushort_t* l1h = (ushort_t*)alloc(sizeof(ushort_t) * 128 * 128);
    ushort_t* l1l = (ushort_t*)alloc(sizeof(ushort_t) * 128 * 128);
    ushort_t* tsh = (ushort_t*)alloc(sizeof(ushort_t) * 64 * 128);
    ushort_t* tsl = (ushort_t*)alloc(sizeof(ushort_t) * 64 * 128);
    int* cnt    = (int*)alloc(sizeof(int) * N_PANO);
    int* cur    = (int*)alloc(sizeof(int) * N_PANO);
    int* bsum   = (int*)alloc(sizeof(int) * 64);
    int* bcur   = (int*)alloc(sizeof(int) * 256);
    int* ptr_pp = (int*)alloc(sizeof(int) * (N_PANO + 1));
    int* col_pp = (int*)alloc(sizeof(int) * E_PP);
    int* ptr_pf = (int*)alloc(sizeof(int) * (N_FP + 1));
    int* col_pf = (int*)alloc(sizeof(int) * E_PF);

    const int* pp_src = edge_pp;
    const int* pp_dst = edge_pp + E_PP;

    // ---- CSR build (pp): count -> scan -> bucketed two-phase scatter ----
    {
        int nb = cdiv(N_PANO, 1024);
        zero_i32<<<cdiv(N_PANO, 256), 256, 0, stream>>>(cnt, N_PANO);
        count_k<<<cdiv(E_PP, 256), 256, 0, stream>>>(pp_dst, E_PP, cnt);
        scan_local<<<nb, 1024, 0, stream>>>(cnt, ptr_pp, bsum, N_PANO);
        scan_bsum<<<1, 64, 0, stream>>>(bsum, nb, &ptr_pp[N_PANO]);
        scan_add<<<nb, 1024, 0, stream>>>(ptr_pp, cur, bsum, N_PANO);
        bucket_init<<<1, 256, 0, stream>>>(ptr_pp, bcur, N_PANO);
        bucket_scatter<<<cdiv(E_PP, 256), 256, 0, stream>>>(pp_src, pp_dst, E_PP, bcur, tmp_pp);
        fine_scatter<<<cdiv(E_PP, 256), 256, 0, stream>>>(tmp_pp, E_PP, cur, col_pp);
    }
    // ---- CSR build (pf): small, simple scatter ----
    {
        int nb = cdiv(N_FP, 1024);
        zero_i32<<<cdiv(N_FP, 256), 256, 0, stream>>>(cnt, N_FP);
        count_k<<<cdiv(E_PF, 256), 256, 0, stream>>>(pf_dst, E_PF, cnt);
        scan_local<<<nb, 1024, 0, stream>>>(cnt, ptr_pf, bsum, N_FP);
        scan_bsum<<<1, 64, 0, stream>>>(bsum, nb, &ptr_pf[N_FP]);
        scan_add<<<nb, 1024, 0, stream>>>(ptr_pf, cur, bsum, N_FP);
        scatter_k<<<cdiv(E_PF, 256), 256, 0, stream>>>(pf_src, pf_dst, E_PF, cur, col_pf);
    }
    // ---- fold Wd @ a_d ; convert weights to fragment order ----
    wed_all<<<320, 64, 0, stream>>>(Wd0, ad0, Wd1, ad1, Wtd, atd, wed0, wed1, wedt);
    wconv<<<288, 256, 0, stream>>>(Ws0, Lw0, Ws1, Lw1, Wts,
                                   s0h, s0l, l0h, l0l, s1h, s1l, l1h, l1l, tsh, tsl);

    const int gemm_grid = cdiv(N_PANO, 128);

    // ---- layer 0 (fp32 input) ----
    gemm_mfma<128, true, true><<<gemm_grid, 256, 0, stream>>>(
        x_pano, nullptr, nullptr, s0h, s0l, l0h, l0l,
        hsb, lin, as0, es, wed0, ed, N_PANO);
    agg_pano4<<<cdiv(N_PANO, 4), 256, 0, stream>>>(ptr_pp, col_pp, es, ed, hsb, lin, b0, Lb0, hh, hl, N_PANO);

    // ---- layer 1 (bf16 hi/lo input) ----
    gemm_mfma<128, true, false><<<gemm_grid, 256, 0, stream>>>(
        nullptr, (const ushort_t*)hh, (const ushort_t*)hl, s1h, s1l, l1h, l1l,
        hsb, lin, as1, es, wed1, ed, N_PANO);
    agg_pano4<<<cdiv(N_PANO, 4), 256, 0, stream>>>(ptr_pp, col_pp, es, ed, hsb, lin, b1, Lb1, hh, hl, N_PANO);

    // ---- translate (pano -> footprint) ----
    gemm_mfma<64, false, false><<<gemm_grid, 256, 0, stream>>>(
        nullptr, (const ushort_t*)hh, (const ushort_t*)hl, tsh, tsl, nullptr, nullptr,
        hstb, nullptr, ats, es, nullptr, nullptr, N_PANO);
    matvec_k<64><<<cdiv(N_FP, 4), 256, 0, stream>>>(x_fp, wedt, edt, N_FP);
    agg_fp3<<<cdiv(N_FP, 4), 256, 0, stream>>>(ptr_pf, col_pf, es, edt, hstb, bt, out, N_FP);
}

// Round 7
// 381.901 us; speedup vs baseline: 2.1403x; 2.1403x over previous
//
#include <hip/hip_runtime.h>
#include <hip/hip_bf16.h>
#include <math.h>

#define N_PANO 50000
#define N_FP   10000
#define HID    128
#define OUT_C  64
#define E_PP   800000
#define E_PF   50000
#define NBKT   196   // cdiv(N_PANO, 256) coarse buckets for the pp scatter
#define EPB    4096  // edges per block in the aggregated coarse scatter

typedef unsigned short ushort_t;
typedef unsigned int uint_t;
typedef __attribute__((ext_vector_type(8))) short short8;
typedef __attribute__((ext_vector_type(4))) float f32x4;

static inline int cdiv(int a, int b) { return (a + b - 1) / b; }

__device__ inline ushort_t f2bf(float x) {
    __hip_bfloat16 h = __float2bfloat16(x);   // RNE
    return *reinterpret_cast<ushort_t*>(&h);
}
__device__ inline float bfu2f(ushort_t u) {
    return __uint_as_float(((uint_t)u) << 16);
}
__device__ inline uint_t pack2bf(float a, float b) {
    return (uint_t)f2bf(a) | ((uint_t)f2bf(b) << 16);
}
__device__ inline f32x4 mfma16(short8 a, short8 b, f32x4 c) {
    return __builtin_amdgcn_mfma_f32_16x16x32_bf16(a, b, c, 0, 0, 0);
}

// ---------------- CSR build ----------------
__global__ __launch_bounds__(256) void zero_i32(int* p, int n) {
    int i = blockIdx.x * 256 + threadIdx.x;
    if (i < n) p[i] = 0;
}

__global__ __launch_bounds__(256) void count_k(const int* __restrict__ dst, int E, int* __restrict__ cnt) {
    int i = blockIdx.x * 256 + threadIdx.x;
    if (i < E) atomicAdd(&cnt[dst[i]], 1);
}

__global__ __launch_bounds__(1024) void scan_local(const int* __restrict__ cnt, int* __restrict__ ptr,
                                                   int* __restrict__ bsum, int n) {
    __shared__ int wsum[16];
    int tid = threadIdx.x, lane = tid & 63, wid = tid >> 6;
    int i = blockIdx.x * 1024 + tid;
    int v = (i < n) ? cnt[i] : 0;
    int incl = v;
    #pragma unroll
    for (int off = 1; off < 64; off <<= 1) {
        int t = __shfl_up(incl, off, 64);
        if (lane >= off) incl += t;
    }
    if (lane == 63) wsum[wid] = incl;
    __syncthreads();
    if (tid == 0) {
        int run = 0;
        #pragma unroll
        for (int w = 0; w < 16; ++w) { int t = wsum[w]; wsum[w] = run; run += t; }
        bsum[blockIdx.x] = run;
    }
    __syncthreads();
    int excl = wsum[wid] + incl - v;
    if (i < n) ptr[i] = excl;
}

__global__ __launch_bounds__(64) void scan_bsum(int* __restrict__ bsum, int nb, int* __restrict__ total_out) {
    int lane = threadIdx.x;
    int v = (lane < nb) ? bsum[lane] : 0;
    int incl = v;
    #pragma unroll
    for (int off = 1; off < 64; off <<= 1) {
        int t = __shfl_up(incl, off, 64);
        if (lane >= off) incl += t;
    }
    if (lane < nb) bsum[lane] = incl - v;
    if (lane == 63) *total_out = incl;
}

__global__ __launch_bounds__(1024) void scan_add(int* __restrict__ ptr, int* __restrict__ cur,
                                                 const int* __restrict__ bsum, int n) {
    int i = blockIdx.x * 1024 + threadIdx.x;
    if (i < n) {
        int v = ptr[i] + bsum[blockIdx.x];
        ptr[i] = v;
        cur[i] = v;
    }
}

// simple scatter (used for the small pf edge set only)
__global__ __launch_bounds__(256) void scatter_k(const int* __restrict__ src, const int* __restrict__ dst,
                                                 int E, int* __restrict__ cur, int* __restrict__ col) {
    int i = blockIdx.x * 256 + threadIdx.x;
    if (i < E) {
        int p = atomicAdd(&cur[dst[i]], 1);
        col[p] = src[i];
    }
}

// ---- bucketed scatter for pp ----
// bcur is padded: counter b lives at bcur[b*16] (one per 64-B line) to avoid
// cross-XCD same-line atomic serialization (round-6 lesson: 800k atomics on 13
// lines = 450 us).
__global__ __launch_bounds__(256) void bucket_init(const int* __restrict__ ptr, int* __restrict__ bcur) {
    int b = blockIdx.x * 256 + threadIdx.x;
    if (b < NBKT) bcur[b * 16] = ptr[b << 8];
}

// Block-aggregated coarse scatter: LDS histogram -> one global atomic per
// (block,bucket) -> LDS-cursor placement. 38k global atomics instead of 800k.
__global__ __launch_bounds__(256) void bucket_scatter_agg(const int* __restrict__ src,
                                                          const int* __restrict__ dst, int E,
                                                          int* __restrict__ bcur, int2* __restrict__ tmp) {
    __shared__ int hist[NBKT];
    __shared__ int base[NBKT];
    const int tid = threadIdx.x;
    const int e0 = blockIdx.x * EPB;
    for (int t = tid; t < NBKT; t += 256) hist[t] = 0;
    __syncthreads();
    int d[16];
    #pragma unroll
    for (int u = 0; u < 16; ++u) {
        int e = e0 + u * 256 + tid;
        d[u] = (e < E) ? dst[e] : -1;
        if (d[u] >= 0) atomicAdd(&hist[d[u] >> 8], 1);
    }
    __syncthreads();
    for (int t = tid; t < NBKT; t += 256) {
        int c = hist[t];
        base[t] = (c > 0) ? atomicAdd(&bcur[t * 16], c) : 0;
        hist[t] = 0;
    }
    __syncthreads();
    #pragma unroll
    for (int u = 0; u < 16; ++u) {
        if (d[u] >= 0) {
            int b = d[u] >> 8;
            int p = base[b] + atomicAdd(&hist[b], 1);
            tmp[p] = make_int2(src[e0 + u * 256 + tid], d[u]);
        }
    }
}

__global__ __launch_bounds__(256) void fine_scatter(const int2* __restrict__ tmp, int E,
                                                    int* __restrict__ cur, int* __restrict__ col) {
    int i = blockIdx.x * 256 + threadIdx.x;
    if (i < E) {
        int2 e = tmp[i];
        int p = atomicAdd(&cur[e.y], 1);
        col[p] = e.x;                    // p lies in the same bucket window as i
    }
}

// ---------------- wed[i] = sum_j W[i][j]*a[j] for all three layers, one launch ----------------
__global__ __launch_bounds__(64) void wed_all(const float* __restrict__ Wd0, const float* __restrict__ ad0,
                                              const float* __restrict__ Wd1, const float* __restrict__ ad1,
                                              const float* __restrict__ Wtd, const float* __restrict__ atd,
                                              float* __restrict__ o0, float* __restrict__ o1,
                                              float* __restrict__ ot) {
    int bid = blockIdx.x, lane = threadIdx.x;
    const float* W; const float* a; float* o; int r, C;
    if (bid < 128)      { W = Wd0; a = ad0; o = o0; r = bid;       C = 128; }
    else if (bid < 256) { W = Wd1; a = ad1; o = o1; r = bid - 128; C = 128; }
    else                { W = Wtd; a = atd; o = ot; r = bid - 256; C = 64;  }
    float s = 0.f;
    for (int j = lane; j < C; j += 64) s += W[r * C + j] * a[j];
    #pragma unroll
    for (int off = 32; off; off >>= 1) s += __shfl_down(s, off, 64);
    if (lane == 0) o[r] = s;
}

// ---------------- weight -> bf16 hi/lo split, permuted to MFMA B-fragment order ----
__global__ __launch_bounds__(256) void wconv(const float* __restrict__ Ws0, const float* __restrict__ Lw0,
                                             const float* __restrict__ Ws1, const float* __restrict__ Lw1,
                                             const float* __restrict__ Wts,
                                             ushort_t* s0h, ushort_t* s0l, ushort_t* l0h, ushort_t* l0l,
                                             ushort_t* s1h, ushort_t* s1l, ushort_t* l1h, ushort_t* l1l,
                                             ushort_t* tsh, ushort_t* tsl) {
    int i = blockIdx.x * 256 + threadIdx.x;
    const float* W; ushort_t* oh; ushort_t* ol;
    int d, NIc, Cc;
    if (i < 65536) {
        int m = i >> 14; d = i & 16383;
        W = (m == 0) ? Ws0 : (m == 1) ? Lw0 : (m == 2) ? Ws1 : Lw1;
        oh = (m == 0) ? s0h : (m == 1) ? l0h : (m == 2) ? s1h : l1h;
        ol = (m == 0) ? s0l : (m == 1) ? l0l : (m == 2) ? s1l : l1l;
        NIc = 8; Cc = 128;
    } else if (i < 73728) {
        d = i - 65536; W = Wts; oh = tsh; ol = tsl;
        NIc = 4; Cc = 64;
    } else return;
    int j = d & 7, l = (d >> 3) & 63;
    int kcl = (d >> 9) & 1;
    int ni = (d >> 10) & (NIc - 1);
    int p = d >> (10 + (NIc == 8 ? 3 : 2));
    int kc = p * 2 + kcl;
    int n = ni * 16 + (l & 15);
    int k = kc * 32 + (l >> 4) * 8 + j;
    float v = W[k * Cc + n];
    ushort_t hi = f2bf(v);
    ushort_t lo = f2bf(v - bfu2f(hi));
    oh[d] = hi;
    ol[d] = lo;
}

// ---------------- MFMA GEMM with LDS-staged fragment-order weights ----------------
template <int CN, bool DUAL, bool FP32IN>
__global__ __launch_bounds__(256, 2) void gemm_mfma(const float* __restrict__ Xf,
                                                 const ushort_t* __restrict__ Xh, const ushort_t* __restrict__ Xl,
                                                 const ushort_t* __restrict__ W1h, const ushort_t* __restrict__ W1l,
                                                 const ushort_t* __restrict__ W2h, const ushort_t* __restrict__ W2l,
                                                 ushort_t* __restrict__ Y1, float* __restrict__ Y2,
                                                 const float* __restrict__ avec, float* __restrict__ evec,
                                                 const float* __restrict__ wed, float* __restrict__ edv,
                                                 int N) {
    constexpr int NI = CN / 16;
    constexpr int NMAT = DUAL ? 4 : 2;
    constexpr int SLAB = NI * 1024;          // ushorts per matrix per phase
    __shared__ ushort_t Bsh[NMAT * SLAB];    // 64 KB dual / 16 KB single
    const int tid = threadIdx.x;
    const int w = tid >> 6, l = tid & 63;
    const int col = l & 15, q = l >> 4;
    const int row0 = blockIdx.x * 128 + w * 32;
    f32x4 acc1[2][NI];
    f32x4 acc2[2][DUAL ? NI : 1];
    #pragma unroll
    for (int m = 0; m < 2; ++m)
        #pragma unroll
        for (int ni = 0; ni < NI; ++ni)
            #pragma unroll
            for (int r = 0; r < 4; ++r) acc1[m][ni][r] = 0.f;
    if (DUAL) {
        #pragma unroll
        for (int m = 0; m < 2; ++m)
            #pragma unroll
            for (int ni = 0; ni < NI; ++ni)
                #pragma unroll
                for (int r = 0; r < 4; ++r) acc2[m][ni][r] = 0.f;
    }
    float ped[2] = {0.f, 0.f};

    const ushort_t* Wp[NMAT];
    Wp[0] = W1h; Wp[1] = W1l;
    if (DUAL) { Wp[2] = W2h; Wp[3] = W2l; }

    #pragma unroll
    for (int p = 0; p < 2; ++p) {
        if (p) __syncthreads();
        #pragma unroll
        for (int m = 0; m < NMAT; ++m) {
            const uint4* src = (const uint4*)Wp[m] + p * (SLAB / 8);
            uint4* dst = (uint4*)&Bsh[m * SLAB];
            #pragma unroll
            for (int f = tid; f < SLAB / 8; f += 256) dst[f] = src[f];
        }
        __syncthreads();
        #pragma unroll
        for (int kcl = 0; kcl < 2; ++kcl) {
            const int kc = p * 2 + kcl;
            const int k0 = kc * 32 + q * 8;
            short8 Ah[2], Al[2];
            #pragma unroll
            for (int m = 0; m < 2; ++m) {
                const int arow = row0 + m * 16 + col;
                if (FP32IN) {
                    float xv[8];
                    if (arow < N) {
                        float4 a0 = *(const float4*)&Xf[(size_t)arow * 128 + k0];
                        float4 a1 = *(const float4*)&Xf[(size_t)arow * 128 + k0 + 4];
                        xv[0] = a0.x; xv[1] = a0.y; xv[2] = a0.z; xv[3] = a0.w;
                        xv[4] = a1.x; xv[5] = a1.y; xv[6] = a1.z; xv[7] = a1.w;
                    } else {
                        #pragma unroll
                        for (int j = 0; j < 8; ++j) xv[j] = 0.f;
                    }
                    #pragma unroll
                    for (int j = 0; j < 8; ++j) {
                        ushort_t hi = f2bf(xv[j]);
                        ushort_t lo = f2bf(xv[j] - bfu2f(hi));
                        Ah[m][j] = (short)hi;
                        Al[m][j] = (short)lo;
                    }
                    if (wed) {
                        float4 w0 = *(const float4*)&wed[k0];
                        float4 w1 = *(const float4*)&wed[k0 + 4];
                        ped[m] += xv[0] * w0.x + xv[1] * w0.y + xv[2] * w0.z + xv[3] * w0.w
                                + xv[4] * w1.x + xv[5] * w1.y + xv[6] * w1.z + xv[7] * w1.w;
                    }
                } else {
                    if (arow < N) {
                        Ah[m] = *(const short8*)&Xh[(size_t)arow * 128 + k0];
                        Al[m] = *(const short8*)&Xl[(size_t)arow * 128 + k0];
                    } else {
                        #pragma unroll
                        for (int j = 0; j < 8; ++j) { Ah[m][j] = 0; Al[m][j] = 0; }
                    }
                    if (wed) {
                        float4 w0 = *(const float4*)&wed[k0];
                        float4 w1 = *(const float4*)&wed[k0 + 4];
                        float wv[8] = {w0.x, w0.y, w0.z, w0.w, w1.x, w1.y, w1.z, w1.w};
                        #pragma unroll
                        for (int j = 0; j < 8; ++j)
                            ped[m] += (bfu2f((ushort_t)Ah[m][j]) + bfu2f((ushort_t)Al[m][j])) * wv[j];
                    }
                }
            }
            #pragma unroll
            for (int ni = 0; ni < NI; ++ni) {
                const int lb = ((ni * 2 + kcl) * 64 + l) * 8;
                short8 B1h = *(const short8*)&Bsh[0 * SLAB + lb];
                short8 B1l = *(const short8*)&Bsh[1 * SLAB + lb];
                #pragma unroll
                for (int m = 0; m < 2; ++m) {
                    acc1[m][ni] = mfma16(Ah[m], B1h, acc1[m][ni]);
                    acc1[m][ni] = mfma16(Al[m], B1h, acc1[m][ni]);
                    acc1[m][ni] = mfma16(Ah[m], B1l, acc1[m][ni]);
                }
                if (DUAL) {
                    short8 B2h = *(const short8*)&Bsh[2 * SLAB + lb];
                    short8 B2l = *(const short8*)&Bsh[3 * SLAB + lb];
                    #pragma unroll
                    for (int m = 0; m < 2; ++m) {
                        acc2[m][ni] = mfma16(Ah[m], B2h, acc2[m][ni]);
                        acc2[m][ni] = mfma16(Al[m], B2h, acc2[m][ni]);
                        acc2[m][ni] = mfma16(Ah[m], B2l, acc2[m][ni]);
                    }
                }
            }
        }
    }

    #pragma unroll
    for (int m = 0; m < 2; ++m) {
        #pragma unroll
        for (int ni = 0; ni < NI; ++ni) {
            #pragma unroll
            for (int r = 0; r < 4; ++r) {
                int mrow = row0 + m * 16 + q * 4 + r;
                if (mrow < N) {
                    Y1[(size_t)mrow * CN + ni * 16 + col] = f2bf(acc1[m][ni][r]);
                    if (DUAL) Y2[(size_t)mrow * CN + ni * 16 + col] = acc2[m][ni][r];
                }
            }
        }
    }
    float av[NI];
    #pragma unroll
    for (int ni = 0; ni < NI; ++ni) av[ni] = avec[ni * 16 + col];
    #pragma unroll
    for (int m = 0; m < 2; ++m) {
        #pragma unroll
        for (int r = 0; r < 4; ++r) {
            float pp = 0.f;
            #pragma unroll
            for (int ni = 0; ni < NI; ++ni) pp += acc1[m][ni][r] * av[ni];
            pp += __shfl_xor(pp, 1, 64);
            pp += __shfl_xor(pp, 2, 64);
            pp += __shfl_xor(pp, 4, 64);
            pp += __shfl_xor(pp, 8, 64);
            int mrow = row0 + m * 16 + q * 4 + r;
            if (col == 0 && mrow < N) evec[mrow] = pp;
        }
    }
    if (wed) {
        #pragma unroll
        for (int m = 0; m < 2; ++m) {
            ped[m] += __shfl_xor(ped[m], 16, 64);
            ped[m] += __shfl_xor(ped[m], 32, 64);
            int arow = row0 + m * 16 + col;
            if (q == 0 && arow < N) edv[arow] = ped[m];
        }
    }
}

// ---------------- matvec (x_fp @ wedt), one wave per row ----------------
template <int K>
__global__ __launch_bounds__(256) void matvec_k(const float* __restrict__ X, const float* __restrict__ v,
                                                float* __restrict__ y, int N) {
    int lane = threadIdx.x & 63, wid = threadIdx.x >> 6;
    int node = blockIdx.x * 4 + wid;
    if (node >= N) return;
    float s = X[node * K + lane] * v[lane];
    if (K > 64) s += X[node * K + 64 + lane] * v[64 + lane];
    #pragma unroll
    for (int off = 32; off; off >>= 1) s += __shfl_down(s, off, 64);
    if (lane == 0) y[node] = s;
}

// ---------------- GAT aggregate (pano, C=128, bf16 hs gather) -> h as bf16 hi/lo ----------------
__global__ __launch_bounds__(256) void agg_pano4(const int* __restrict__ ptr, const int* __restrict__ col,
                                                 const float* __restrict__ es, const float* __restrict__ ed,
                                                 const ushort_t* __restrict__ hsb, const float* __restrict__ lin,
                                                 const float* __restrict__ b, const float* __restrict__ Lb,
                                                 uint_t* __restrict__ hh, uint_t* __restrict__ hl, int N) {
    int lane = threadIdx.x & 63, wid = threadIdx.x >> 6;
    int node = blockIdx.x * 4 + wid;
    if (node >= N) return;
    int beg = ptr[node], end = ptr[node + 1];
    float edn = ed[node];
    int ch = lane * 2;
    float ax = 0.f, ay = 0.f, den = 0.f;
    int i = beg;
    for (; i + 8 <= end; i += 8) {
        int s[8];
        #pragma unroll
        for (int u = 0; u < 8; ++u) s[u] = col[i + u];
        float w[8];
        #pragma unroll
        for (int u = 0; u < 8; ++u) {
            float e = es[s[u]] + edn;
            e = fmaxf(e, 0.2f * e);
            w[u] = __expf(e);
        }
        uint_t hv[8];
        #pragma unroll
        for (int u = 0; u < 8; ++u) hv[u] = *(const uint_t*)&hsb[(size_t)s[u] * 128 + ch];
        #pragma unroll
        for (int u = 0; u < 8; ++u) {
            float hx = __uint_as_float((hv[u] & 0xffffu) << 16);
            float hy = __uint_as_float(hv[u] & 0xffff0000u);
            den += w[u];
            ax += w[u] * hx;
            ay += w[u] * hy;
        }
    }
    for (; i < end; ++i) {
        int s = col[i];
        float e = es[s] + edn;
        e = fmaxf(e, 0.2f * e);
        float wgt = __expf(e);
        uint_t hv = *(const uint_t*)&hsb[(size_t)s * 128 + ch];
        float hx = __uint_as_float((hv & 0xffffu) << 16);
        float hy = __uint_as_float(hv & 0xffff0000u);
        den += wgt;
        ax += wgt * hx;
        ay += wgt * hy;
    }
    float inv = (end > beg) ? (1.f / den) : 0.f;
    float2 l2 = *(const float2*)&lin[(size_t)node * 128 + ch];
    float2 bb = *(const float2*)&b[ch];
    float2 lb = *(const float2*)&Lb[ch];
    float ox = fmaxf(ax * inv + bb.x + l2.x + lb.x, 0.f);
    float oy = fmaxf(ay * inv + bb.y + l2.y + lb.y, 0.f);
    ushort_t hx = f2bf(ox), hy = f2bf(oy);
    hh[(size_t)node * 64 + lane] = (uint_t)hx | ((uint_t)hy << 16);
    hl[(size_t)node * 64 + lane] = pack2bf(ox - bfu2f(hx), oy - bfu2f(hy));
}

// ---------------- translate aggregate (C=64, bf16 hs gather) ----------------
__global__ __launch_bounds__(256) void agg_fp3(const int* __restrict__ ptr, const int* __restrict__ col,
                                               const float* __restrict__ es, const float* __restrict__ ed,
                                               const ushort_t* __restrict__ hsb, const float* __restrict__ bt,
                                               float* __restrict__ out, int N) {
    int lane = threadIdx.x & 63, wid = threadIdx.x >> 6;
    int node = blockIdx.x * 4 + wid;
    if (node >= N) return;
    int beg = ptr[node], end = ptr[node + 1];
    float edn = ed[node];
    float acc = 0.f, den = 0.f;
    int i = beg;
    for (; i + 8 <= end; i += 8) {
        int s[8];
        #pragma unroll
        for (int u = 0; u < 8; ++u) s[u] = col[i + u];
        float w[8];
        #pragma unroll
        for (int u = 0; u < 8; ++u) {
            float e = es[s[u]] + edn;
            e = fmaxf(e, 0.2f * e);
            w[u] = __expf(e);
        }
        ushort_t hv[8];
        #pragma unroll
        for (int u = 0; u < 8; ++u) hv[u] = hsb[(size_t)s[u] * 64 + lane];
        #pragma unroll
        for (int u = 0; u < 8; ++u) {
            den += w[u];
            acc += w[u] * bfu2f(hv[u]);
        }
    }
    for (; i < end; ++i) {
        int s = col[i];
        float e = es[s] + edn;
        e = fmaxf(e, 0.2f * e);
        float wgt = __expf(e);
        den += wgt;
        acc += wgt * bfu2f(hsb[(size_t)s * 64 + lane]);
    }
    float inv = (end > beg) ? (1.f / den) : 0.f;
    out[(size_t)node * 64 + lane] = acc * inv + bt[lane];
}

extern "C" void kernel_launch(void* const* d_in, const int* in_sizes, int n_in,
                              void* d_out, int out_size, void* d_ws, size_t ws_size,
                              hipStream_t stream) {
    const float* x_pano = (const float*)d_in[0];
    const float* x_fp   = (const float*)d_in[1];
    const float* Ws0 = (const float*)d_in[2];
    const float* Wd0 = (const float*)d_in[3];
    const float* as0 = (const float*)d_in[4];
    const float* ad0 = (const float*)d_in[5];
    const float* b0  = (const float*)d_in[6];
    const float* Lw0 = (const float*)d_in[7];
    const float* Lb0 = (const float*)d_in[8];
    const float* Ws1 = (const float*)d_in[9];
    const float* Wd1 = (const float*)d_in[10];
    const float* as1 = (const float*)d_in[11];
    const float* ad1 = (const float*)d_in[12];
    const float* b1  = (const float*)d_in[13];
    const float* Lw1 = (const float*)d_in[14];
    const float* Lb1 = (const float*)d_in[15];
    const float* Wts = (const float*)d_in[16];
    const float* Wtd = (const float*)d_in[17];
    const float* ats = (const float*)d_in[18];
    const float* atd = (const float*)d_in[19];
    const float* bt  = (const float*)d_in[20];
    const int* edge_pp = (const int*)d_in[21];
    const int* pf_src  = (const int*)d_in[22];
    const int* pf_dst  = (const int*)d_in[23];
    float* out = (float*)d_out;

    char* wsp = (char*)d_ws;
    size_t off = 0;
    auto alloc = [&](size_t bytes) -> char* {
        char* p = wsp + off;
        off += (bytes + 255) & ~(size_t)255;
        return p;
    };
    ushort_t* hsb  = (ushort_t*)alloc(sizeof(ushort_t) * N_PANO * HID);   // 12.8 MB
    float* lin     = (float*)alloc(sizeof(float) * N_PANO * HID);         // 25.6 MB
    uint_t* hh     = (uint_t*)alloc(sizeof(uint_t) * N_PANO * 64);        // 12.8 MB
    uint_t* hl     = (uint_t*)alloc(sizeof(uint_t) * N_PANO * 64);        // 12.8 MB
    ushort_t* hstb = (ushort_t*)alloc(sizeof(ushort_t) * N_PANO * OUT_C); // 6.4 MB
    int2* tmp_pp   = (int2*)alloc(sizeof(int2) * E_PP);                   // 6.4 MB
    float* es   = (float*)alloc(sizeof(float) * N_PANO);
    float* ed   = (float*)alloc(sizeof(float) * N_PANO);
    float* edt  = (float*)alloc(sizeof(float) * N_FP);
    float* wed0 = (float*)alloc(sizeof(float) * HID);
    float* wed1 = (float*)alloc(sizeof(float) * HID);
    float* wedt = (float*)alloc(sizeof(float) * OUT_C);
    ushort_t* s0h = (ushort_t*)alloc(sizeof(ushort_t) * 128 * 128);
    ushort_t* s0l = (ushort_t*)alloc(sizeof(ushort_t) * 128 * 128);
    ushort_t* l0h = (ushort_t*)alloc(sizeof(ushort_t) * 128 * 128);
    ushort_t* l0l = (ushort_t*)alloc(sizeof(ushort_t) * 128 * 128);
    ushort_t* s1h = (ushort_t*)alloc(sizeof(ushort_t) * 128 * 128);
    ushort_t* s1l = (ushort_t*)alloc(sizeof(ushort_t) * 128 * 128);
    ushort_t* l1h = (ushort_t*)alloc(sizeof(ushort_t) * 128 * 128);
    ushort_t* l1l = (ushort_t*)alloc(sizeof(ushort_t) * 128 * 128);
    ushort_t* tsh = (ushort_t*)alloc(sizeof(ushort_t) * 64 * 128);
    ushort_t* tsl = (ushort_t*)alloc(sizeof(ushort_t) * 64 * 128);
    int* cnt    = (int*)alloc(sizeof(int) * N_PANO);
    int* cur    = (int*)alloc(sizeof(int) * N_PANO);
    int* bsum   = (int*)alloc(sizeof(int) * 64);
    int* bcur   = (int*)alloc(sizeof(int) * NBKT * 16);   // padded: 1 counter / 64B line
    int* ptr_pp = (int*)alloc(sizeof(int) * (N_PANO + 1));
    int* col_pp = (int*)alloc(sizeof(int) * E_PP);
    int* ptr_pf = (int*)alloc(sizeof(int) * (N_FP + 1));
    int* col_pf = (int*)alloc(sizeof(int) * E_PF);

    const int* pp_src = edge_pp;
    const int* pp_dst = edge_pp + E_PP;

    // ---- CSR build (pp): count -> scan -> aggregated bucketed scatter ----
    {
        int nb = cdiv(N_PANO, 1024);
        zero_i32<<<cdiv(N_PANO, 256), 256, 0, stream>>>(cnt, N_PANO);
        count_k<<<cdiv(E_PP, 256), 256, 0, stream>>>(pp_dst, E_PP, cnt);
        scan_local<<<nb, 1024, 0, stream>>>(cnt, ptr_pp, bsum, N_PANO);
        scan_bsum<<<1, 64, 0, stream>>>(bsum, nb, &ptr_pp[N_PANO]);
        scan_add<<<nb, 1024, 0, stream>>>(ptr_pp, cur, bsum, N_PANO);
        bucket_init<<<1, 256, 0, stream>>>(ptr_pp, bcur);
        bucket_scatter_agg<<<cdiv(E_PP, EPB), 256, 0, stream>>>(pp_src, pp_dst, E_PP, bcur, tmp_pp);
        fine_scatter<<<cdiv(E_PP, 256), 256, 0, stream>>>(tmp_pp, E_PP, cur, col_pp);
    }
    // ---- CSR build (pf): small, simple scatter ----
    {
        int nb = cdiv(N_FP, 1024);
        zero_i32<<<cdiv(N_FP, 256), 256, 0, stream>>>(cnt, N_FP);
        count_k<<<cdiv(E_PF, 256), 256, 0, stream>>>(pf_dst, E_PF, cnt);
        scan_local<<<nb, 1024, 0, stream>>>(cnt, ptr_pf, bsum, N_FP);
        scan_bsum<<<1, 64, 0, stream>>>(bsum, nb, &ptr_pf[N_FP]);
        scan_add<<<nb, 1024, 0, stream>>>(ptr_pf, cur, bsum, N_FP);
        scatter_k<<<cdiv(E_PF, 256), 256, 0, stream>>>(pf_src, pf_dst, E_PF, cur, col_pf);
    }
    // ---- fold Wd @ a_d ; convert weights to fragment order ----
    wed_all<<<320, 64, 0, stream>>>(Wd0, ad0, Wd1, ad1, Wtd, atd, wed0, wed1, wedt);
    wconv<<<288, 256, 0, stream>>>(Ws0, Lw0, Ws1, Lw1, Wts,
                                   s0h, s0l, l0h, l0l, s1h, s1l, l1h, l1l, tsh, tsl);

    const int gemm_grid = cdiv(N_PANO, 128);

    // ---- layer 0 (fp32 input) ----
    gemm_mfma<128, true, true><<<gemm_grid, 256, 0, stream>>>(
        x_pano, nullptr, nullptr, s0h, s0l, l0h, l0l,
        hsb, lin, as0, es, wed0, ed, N_PANO);
    agg_pano4<<<cdiv(N_PANO, 4), 256, 0, stream>>>(ptr_pp, col_pp, es, ed, hsb, lin, b0, Lb0, hh, hl, N_PANO);

    // ---- layer 1 (bf16 hi/lo input) ----
    gemm_mfma<128, true, false><<<gemm_grid, 256, 0, stream>>>(
        nullptr, (const ushort_t*)hh, (const ushort_t*)hl, s1h, s1l, l1h, l1l,
        hsb, lin, as1, es, wed1, ed, N_PANO);
    agg_pano4<<<cdiv(N_PANO, 4), 256, 0, stream>>>(ptr_pp, col_pp, es, ed, hsb, lin, b1, Lb1, hh, hl, N_PANO);

    // ---- translate (pano -> footprint) ----
    gemm_mfma<64, false, false><<<gemm_grid, 256, 0, stream>>>(
        nullptr, (const ushort_t*)hh, (const ushort_t*)hl, tsh, tsl, nullptr, nullptr,
        hstb, nullptr, ats, es, nullptr, nullptr, N_PANO);
    matvec_k<64><<<cdiv(N_FP, 4), 256, 0, stream>>>(x_fp, wedt, edt, N_FP);
    agg_fp3<<<cdiv(N_FP, 4), 256, 0, stream>>>(ptr_pf, col_pf, es, edt, hstb, bt, out, N_FP);
}

// Round 8
// 363.900 us; speedup vs baseline: 2.2462x; 1.0495x over previous
//
#include <hip/hip_runtime.h>
#include <hip/hip_bf16.h>
#include <math.h>

#define N_PANO 50000
#define N_FP   10000
#define HID    128
#define OUT_C  64
#define E_PP   800000
#define E_PF   50000
#define NBKT   196   // cdiv(N_PANO, 256) coarse buckets for the pp scatter
#define EPB    4096  // edges per block in the aggregated coarse scatter

typedef unsigned short ushort_t;
typedef unsigned int uint_t;
typedef __attribute__((ext_vector_type(8))) short short8;
typedef __attribute__((ext_vector_type(4))) float f32x4;

static inline int cdiv(int a, int b) { return (a + b - 1) / b; }

__device__ inline ushort_t f2bf(float x) {
    __hip_bfloat16 h = __float2bfloat16(x);   // RNE
    return *reinterpret_cast<ushort_t*>(&h);
}
__device__ inline float bfu2f(ushort_t u) {
    return __uint_as_float(((uint_t)u) << 16);
}
__device__ inline uint_t pack2bf(float a, float b) {
    return (uint_t)f2bf(a) | ((uint_t)f2bf(b) << 16);
}
__device__ inline f32x4 mfma16(short8 a, short8 b, f32x4 c) {
    return __builtin_amdgcn_mfma_f32_16x16x32_bf16(a, b, c, 0, 0, 0);
}

// ---------------- CSR build ----------------
__global__ __launch_bounds__(256) void zero_i32(int* p, int n) {
    int i = blockIdx.x * 256 + threadIdx.x;
    if (i < n) p[i] = 0;
}

__global__ __launch_bounds__(256) void count_k(const int* __restrict__ dst, int E, int* __restrict__ cnt) {
    int i = blockIdx.x * 256 + threadIdx.x;
    if (i < E) atomicAdd(&cnt[dst[i]], 1);
}

__global__ __launch_bounds__(1024) void scan_local(const int* __restrict__ cnt, int* __restrict__ ptr,
                                                   int* __restrict__ bsum, int n) {
    __shared__ int wsum[16];
    int tid = threadIdx.x, lane = tid & 63, wid = tid >> 6;
    int i = blockIdx.x * 1024 + tid;
    int v = (i < n) ? cnt[i] : 0;
    int incl = v;
    #pragma unroll
    for (int off = 1; off < 64; off <<= 1) {
        int t = __shfl_up(incl, off, 64);
        if (lane >= off) incl += t;
    }
    if (lane == 63) wsum[wid] = incl;
    __syncthreads();
    if (tid == 0) {
        int run = 0;
        #pragma unroll
        for (int w = 0; w < 16; ++w) { int t = wsum[w]; wsum[w] = run; run += t; }
        bsum[blockIdx.x] = run;
    }
    __syncthreads();
    int excl = wsum[wid] + incl - v;
    if (i < n) ptr[i] = excl;
}

__global__ __launch_bounds__(64) void scan_bsum(int* __restrict__ bsum, int nb, int* __restrict__ total_out) {
    int lane = threadIdx.x;
    int v = (lane < nb) ? bsum[lane] : 0;
    int incl = v;
    #pragma unroll
    for (int off = 1; off < 64; off <<= 1) {
        int t = __shfl_up(incl, off, 64);
        if (lane >= off) incl += t;
    }
    if (lane < nb) bsum[lane] = incl - v;
    if (lane == 63) *total_out = incl;
}

__global__ __launch_bounds__(1024) void scan_add(int* __restrict__ ptr, int* __restrict__ cur,
                                                 const int* __restrict__ bsum, int n) {
    int i = blockIdx.x * 1024 + threadIdx.x;
    if (i < n) {
        int v = ptr[i] + bsum[blockIdx.x];
        ptr[i] = v;
        cur[i] = v;
    }
}

// simple scatter (used for the small pf edge set only)
__global__ __launch_bounds__(256) void scatter_k(const int* __restrict__ src, const int* __restrict__ dst,
                                                 int E, int* __restrict__ cur, int* __restrict__ col) {
    int i = blockIdx.x * 256 + threadIdx.x;
    if (i < E) {
        int p = atomicAdd(&cur[dst[i]], 1);
        col[p] = src[i];
    }
}

// ---- bucketed scatter for pp ----
__global__ __launch_bounds__(256) void bucket_init(const int* __restrict__ ptr, int* __restrict__ bcur) {
    int b = blockIdx.x * 256 + threadIdx.x;
    if (b < NBKT) bcur[b * 16] = ptr[b << 8];
}

// Block-aggregated coarse scatter: LDS histogram -> one global atomic per
// (block,bucket) -> LDS-cursor placement. 38k global atomics instead of 800k.
__global__ __launch_bounds__(256) void bucket_scatter_agg(const int* __restrict__ src,
                                                          const int* __restrict__ dst, int E,
                                                          int* __restrict__ bcur, int2* __restrict__ tmp) {
    __shared__ int hist[NBKT];
    __shared__ int base[NBKT];
    const int tid = threadIdx.x;
    const int e0 = blockIdx.x * EPB;
    for (int t = tid; t < NBKT; t += 256) hist[t] = 0;
    __syncthreads();
    int d[16];
    #pragma unroll
    for (int u = 0; u < 16; ++u) {
        int e = e0 + u * 256 + tid;
        d[u] = (e < E) ? dst[e] : -1;
        if (d[u] >= 0) atomicAdd(&hist[d[u] >> 8], 1);
    }
    __syncthreads();
    for (int t = tid; t < NBKT; t += 256) {
        int c = hist[t];
        base[t] = (c > 0) ? atomicAdd(&bcur[t * 16], c) : 0;
        hist[t] = 0;
    }
    __syncthreads();
    #pragma unroll
    for (int u = 0; u < 16; ++u) {
        if (d[u] >= 0) {
            int b = d[u] >> 8;
            int p = base[b] + atomicAdd(&hist[b], 1);
            tmp[p] = make_int2(src[e0 + u * 256 + tid], d[u]);
        }
    }
}

__global__ __launch_bounds__(256) void fine_scatter(const int2* __restrict__ tmp, int E,
                                                    int* __restrict__ cur, int* __restrict__ col) {
    int i = blockIdx.x * 256 + threadIdx.x;
    if (i < E) {
        int2 e = tmp[i];
        int p = atomicAdd(&cur[e.y], 1);
        col[p] = e.x;                    // p lies in the same bucket window as i
    }
}

// ---------------- wed[i] = sum_j W[i][j]*a[j] for all three layers, one launch ----------------
__global__ __launch_bounds__(64) void wed_all(const float* __restrict__ Wd0, const float* __restrict__ ad0,
                                              const float* __restrict__ Wd1, const float* __restrict__ ad1,
                                              const float* __restrict__ Wtd, const float* __restrict__ atd,
                                              float* __restrict__ o0, float* __restrict__ o1,
                                              float* __restrict__ ot) {
    int bid = blockIdx.x, lane = threadIdx.x;
    const float* W; const float* a; float* o; int r, C;
    if (bid < 128)      { W = Wd0; a = ad0; o = o0; r = bid;       C = 128; }
    else if (bid < 256) { W = Wd1; a = ad1; o = o1; r = bid - 128; C = 128; }
    else                { W = Wtd; a = atd; o = ot; r = bid - 256; C = 64;  }
    float s = 0.f;
    for (int j = lane; j < C; j += 64) s += W[r * C + j] * a[j];
    #pragma unroll
    for (int off = 32; off; off >>= 1) s += __shfl_down(s, off, 64);
    if (lane == 0) o[r] = s;
}

// ---------------- weight -> bf16 hi/lo split, permuted to MFMA B-fragment order ----
__global__ __launch_bounds__(256) void wconv(const float* __restrict__ Ws0, const float* __restrict__ Lw0,
                                             const float* __restrict__ Ws1, const float* __restrict__ Lw1,
                                             const float* __restrict__ Wts,
                                             ushort_t* s0h, ushort_t* s0l, ushort_t* l0h, ushort_t* l0l,
                                             ushort_t* s1h, ushort_t* s1l, ushort_t* l1h, ushort_t* l1l,
                                             ushort_t* tsh, ushort_t* tsl) {
    int i = blockIdx.x * 256 + threadIdx.x;
    const float* W; ushort_t* oh; ushort_t* ol;
    int d, NIc, Cc;
    if (i < 65536) {
        int m = i >> 14; d = i & 16383;
        W = (m == 0) ? Ws0 : (m == 1) ? Lw0 : (m == 2) ? Ws1 : Lw1;
        oh = (m == 0) ? s0h : (m == 1) ? l0h : (m == 2) ? s1h : l1h;
        ol = (m == 0) ? s0l : (m == 1) ? l0l : (m == 2) ? s1l : l1l;
        NIc = 8; Cc = 128;
    } else if (i < 73728) {
        d = i - 65536; W = Wts; oh = tsh; ol = tsl;
        NIc = 4; Cc = 64;
    } else return;
    int j = d & 7, l = (d >> 3) & 63;
    int kcl = (d >> 9) & 1;
    int ni = (d >> 10) & (NIc - 1);
    int p = d >> (10 + (NIc == 8 ? 3 : 2));
    int kc = p * 2 + kcl;
    int n = ni * 16 + (l & 15);
    int k = kc * 32 + (l >> 4) * 8 + j;
    float v = W[k * Cc + n];
    ushort_t hi = f2bf(v);
    ushort_t lo = f2bf(v - bfu2f(hi));
    oh[d] = hi;
    ol[d] = lo;
}

// ---------------- MFMA GEMM with LDS-staged fragment-order weights ----------------
// Y1 -> bf16 (+fused es); DUAL: Y2 -> bf16 (residual branch; bf16 is enough since
// it feeds only the +lin add, abs err ~4e-3 vs 4.6e-2 margin); opt ed = X.wed.
template <int CN, bool DUAL, bool FP32IN>
__global__ __launch_bounds__(256, 2) void gemm_mfma(const float* __restrict__ Xf,
                                                 const ushort_t* __restrict__ Xh, const ushort_t* __restrict__ Xl,
                                                 const ushort_t* __restrict__ W1h, const ushort_t* __restrict__ W1l,
                                                 const ushort_t* __restrict__ W2h, const ushort_t* __restrict__ W2l,
                                                 ushort_t* __restrict__ Y1, ushort_t* __restrict__ Y2,
                                                 const float* __restrict__ avec, float* __restrict__ evec,
                                                 const float* __restrict__ wed, float* __restrict__ edv,
                                                 int N) {
    constexpr int NI = CN / 16;
    constexpr int NMAT = DUAL ? 4 : 2;
    constexpr int SLAB = NI * 1024;          // ushorts per matrix per phase
    __shared__ ushort_t Bsh[NMAT * SLAB];    // 64 KB dual / 16 KB single
    const int tid = threadIdx.x;
    const int w = tid >> 6, l = tid & 63;
    const int col = l & 15, q = l >> 4;
    const int row0 = blockIdx.x * 128 + w * 32;
    f32x4 acc1[2][NI];
    f32x4 acc2[2][DUAL ? NI : 1];
    #pragma unroll
    for (int m = 0; m < 2; ++m)
        #pragma unroll
        for (int ni = 0; ni < NI; ++ni)
            #pragma unroll
            for (int r = 0; r < 4; ++r) acc1[m][ni][r] = 0.f;
    if (DUAL) {
        #pragma unroll
        for (int m = 0; m < 2; ++m)
            #pragma unroll
            for (int ni = 0; ni < NI; ++ni)
                #pragma unroll
                for (int r = 0; r < 4; ++r) acc2[m][ni][r] = 0.f;
    }
    float ped[2] = {0.f, 0.f};

    const ushort_t* Wp[NMAT];
    Wp[0] = W1h; Wp[1] = W1l;
    if (DUAL) { Wp[2] = W2h; Wp[3] = W2l; }

    #pragma unroll
    for (int p = 0; p < 2; ++p) {
        if (p) __syncthreads();
        #pragma unroll
        for (int m = 0; m < NMAT; ++m) {
            const uint4* src = (const uint4*)Wp[m] + p * (SLAB / 8);
            uint4* dst = (uint4*)&Bsh[m * SLAB];
            #pragma unroll
            for (int f = tid; f < SLAB / 8; f += 256) dst[f] = src[f];
        }
        __syncthreads();
        #pragma unroll
        for (int kcl = 0; kcl < 2; ++kcl) {
            const int kc = p * 2 + kcl;
            const int k0 = kc * 32 + q * 8;
            short8 Ah[2], Al[2];
            #pragma unroll
            for (int m = 0; m < 2; ++m) {
                const int arow = row0 + m * 16 + col;
                if (FP32IN) {
                    float xv[8];
                    if (arow < N) {
                        float4 a0 = *(const float4*)&Xf[(size_t)arow * 128 + k0];
                        float4 a1 = *(const float4*)&Xf[(size_t)arow * 128 + k0 + 4];
                        xv[0] = a0.x; xv[1] = a0.y; xv[2] = a0.z; xv[3] = a0.w;
                        xv[4] = a1.x; xv[5] = a1.y; xv[6] = a1.z; xv[7] = a1.w;
                    } else {
                        #pragma unroll
                        for (int j = 0; j < 8; ++j) xv[j] = 0.f;
                    }
                    #pragma unroll
                    for (int j = 0; j < 8; ++j) {
                        ushort_t hi = f2bf(xv[j]);
                        ushort_t lo = f2bf(xv[j] - bfu2f(hi));
                        Ah[m][j] = (short)hi;
                        Al[m][j] = (short)lo;
                    }
                    if (wed) {
                        float4 w0 = *(const float4*)&wed[k0];
                        float4 w1 = *(const float4*)&wed[k0 + 4];
                        ped[m] += xv[0] * w0.x + xv[1] * w0.y + xv[2] * w0.z + xv[3] * w0.w
                                + xv[4] * w1.x + xv[5] * w1.y + xv[6] * w1.z + xv[7] * w1.w;
                    }
                } else {
                    if (arow < N) {
                        Ah[m] = *(const short8*)&Xh[(size_t)arow * 128 + k0];
                        Al[m] = *(const short8*)&Xl[(size_t)arow * 128 + k0];
                    } else {
                        #pragma unroll
                        for (int j = 0; j < 8; ++j) { Ah[m][j] = 0; Al[m][j] = 0; }
                    }
                    if (wed) {
                        float4 w0 = *(const float4*)&wed[k0];
                        float4 w1 = *(const float4*)&wed[k0 + 4];
                        float wv[8] = {w0.x, w0.y, w0.z, w0.w, w1.x, w1.y, w1.z, w1.w};
                        #pragma unroll
                        for (int j = 0; j < 8; ++j)
                            ped[m] += (bfu2f((ushort_t)Ah[m][j]) + bfu2f((ushort_t)Al[m][j])) * wv[j];
                    }
                }
            }
            #pragma unroll
            for (int ni = 0; ni < NI; ++ni) {
                const int lb = ((ni * 2 + kcl) * 64 + l) * 8;
                short8 B1h = *(const short8*)&Bsh[0 * SLAB + lb];
                short8 B1l = *(const short8*)&Bsh[1 * SLAB + lb];
                #pragma unroll
                for (int m = 0; m < 2; ++m) {
                    acc1[m][ni] = mfma16(Ah[m], B1h, acc1[m][ni]);
                    acc1[m][ni] = mfma16(Al[m], B1h, acc1[m][ni]);
                    acc1[m][ni] = mfma16(Ah[m], B1l, acc1[m][ni]);
                }
                if (DUAL) {
                    short8 B2h = *(const short8*)&Bsh[2 * SLAB + lb];
                    short8 B2l = *(const short8*)&Bsh[3 * SLAB + lb];
                    #pragma unroll
                    for (int m = 0; m < 2; ++m) {
                        acc2[m][ni] = mfma16(Ah[m], B2h, acc2[m][ni]);
                        acc2[m][ni] = mfma16(Al[m], B2h, acc2[m][ni]);
                        acc2[m][ni] = mfma16(Ah[m], B2l, acc2[m][ni]);
                    }
                }
            }
        }
    }

    #pragma unroll
    for (int m = 0; m < 2; ++m) {
        #pragma unroll
        for (int ni = 0; ni < NI; ++ni) {
            #pragma unroll
            for (int r = 0; r < 4; ++r) {
                int mrow = row0 + m * 16 + q * 4 + r;
                if (mrow < N) {
                    Y1[(size_t)mrow * CN + ni * 16 + col] = f2bf(acc1[m][ni][r]);
                    if (DUAL) Y2[(size_t)mrow * CN + ni * 16 + col] = f2bf(acc2[m][ni][r]);
                }
            }
        }
    }
    float av[NI];
    #pragma unroll
    for (int ni = 0; ni < NI; ++ni) av[ni] = avec[ni * 16 + col];
    #pragma unroll
    for (int m = 0; m < 2; ++m) {
        #pragma unroll
        for (int r = 0; r < 4; ++r) {
            float pp = 0.f;
            #pragma unroll
            for (int ni = 0; ni < NI; ++ni) pp += acc1[m][ni][r] * av[ni];
            pp += __shfl_xor(pp, 1, 64);
            pp += __shfl_xor(pp, 2, 64);
            pp += __shfl_xor(pp, 4, 64);
            pp += __shfl_xor(pp, 8, 64);
            int mrow = row0 + m * 16 + q * 4 + r;
            if (col == 0 && mrow < N) evec[mrow] = pp;
        }
    }
    if (wed) {
        #pragma unroll
        for (int m = 0; m < 2; ++m) {
            ped[m] += __shfl_xor(ped[m], 16, 64);
            ped[m] += __shfl_xor(ped[m], 32, 64);
            int arow = row0 + m * 16 + col;
            if (q == 0 && arow < N) edv[arow] = ped[m];
        }
    }
}

// ---------------- matvec (x_fp @ wedt), one wave per row ----------------
template <int K>
__global__ __launch_bounds__(256) void matvec_k(const float* __restrict__ X, const float* __restrict__ v,
                                                float* __restrict__ y, int N) {
    int lane = threadIdx.x & 63, wid = threadIdx.x >> 6;
    int node = blockIdx.x * 4 + wid;
    if (node >= N) return;
    float s = X[node * K + lane] * v[lane];
    if (K > 64) s += X[node * K + 64 + lane] * v[64 + lane];
    #pragma unroll
    for (int off = 32; off; off >>= 1) s += __shfl_down(s, off, 64);
    if (lane == 0) y[node] = s;
}

// ---------------- GAT aggregate (pano), phase-split ----------------
// Phase 1: weights for up to 64 edges lane-parallel (1 exp/edge total).
// Phase 2: shfl-broadcast (src,w); per edge per lane only load+unpack+2 FMA.
__global__ __launch_bounds__(256) void agg_pano5(const int* __restrict__ ptr, const int* __restrict__ col,
                                                 const float* __restrict__ es, const float* __restrict__ ed,
                                                 const ushort_t* __restrict__ hsb, const uint_t* __restrict__ linb,
                                                 const float* __restrict__ b, const float* __restrict__ Lb,
                                                 uint_t* __restrict__ hh, uint_t* __restrict__ hl, int N) {
    int lane = threadIdx.x & 63, wid = threadIdx.x >> 6;
    int node = blockIdx.x * 4 + wid;
    if (node >= N) return;
    int beg = ptr[node], end = ptr[node + 1];
    float edn = ed[node];
    int ch = lane * 2;
    float ax = 0.f, ay = 0.f, denp = 0.f;
    for (int base = beg; base < end; base += 64) {
        int m = min(64, end - base);
        int s = 0;
        float wgt = 0.f;
        if (lane < m) {
            s = col[base + lane];
            float e = es[s] + edn;
            e = fmaxf(e, 0.2f * e);
            wgt = __expf(e);
        }
        denp += wgt;
        int u = 0;
        for (; u + 4 <= m; u += 4) {
            int s0 = __shfl(s, u, 64), s1 = __shfl(s, u + 1, 64);
            int s2 = __shfl(s, u + 2, 64), s3 = __shfl(s, u + 3, 64);
            float w0 = __shfl(wgt, u, 64), w1 = __shfl(wgt, u + 1, 64);
            float w2 = __shfl(wgt, u + 2, 64), w3 = __shfl(wgt, u + 3, 64);
            uint_t h0 = *(const uint_t*)&hsb[(size_t)s0 * 128 + ch];
            uint_t h1 = *(const uint_t*)&hsb[(size_t)s1 * 128 + ch];
            uint_t h2 = *(const uint_t*)&hsb[(size_t)s2 * 128 + ch];
            uint_t h3 = *(const uint_t*)&hsb[(size_t)s3 * 128 + ch];
            ax += w0 * __uint_as_float((h0 & 0xffffu) << 16);
            ay += w0 * __uint_as_float(h0 & 0xffff0000u);
            ax += w1 * __uint_as_float((h1 & 0xffffu) << 16);
            ay += w1 * __uint_as_float(h1 & 0xffff0000u);
            ax += w2 * __uint_as_float((h2 & 0xffffu) << 16);
            ay += w2 * __uint_as_float(h2 & 0xffff0000u);
            ax += w3 * __uint_as_float((h3 & 0xffffu) << 16);
            ay += w3 * __uint_as_float(h3 & 0xffff0000u);
        }
        for (; u < m; ++u) {
            int su = __shfl(s, u, 64);
            float wu = __shfl(wgt, u, 64);
            uint_t hv = *(const uint_t*)&hsb[(size_t)su * 128 + ch];
            ax += wu * __uint_as_float((hv & 0xffffu) << 16);
            ay += wu * __uint_as_float(hv & 0xffff0000u);
        }
    }
    float den = denp;
    #pragma unroll
    for (int off = 1; off < 64; off <<= 1) den += __shfl_xor(den, off, 64);
    float inv = (end > beg) ? (1.f / den) : 0.f;
    uint_t lv = linb[(size_t)node * 64 + lane];
    float lx = __uint_as_float((lv & 0xffffu) << 16);
    float ly = __uint_as_float(lv & 0xffff0000u);
    float2 bb = *(const float2*)&b[ch];
    float2 lb = *(const float2*)&Lb[ch];
    float ox = fmaxf(ax * inv + bb.x + lx + lb.x, 0.f);
    float oy = fmaxf(ay * inv + bb.y + ly + lb.y, 0.f);
    ushort_t hx = f2bf(ox), hy = f2bf(oy);
    hh[(size_t)node * 64 + lane] = (uint_t)hx | ((uint_t)hy << 16);
    hl[(size_t)node * 64 + lane] = pack2bf(ox - bfu2f(hx), oy - bfu2f(hy));
}

// ---------------- translate aggregate (C=64), phase-split ----------------
__global__ __launch_bounds__(256) void agg_fp4(const int* __restrict__ ptr, const int* __restrict__ col,
                                               const float* __restrict__ es, const float* __restrict__ ed,
                                               const ushort_t* __restrict__ hsb, const float* __restrict__ bt,
                                               float* __restrict__ out, int N) {
    int lane = threadIdx.x & 63, wid = threadIdx.x >> 6;
    int node = blockIdx.x * 4 + wid;
    if (node >= N) return;
    int beg = ptr[node], end = ptr[node + 1];
    float edn = ed[node];
    float acc = 0.f, denp = 0.f;
    for (int base = beg; base < end; base += 64) {
        int m = min(64, end - base);
        int s = 0;
        float wgt = 0.f;
        if (lane < m) {
            s = col[base + lane];
            float e = es[s] + edn;
            e = fmaxf(e, 0.2f * e);
            wgt = __expf(e);
        }
        denp += wgt;
        int u = 0;
        for (; u + 4 <= m; u += 4) {
            int s0 = __shfl(s, u, 64), s1 = __shfl(s, u + 1, 64);
            int s2 = __shfl(s, u + 2, 64), s3 = __shfl(s, u + 3, 64);
            float w0 = __shfl(wgt, u, 64), w1 = __shfl(wgt, u + 1, 64);
            float w2 = __shfl(wgt, u + 2, 64), w3 = __shfl(wgt, u + 3, 64);
            float h0 = bfu2f(hsb[(size_t)s0 * 64 + lane]);
            float h1 = bfu2f(hsb[(size_t)s1 * 64 + lane]);
            float h2 = bfu2f(hsb[(size_t)s2 * 64 + lane]);
            float h3 = bfu2f(hsb[(size_t)s3 * 64 + lane]);
            acc += w0 * h0 + w1 * h1 + w2 * h2 + w3 * h3;
        }
        for (; u < m; ++u) {
            int su = __shfl(s, u, 64);
            float wu = __shfl(wgt, u, 64);
            acc += wu * bfu2f(hsb[(size_t)su * 64 + lane]);
        }
    }
    float den = denp;
    #pragma unroll
    for (int off = 1; off < 64; off <<= 1) den += __shfl_xor(den, off, 64);
    float inv = (end > beg) ? (1.f / den) : 0.f;
    out[(size_t)node * 64 + lane] = acc * inv + bt[lane];
}

extern "C" void kernel_launch(void* const* d_in, const int* in_sizes, int n_in,
                              void* d_out, int out_size, void* d_ws, size_t ws_size,
                              hipStream_t stream) {
    const float* x_pano = (const float*)d_in[0];
    const float* x_fp   = (const float*)d_in[1];
    const float* Ws0 = (const float*)d_in[2];
    const float* Wd0 = (const float*)d_in[3];
    const float* as0 = (const float*)d_in[4];
    const float* ad0 = (const float*)d_in[5];
    const float* b0  = (const float*)d_in[6];
    const float* Lw0 = (const float*)d_in[7];
    const float* Lb0 = (const float*)d_in[8];
    const float* Ws1 = (const float*)d_in[9];
    const float* Wd1 = (const float*)d_in[10];
    const float* as1 = (const float*)d_in[11];
    const float* ad1 = (const float*)d_in[12];
    const float* b1  = (const float*)d_in[13];
    const float* Lw1 = (const float*)d_in[14];
    const float* Lb1 = (const float*)d_in[15];
    const float* Wts = (const float*)d_in[16];
    const float* Wtd = (const float*)d_in[17];
    const float* ats = (const float*)d_in[18];
    const float* atd = (const float*)d_in[19];
    const float* bt  = (const float*)d_in[20];
    const int* edge_pp = (const int*)d_in[21];
    const int* pf_src  = (const int*)d_in[22];
    const int* pf_dst  = (const int*)d_in[23];
    float* out = (float*)d_out;

    char* wsp = (char*)d_ws;
    size_t off = 0;
    auto alloc = [&](size_t bytes) -> char* {
        char* p = wsp + off;
        off += (bytes + 255) & ~(size_t)255;
        return p;
    };
    ushort_t* hsb  = (ushort_t*)alloc(sizeof(ushort_t) * N_PANO * HID);   // 12.8 MB
    ushort_t* linb = (ushort_t*)alloc(sizeof(ushort_t) * N_PANO * HID);   // 12.8 MB (bf16 residual)
    uint_t* hh     = (uint_t*)alloc(sizeof(uint_t) * N_PANO * 64);        // 12.8 MB
    uint_t* hl     = (uint_t*)alloc(sizeof(uint_t) * N_PANO * 64);        // 12.8 MB
    ushort_t* hstb = (ushort_t*)alloc(sizeof(ushort_t) * N_PANO * OUT_C); // 6.4 MB
    int2* tmp_pp   = (int2*)alloc(sizeof(int2) * E_PP);                   // 6.4 MB
    float* es   = (float*)alloc(sizeof(float) * N_PANO);
    float* ed   = (float*)alloc(sizeof(float) * N_PANO);
    float* edt  = (float*)alloc(sizeof(float) * N_FP);
    float* wed0 = (float*)alloc(sizeof(float) * HID);
    float* wed1 = (float*)alloc(sizeof(float) * HID);
    float* wedt = (float*)alloc(sizeof(float) * OUT_C);
    ushort_t* s0h = (ushort_t*)alloc(sizeof(ushort_t) * 128 * 128);
    ushort_t* s0l = (ushort_t*)alloc(sizeof(ushort_t) * 128 * 128);
    ushort_t* l0h = (ushort_t*)alloc(sizeof(ushort_t) * 128 * 128);
    ushort_t* l0l = (ushort_t*)alloc(sizeof(ushort_t) * 128 * 128);
    ushort_t* s1h = (ushort_t*)alloc(sizeof(ushort_t) * 128 * 128);
    ushort_t* s1l = (ushort_t*)alloc(sizeof(ushort_t) * 128 * 128);
    ushort_t* l1h = (ushort_t*)alloc(sizeof(ushort_t) * 128 * 128);
    ushort_t* l1l = (ushort_t*)alloc(sizeof(ushort_t) * 128 * 128);
    ushort_t* tsh = (ushort_t*)alloc(sizeof(ushort_t) * 64 * 128);
    ushort_t* tsl = (ushort_t*)alloc(sizeof(ushort_t) * 64 * 128);
    int* cnt    = (int*)alloc(sizeof(int) * N_PANO);
    int* cur    = (int*)alloc(sizeof(int) * N_PANO);
    int* bsum   = (int*)alloc(sizeof(int) * 64);
    int* bcur   = (int*)alloc(sizeof(int) * NBKT * 16);   // padded: 1 counter / 64B line
    int* ptr_pp = (int*)alloc(sizeof(int) * (N_PANO + 1));
    int* col_pp = (int*)alloc(sizeof(int) * E_PP);
    int* ptr_pf = (int*)alloc(sizeof(int) * (N_FP + 1));
    int* col_pf = (int*)alloc(sizeof(int) * E_PF);

    const int* pp_src = edge_pp;
    const int* pp_dst = edge_pp + E_PP;

    // ---- CSR build (pp): count -> scan -> aggregated bucketed scatter ----
    {
        int nb = cdiv(N_PANO, 1024);
        zero_i32<<<cdiv(N_PANO, 256), 256, 0, stream>>>(cnt, N_PANO);
        count_k<<<cdiv(E_PP, 256), 256, 0, stream>>>(pp_dst, E_PP, cnt);
        scan_local<<<nb, 1024, 0, stream>>>(cnt, ptr_pp, bsum, N_PANO);
        scan_bsum<<<1, 64, 0, stream>>>(bsum, nb, &ptr_pp[N_PANO]);
        scan_add<<<nb, 1024, 0, stream>>>(ptr_pp, cur, bsum, N_PANO);
        bucket_init<<<1, 256, 0, stream>>>(ptr_pp, bcur);
        bucket_scatter_agg<<<cdiv(E_PP, EPB), 256, 0, stream>>>(pp_src, pp_dst, E_PP, bcur, tmp_pp);
        fine_scatter<<<cdiv(E_PP, 256), 256, 0, stream>>>(tmp_pp, E_PP, cur, col_pp);
    }
    // ---- CSR build (pf): small, simple scatter ----
    {
        int nb = cdiv(N_FP, 1024);
        zero_i32<<<cdiv(N_FP, 256), 256, 0, stream>>>(cnt, N_FP);
        count_k<<<cdiv(E_PF, 256), 256, 0, stream>>>(pf_dst, E_PF, cnt);
        scan_local<<<nb, 1024, 0, stream>>>(cnt, ptr_pf, bsum, N_FP);
        scan_bsum<<<1, 64, 0, stream>>>(bsum, nb, &ptr_pf[N_FP]);
        scan_add<<<nb, 1024, 0, stream>>>(ptr_pf, cur, bsum, N_FP);
        scatter_k<<<cdiv(E_PF, 256), 256, 0, stream>>>(pf_src, pf_dst, E_PF, cur, col_pf);
    }
    // ---- fold Wd @ a_d ; convert weights to fragment order ----
    wed_all<<<320, 64, 0, stream>>>(Wd0, ad0, Wd1, ad1, Wtd, atd, wed0, wed1, wedt);
    wconv<<<288, 256, 0, stream>>>(Ws0, Lw0, Ws1, Lw1, Wts,
                                   s0h, s0l, l0h, l0l, s1h, s1l, l1h, l1l, tsh, tsl);

    const int gemm_grid = cdiv(N_PANO, 128);

    // ---- layer 0 (fp32 input) ----
    gemm_mfma<128, true, true><<<gemm_grid, 256, 0, stream>>>(
        x_pano, nullptr, nullptr, s0h, s0l, l0h, l0l,
        hsb, linb, as0, es, wed0, ed, N_PANO);
    agg_pano5<<<cdiv(N_PANO, 4), 256, 0, stream>>>(ptr_pp, col_pp, es, ed, hsb, (const uint_t*)linb,
                                                   b0, Lb0, hh, hl, N_PANO);

    // ---- layer 1 (bf16 hi/lo input) ----
    gemm_mfma<128, true, false><<<gemm_grid, 256, 0, stream>>>(
        nullptr, (const ushort_t*)hh, (const ushort_t*)hl, s1h, s1l, l1h, l1l,
        hsb, linb, as1, es, wed1, ed, N_PANO);
    agg_pano5<<<cdiv(N_PANO, 4), 256, 0, stream>>>(ptr_pp, col_pp, es, ed, hsb, (const uint_t*)linb,
                                                   b1, Lb1, hh, hl, N_PANO);

    // ---- translate (pano -> footprint) ----
    gemm_mfma<64, false, false><<<gemm_grid, 256, 0, stream>>>(
        nullptr, (const ushort_t*)hh, (const ushort_t*)hl, tsh, tsl, nullptr, nullptr,
        hstb, nullptr, ats, es, nullptr, nullptr, N_PANO);
    matvec_k<64><<<cdiv(N_FP, 4), 256, 0, stream>>>(x_fp, wedt, edt, N_FP);
    agg_fp4<<<cdiv(N_FP, 4), 256, 0, stream>>>(ptr_pf, col_pf, es, edt, hstb, bt, out, N_FP);
}

// Round 9
// 329.463 us; speedup vs baseline: 2.4810x; 1.1045x over previous
//
#include <hip/hip_runtime.h>
#include <hip/hip_bf16.h>
#include <math.h>

#define N_PANO 50000
#define N_FP   10000
#define N_UNI  60000   // unified dst id-space: pano [0,50000), fp mapped to 50000+d
#define HID    128
#define OUT_C  64
#define E_PP   800000
#define E_PF   50000
#define E_UNI  850000
#define NBKT   235     // cdiv(N_UNI, 256) coarse buckets
#define EPB    4096    // edges per block in the aggregated coarse scatter

typedef unsigned short ushort_t;
typedef unsigned int uint_t;
typedef __attribute__((ext_vector_type(8))) short short8;
typedef __attribute__((ext_vector_type(4))) float f32x4;

static inline int cdiv(int a, int b) { return (a + b - 1) / b; }

__device__ inline ushort_t f2bf(float x) {
    __hip_bfloat16 h = __float2bfloat16(x);   // RNE
    return *reinterpret_cast<ushort_t*>(&h);
}
__device__ inline float bfu2f(ushort_t u) {
    return __uint_as_float(((uint_t)u) << 16);
}
__device__ inline f32x4 mfma16(short8 a, short8 b, f32x4 c) {
    return __builtin_amdgcn_mfma_f32_16x16x32_bf16(a, b, c, 0, 0, 0);
}

// ---------------- unified CSR build ----------------
__global__ __launch_bounds__(256) void zero_i32(int* p, int n) {
    int i = blockIdx.x * 256 + threadIdx.x;
    if (i < n) p[i] = 0;
}

// counts both edge sets into one 60000-entry histogram
__global__ __launch_bounds__(256) void count_uni(const int* __restrict__ pp_dst,
                                                 const int* __restrict__ pf_dst,
                                                 int* __restrict__ cnt) {
    int i = blockIdx.x * 256 + threadIdx.x;
    if (i < E_PP) atomicAdd(&cnt[pp_dst[i]], 1);
    else if (i < E_UNI) atomicAdd(&cnt[N_PANO + pf_dst[i - E_PP]], 1);
}

__global__ __launch_bounds__(1024) void scan_local(const int* __restrict__ cnt, int* __restrict__ ptr,
                                                   int* __restrict__ bsum, int n) {
    __shared__ int wsum[16];
    int tid = threadIdx.x, lane = tid & 63, wid = tid >> 6;
    int i = blockIdx.x * 1024 + tid;
    int v = (i < n) ? cnt[i] : 0;
    int incl = v;
    #pragma unroll
    for (int off = 1; off < 64; off <<= 1) {
        int t = __shfl_up(incl, off, 64);
        if (lane >= off) incl += t;
    }
    if (lane == 63) wsum[wid] = incl;
    __syncthreads();
    if (tid == 0) {
        int run = 0;
        #pragma unroll
        for (int w = 0; w < 16; ++w) { int t = wsum[w]; wsum[w] = run; run += t; }
        bsum[blockIdx.x] = run;
    }
    __syncthreads();
    int excl = wsum[wid] + incl - v;
    if (i < n) ptr[i] = excl;
}

__global__ __launch_bounds__(64) void scan_bsum(int* __restrict__ bsum, int nb, int* __restrict__ total_out) {
    int lane = threadIdx.x;
    int v = (lane < nb) ? bsum[lane] : 0;
    int incl = v;
    #pragma unroll
    for (int off = 1; off < 64; off <<= 1) {
        int t = __shfl_up(incl, off, 64);
        if (lane >= off) incl += t;
    }
    if (lane < nb) bsum[lane] = incl - v;
    if (lane == 63) *total_out = incl;
}

__global__ __launch_bounds__(1024) void scan_add(int* __restrict__ ptr, int* __restrict__ cur,
                                                 const int* __restrict__ bsum, int n) {
    int i = blockIdx.x * 1024 + threadIdx.x;
    if (i < n) {
        int v = ptr[i] + bsum[blockIdx.x];
        ptr[i] = v;
        cur[i] = v;
    }
}

// bcur padded: counter b at bcur[b*16] (one per 64-B line) — avoids cross-XCD
// same-line atomic serialization (round-6 lesson: 800k atomics on 13 lines = 450us)
__global__ __launch_bounds__(256) void bucket_init(const int* __restrict__ ptr, int* __restrict__ bcur) {
    int b = blockIdx.x * 256 + threadIdx.x;
    if (b < NBKT) bcur[b * 16] = ptr[b << 8];
}

// Block-aggregated coarse scatter over BOTH edge sets: LDS histogram -> one
// global atomic per (block,bucket) -> LDS-cursor placement.
__global__ __launch_bounds__(256) void bucket_scatter_uni(const int* __restrict__ pp_src,
                                                          const int* __restrict__ pp_dst,
                                                          const int* __restrict__ pf_src,
                                                          const int* __restrict__ pf_dst,
                                                          int* __restrict__ bcur, int2* __restrict__ tmp) {
    __shared__ int hist[NBKT];
    __shared__ int base[NBKT];
    const int tid = threadIdx.x;
    const int e0 = blockIdx.x * EPB;
    for (int t = tid; t < NBKT; t += 256) hist[t] = 0;
    __syncthreads();
    int d[16], s[16];
    #pragma unroll
    for (int u = 0; u < 16; ++u) {
        int e = e0 + u * 256 + tid;
        if (e < E_PP)       { d[u] = pp_dst[e];                s[u] = pp_src[e]; }
        else if (e < E_UNI) { d[u] = N_PANO + pf_dst[e - E_PP]; s[u] = pf_src[e - E_PP]; }
        else d[u] = -1;
        if (d[u] >= 0) atomicAdd(&hist[d[u] >> 8], 1);
    }
    __syncthreads();
    for (int t = tid; t < NBKT; t += 256) {
        int c = hist[t];
        base[t] = (c > 0) ? atomicAdd(&bcur[t * 16], c) : 0;
        hist[t] = 0;
    }
    __syncthreads();
    #pragma unroll
    for (int u = 0; u < 16; ++u) {
        if (d[u] >= 0) {
            int b = d[u] >> 8;
            int p = base[b] + atomicAdd(&hist[b], 1);
            tmp[p] = make_int2(s[u], d[u]);
        }
    }
}

__global__ __launch_bounds__(256) void fine_scatter(const int2* __restrict__ tmp, int E,
                                                    int* __restrict__ cur, int* __restrict__ col) {
    int i = blockIdx.x * 256 + threadIdx.x;
    if (i < E) {
        int2 e = tmp[i];
        int p = atomicAdd(&cur[e.y], 1);
        col[p] = e.x;                    // p lies in the same bucket window as i
    }
}

// ---------------- wed[i] = sum_j W[i][j]*a[j] for all three layers ----------------
__global__ __launch_bounds__(64) void wed_all(const float* __restrict__ Wd0, const float* __restrict__ ad0,
                                              const float* __restrict__ Wd1, const float* __restrict__ ad1,
                                              const float* __restrict__ Wtd, const float* __restrict__ atd,
                                              float* __restrict__ o0, float* __restrict__ o1,
                                              float* __restrict__ ot) {
    int bid = blockIdx.x, lane = threadIdx.x;
    const float* W; const float* a; float* o; int r, C;
    if (bid < 128)      { W = Wd0; a = ad0; o = o0; r = bid;       C = 128; }
    else if (bid < 256) { W = Wd1; a = ad1; o = o1; r = bid - 128; C = 128; }
    else                { W = Wtd; a = atd; o = ot; r = bid - 256; C = 64;  }
    float s = 0.f;
    for (int j = lane; j < C; j += 64) s += W[r * C + j] * a[j];
    #pragma unroll
    for (int off = 32; off; off >>= 1) s += __shfl_down(s, off, 64);
    if (lane == 0) o[r] = s;
}

// ---------------- weight -> bf16, permuted to MFMA B-fragment order ----------------
// Dest element: d = (((kc>>1)*NI*2) + ni*2 + (kc&1))*512 + l*8 + j
// src: W[k][C], n = ni*16+(l&15), k = kc*32+(l>>4)*8+j. Phase slab = linear copy.
__global__ __launch_bounds__(256) void wconv(const float* __restrict__ Ws0, const float* __restrict__ Lw0,
                                             const float* __restrict__ Ws1, const float* __restrict__ Lw1,
                                             const float* __restrict__ Wts,
                                             ushort_t* s0, ushort_t* l0, ushort_t* s1, ushort_t* l1,
                                             ushort_t* ts) {
    int i = blockIdx.x * 256 + threadIdx.x;
    const float* W; ushort_t* oh;
    int d, NIc, Cc;
    if (i < 65536) {
        int m = i >> 14; d = i & 16383;
        W = (m == 0) ? Ws0 : (m == 1) ? Lw0 : (m == 2) ? Ws1 : Lw1;
        oh = (m == 0) ? s0 : (m == 1) ? l0 : (m == 2) ? s1 : l1;
        NIc = 8; Cc = 128;
    } else if (i < 73728) {
        d = i - 65536; W = Wts; oh = ts;
        NIc = 4; Cc = 64;
    } else return;
    int j = d & 7, l = (d >> 3) & 63;
    int kcl = (d >> 9) & 1;
    int ni = (d >> 10) & (NIc - 1);
    int p = d >> (10 + (NIc == 8 ? 3 : 2));
    int kc = p * 2 + kcl;
    int n = ni * 16 + (l & 15);
    int k = kc * 32 + (l >> 4) * 8 + j;
    oh[d] = f2bf(W[k * Cc + n]);
}

// ---------------- bf16 MFMA GEMM, LDS-staged fragment-order weights ----------------
// Block: 4 waves x 128 rows; wave owns 32 rows. K=128 in 2 phases of 64.
// Y1 = X@W1 -> bf16 (+fused es = Y1.avec); DUAL: Y2 = X@W2 -> bf16; opt ed = X.wed.
template <int CN, bool DUAL, bool FP32IN>
__global__ __launch_bounds__(256, 2) void gemm_mfma(const float* __restrict__ Xf,
                                                 const ushort_t* __restrict__ Xh,
                                                 const ushort_t* __restrict__ W1, const ushort_t* __restrict__ W2,
                                                 ushort_t* __restrict__ Y1, ushort_t* __restrict__ Y2,
                                                 const float* __restrict__ avec, float* __restrict__ evec,
                                                 const float* __restrict__ wed, float* __restrict__ edv,
                                                 int N) {
    constexpr int NI = CN / 16;
    constexpr int NMAT = DUAL ? 2 : 1;
    constexpr int SLAB = NI * 1024;          // ushorts per matrix per phase
    __shared__ ushort_t Bsh[NMAT * SLAB];    // 32 KB dual / 8 KB single
    const int tid = threadIdx.x;
    const int w = tid >> 6, l = tid & 63;
    const int col = l & 15, q = l >> 4;
    const int row0 = blockIdx.x * 128 + w * 32;
    f32x4 acc1[2][NI];
    f32x4 acc2[2][DUAL ? NI : 1];
    #pragma unroll
    for (int m = 0; m < 2; ++m)
        #pragma unroll
        for (int ni = 0; ni < NI; ++ni)
            #pragma unroll
            for (int r = 0; r < 4; ++r) acc1[m][ni][r] = 0.f;
    if (DUAL) {
        #pragma unroll
        for (int m = 0; m < 2; ++m)
            #pragma unroll
            for (int ni = 0; ni < NI; ++ni)
                #pragma unroll
                for (int r = 0; r < 4; ++r) acc2[m][ni][r] = 0.f;
    }
    float ped[2] = {0.f, 0.f};

    #pragma unroll
    for (int p = 0; p < 2; ++p) {
        if (p) __syncthreads();
        {
            const uint4* src1 = (const uint4*)W1 + p * (SLAB / 8);
            uint4* dst1 = (uint4*)&Bsh[0];
            #pragma unroll
            for (int f = tid; f < SLAB / 8; f += 256) dst1[f] = src1[f];
            if (DUAL) {
                const uint4* src2 = (const uint4*)W2 + p * (SLAB / 8);
                uint4* dst2 = (uint4*)&Bsh[SLAB];
                #pragma unroll
                for (int f = tid; f < SLAB / 8; f += 256) dst2[f] = src2[f];
            }
        }
        __syncthreads();
        #pragma unroll
        for (int kcl = 0; kcl < 2; ++kcl) {
            const int kc = p * 2 + kcl;
            const int k0 = kc * 32 + q * 8;
            short8 Ah[2];
            #pragma unroll
            for (int m = 0; m < 2; ++m) {
                const int arow = row0 + m * 16 + col;
                if (FP32IN) {
                    float xv[8];
                    if (arow < N) {
                        float4 a0 = *(const float4*)&Xf[(size_t)arow * 128 + k0];
                        float4 a1 = *(const float4*)&Xf[(size_t)arow * 128 + k0 + 4];
                        xv[0] = a0.x; xv[1] = a0.y; xv[2] = a0.z; xv[3] = a0.w;
                        xv[4] = a1.x; xv[5] = a1.y; xv[6] = a1.z; xv[7] = a1.w;
                    } else {
                        #pragma unroll
                        for (int j = 0; j < 8; ++j) xv[j] = 0.f;
                    }
                    #pragma unroll
                    for (int j = 0; j < 8; ++j) Ah[m][j] = (short)f2bf(xv[j]);
                    if (wed) {
                        float4 w0 = *(const float4*)&wed[k0];
                        float4 w1 = *(const float4*)&wed[k0 + 4];
                        ped[m] += xv[0] * w0.x + xv[1] * w0.y + xv[2] * w0.z + xv[3] * w0.w
                                + xv[4] * w1.x + xv[5] * w1.y + xv[6] * w1.z + xv[7] * w1.w;
                    }
                } else {
                    if (arow < N) {
                        Ah[m] = *(const short8*)&Xh[(size_t)arow * 128 + k0];
                    } else {
                        #pragma unroll
                        for (int j = 0; j < 8; ++j) Ah[m][j] = 0;
                    }
                    if (wed) {
                        float4 w0 = *(const float4*)&wed[k0];
                        float4 w1 = *(const float4*)&wed[k0 + 4];
                        float wv[8] = {w0.x, w0.y, w0.z, w0.w, w1.x, w1.y, w1.z, w1.w};
                        #pragma unroll
                        for (int j = 0; j < 8; ++j)
                            ped[m] += bfu2f((ushort_t)Ah[m][j]) * wv[j];
                    }
                }
            }
            #pragma unroll
            for (int ni = 0; ni < NI; ++ni) {
                const int lb = ((ni * 2 + kcl) * 64 + l) * 8;
                short8 B1 = *(const short8*)&Bsh[lb];
                #pragma unroll
                for (int m = 0; m < 2; ++m) acc1[m][ni] = mfma16(Ah[m], B1, acc1[m][ni]);
                if (DUAL) {
                    short8 B2 = *(const short8*)&Bsh[SLAB + lb];
                    #pragma unroll
                    for (int m = 0; m < 2; ++m) acc2[m][ni] = mfma16(Ah[m], B2, acc2[m][ni]);
                }
            }
        }
    }

    // stores: C/D layout row=(q*4+r), col=l&15 per 16x16 tile
    #pragma unroll
    for (int m = 0; m < 2; ++m) {
        #pragma unroll
        for (int ni = 0; ni < NI; ++ni) {
            #pragma unroll
            for (int r = 0; r < 4; ++r) {
                int mrow = row0 + m * 16 + q * 4 + r;
                if (mrow < N) {
                    Y1[(size_t)mrow * CN + ni * 16 + col] = f2bf(acc1[m][ni][r]);
                    if (DUAL) Y2[(size_t)mrow * CN + ni * 16 + col] = f2bf(acc2[m][ni][r]);
                }
            }
        }
    }
    float av[NI];
    #pragma unroll
    for (int ni = 0; ni < NI; ++ni) av[ni] = avec[ni * 16 + col];
    #pragma unroll
    for (int m = 0; m < 2; ++m) {
        #pragma unroll
        for (int r = 0; r < 4; ++r) {
            float pp = 0.f;
            #pragma unroll
            for (int ni = 0; ni < NI; ++ni) pp += acc1[m][ni][r] * av[ni];
            pp += __shfl_xor(pp, 1, 64);
            pp += __shfl_xor(pp, 2, 64);
            pp += __shfl_xor(pp, 4, 64);
            pp += __shfl_xor(pp, 8, 64);
            int mrow = row0 + m * 16 + q * 4 + r;
            if (col == 0 && mrow < N) evec[mrow] = pp;
        }
    }
    if (wed) {
        #pragma unroll
        for (int m = 0; m < 2; ++m) {
            ped[m] += __shfl_xor(ped[m], 16, 64);
            ped[m] += __shfl_xor(ped[m], 32, 64);
            int arow = row0 + m * 16 + col;
            if (q == 0 && arow < N) edv[arow] = ped[m];
        }
    }
}

// ---------------- matvec (x_fp @ wedt), one wave per row ----------------
template <int K>
__global__ __launch_bounds__(256) void matvec_k(const float* __restrict__ X, const float* __restrict__ v,
                                                float* __restrict__ y, int N) {
    int lane = threadIdx.x & 63, wid = threadIdx.x >> 6;
    int node = blockIdx.x * 4 + wid;
    if (node >= N) return;
    float s = X[node * K + lane] * v[lane];
    if (K > 64) s += X[node * K + 64 + lane] * v[64 + lane];
    #pragma unroll
    for (int off = 32; off; off >>= 1) s += __shfl_down(s, off, 64);
    if (lane == 0) y[node] = s;
}

// ---------------- GAT aggregate (pano), phase-split, bf16 h out ----------------
__global__ __launch_bounds__(256) void agg_pano5(const int* __restrict__ ptr, const int* __restrict__ col,
                                                 const float* __restrict__ es, const float* __restrict__ ed,
                                                 const ushort_t* __restrict__ hsb, const uint_t* __restrict__ linb,
                                                 const float* __restrict__ b, const float* __restrict__ Lb,
                                                 uint_t* __restrict__ hh, int N) {
    int lane = threadIdx.x & 63, wid = threadIdx.x >> 6;
    int node = blockIdx.x * 4 + wid;
    if (node >= N) return;
    int beg = ptr[node], end = ptr[node + 1];
    float edn = ed[node];
    int ch = lane * 2;
    float ax = 0.f, ay = 0.f, denp = 0.f;
    for (int base = beg; base < end; base += 64) {
        int m = min(64, end - base);
        int s = 0;
        float wgt = 0.f;
        if (lane < m) {
            s = col[base + lane];
            float e = es[s] + edn;
            e = fmaxf(e, 0.2f * e);
            wgt = __expf(e);
        }
        denp += wgt;
        int u = 0;
        for (; u + 4 <= m; u += 4) {
            int s0 = __shfl(s, u, 64), s1 = __shfl(s, u + 1, 64);
            int s2 = __shfl(s, u + 2, 64), s3 = __shfl(s, u + 3, 64);
            float w0 = __shfl(wgt, u, 64), w1 = __shfl(wgt, u + 1, 64);
            float w2 = __shfl(wgt, u + 2, 64), w3 = __shfl(wgt, u + 3, 64);
            uint_t h0 = *(const uint_t*)&hsb[(size_t)s0 * 128 + ch];
            uint_t h1 = *(const uint_t*)&hsb[(size_t)s1 * 128 + ch];
            uint_t h2 = *(const uint_t*)&hsb[(size_t)s2 * 128 + ch];
            uint_t h3 = *(const uint_t*)&hsb[(size_t)s3 * 128 + ch];
            ax += w0 * __uint_as_float((h0 & 0xffffu) << 16);
            ay += w0 * __uint_as_float(h0 & 0xffff0000u);
            ax += w1 * __uint_as_float((h1 & 0xffffu) << 16);
            ay += w1 * __uint_as_float(h1 & 0xffff0000u);
            ax += w2 * __uint_as_float((h2 & 0xffffu) << 16);
            ay += w2 * __uint_as_float(h2 & 0xffff0000u);
            ax += w3 * __uint_as_float((h3 & 0xffffu) << 16);
            ay += w3 * __uint_as_float(h3 & 0xffff0000u);
        }
        for (; u < m; ++u) {
            int su = __shfl(s, u, 64);
            float wu = __shfl(wgt, u, 64);
            uint_t hv = *(const uint_t*)&hsb[(size_t)su * 128 + ch];
            ax += wu * __uint_as_float((hv & 0xffffu) << 16);
            ay += wu * __uint_as_float(hv & 0xffff0000u);
        }
    }
    float den = denp;
    #pragma unroll
    for (int off = 1; off < 64; off <<= 1) den += __shfl_xor(den, off, 64);
    float inv = (end > beg) ? (1.f / den) : 0.f;
    uint_t lv = linb[(size_t)node * 64 + lane];
    float lx = __uint_as_float((lv & 0xffffu) << 16);
    float ly = __uint_as_float(lv & 0xffff0000u);
    float2 bb = *(const float2*)&b[ch];
    float2 lb = *(const float2*)&Lb[ch];
    float ox = fmaxf(ax * inv + bb.x + lx + lb.x, 0.f);
    float oy = fmaxf(ay * inv + bb.y + ly + lb.y, 0.f);
    hh[(size_t)node * 64 + lane] = (uint_t)f2bf(ox) | ((uint_t)f2bf(oy) << 16);
}

// ---------------- translate aggregate (C=64), phase-split; ptr/col absolute ----------------
__global__ __launch_bounds__(256) void agg_fp4(const int* __restrict__ ptr, const int* __restrict__ col,
                                               const float* __restrict__ es, const float* __restrict__ ed,
                                               const ushort_t* __restrict__ hsb, const float* __restrict__ bt,
                                               float* __restrict__ out, int N) {
    int lane = threadIdx.x & 63, wid = threadIdx.x >> 6;
    int node = blockIdx.x * 4 + wid;
    if (node >= N) return;
    int beg = ptr[node], end = ptr[node + 1];
    float edn = ed[node];
    float acc = 0.f, denp = 0.f;
    for (int base = beg; base < end; base += 64) {
        int m = min(64, end - base);
        int s = 0;
        float wgt = 0.f;
        if (lane < m) {
            s = col[base + lane];
            float e = es[s] + edn;
            e = fmaxf(e, 0.2f * e);
            wgt = __expf(e);
        }
        denp += wgt;
        int u = 0;
        for (; u + 4 <= m; u += 4) {
            int s0 = __shfl(s, u, 64), s1 = __shfl(s, u + 1, 64);
            int s2 = __shfl(s, u + 2, 64), s3 = __shfl(s, u + 3, 64);
            float w0 = __shfl(wgt, u, 64), w1 = __shfl(wgt, u + 1, 64);
            float w2 = __shfl(wgt, u + 2, 64), w3 = __shfl(wgt, u + 3, 64);
            float h0 = bfu2f(hsb[(size_t)s0 * 64 + lane]);
            float h1 = bfu2f(hsb[(size_t)s1 * 64 + lane]);
            float h2 = bfu2f(hsb[(size_t)s2 * 64 + lane]);
            float h3 = bfu2f(hsb[(size_t)s3 * 64 + lane]);
            acc += w0 * h0 + w1 * h1 + w2 * h2 + w3 * h3;
        }
        for (; u < m; ++u) {
            int su = __shfl(s, u, 64);
            float wu = __shfl(wgt, u, 64);
            acc += wu * bfu2f(hsb[(size_t)su * 64 + lane]);
        }
    }
    float den = denp;
    #pragma unroll
    for (int off = 1; off < 64; off <<= 1) den += __shfl_xor(den, off, 64);
    float inv = (end > beg) ? (1.f / den) : 0.f;
    out[(size_t)node * 64 + lane] = acc * inv + bt[lane];
}

extern "C" void kernel_launch(void* const* d_in, const int* in_sizes, int n_in,
                              void* d_out, int out_size, void* d_ws, size_t ws_size,
                              hipStream_t stream) {
    const float* x_pano = (const float*)d_in[0];
    const float* x_fp   = (const float*)d_in[1];
    const float* Ws0 = (const float*)d_in[2];
    const float* Wd0 = (const float*)d_in[3];
    const float* as0 = (const float*)d_in[4];
    const float* ad0 = (const float*)d_in[5];
    const float* b0  = (const float*)d_in[6];
    const float* Lw0 = (const float*)d_in[7];
    const float* Lb0 = (const float*)d_in[8];
    const float* Ws1 = (const float*)d_in[9];
    const float* Wd1 = (const float*)d_in[10];
    const float* as1 = (const float*)d_in[11];
    const float* ad1 = (const float*)d_in[12];
    const float* b1  = (const float*)d_in[13];
    const float* Lw1 = (const float*)d_in[14];
    const float* Lb1 = (const float*)d_in[15];
    const float* Wts = (const float*)d_in[16];
    const float* Wtd = (const float*)d_in[17];
    const float* ats = (const float*)d_in[18];
    const float* atd = (const float*)d_in[19];
    const float* bt  = (const float*)d_in[20];
    const int* edge_pp = (const int*)d_in[21];
    const int* pf_src  = (const int*)d_in[22];
    const int* pf_dst  = (const int*)d_in[23];
    float* out = (float*)d_out;

    char* wsp = (char*)d_ws;
    size_t off = 0;
    auto alloc = [&](size_t bytes) -> char* {
        char* p = wsp + off;
        off += (bytes + 255) & ~(size_t)255;
        return p;
    };
    ushort_t* hsb  = (ushort_t*)alloc(sizeof(ushort_t) * N_PANO * HID);   // 12.8 MB
    ushort_t* linb = (ushort_t*)alloc(sizeof(ushort_t) * N_PANO * HID);   // 12.8 MB
    uint_t* hh     = (uint_t*)alloc(sizeof(uint_t) * N_PANO * 64);        // 12.8 MB (bf16 h, row-major pairs)
    ushort_t* hstb = (ushort_t*)alloc(sizeof(ushort_t) * N_PANO * OUT_C); // 6.4 MB
    int2* tmp_e    = (int2*)alloc(sizeof(int2) * E_UNI);                  // 6.8 MB
    float* es   = (float*)alloc(sizeof(float) * N_PANO);
    float* ed   = (float*)alloc(sizeof(float) * N_PANO);
    float* edt  = (float*)alloc(sizeof(float) * N_FP);
    float* wed0 = (float*)alloc(sizeof(float) * HID);
    float* wed1 = (float*)alloc(sizeof(float) * HID);
    float* wedt = (float*)alloc(sizeof(float) * OUT_C);
    ushort_t* s0 = (ushort_t*)alloc(sizeof(ushort_t) * 128 * 128);
    ushort_t* l0 = (ushort_t*)alloc(sizeof(ushort_t) * 128 * 128);
    ushort_t* s1 = (ushort_t*)alloc(sizeof(ushort_t) * 128 * 128);
    ushort_t* l1 = (ushort_t*)alloc(sizeof(ushort_t) * 128 * 128);
    ushort_t* ts = (ushort_t*)alloc(sizeof(ushort_t) * 64 * 128);
    int* cnt    = (int*)alloc(sizeof(int) * N_UNI);
    int* cur    = (int*)alloc(sizeof(int) * N_UNI);
    int* bsum   = (int*)alloc(sizeof(int) * 64);
    int* bcur   = (int*)alloc(sizeof(int) * NBKT * 16);
    int* P      = (int*)alloc(sizeof(int) * (N_UNI + 1));  // unified row_ptr; P[50000]==E_PP
    int* col_u  = (int*)alloc(sizeof(int) * E_UNI);

    const int* pp_src = edge_pp;
    const int* pp_dst = edge_pp + E_PP;

    // ---- unified CSR build (pp + pf in one pipeline) ----
    {
        int nb = cdiv(N_UNI, 1024);   // 59 blocks (<64, fits scan_bsum wave)
        zero_i32<<<cdiv(N_UNI, 256), 256, 0, stream>>>(cnt, N_UNI);
        count_uni<<<cdiv(E_UNI, 256), 256, 0, stream>>>(pp_dst, pf_dst, cnt);
        scan_local<<<nb, 1024, 0, stream>>>(cnt, P, bsum, N_UNI);
        scan_bsum<<<1, 64, 0, stream>>>(bsum, nb, &P[N_UNI]);
        scan_add<<<nb, 1024, 0, stream>>>(P, cur, bsum, N_UNI);
        bucket_init<<<1, 256, 0, stream>>>(P, bcur);
        bucket_scatter_uni<<<cdiv(E_UNI, EPB), 256, 0, stream>>>(pp_src, pp_dst, pf_src, pf_dst, bcur, tmp_e);
        fine_scatter<<<cdiv(E_UNI, 256), 256, 0, stream>>>(tmp_e, E_UNI, cur, col_u);
    }
    // ---- fold Wd @ a_d ; convert weights to bf16 fragment order ----
    wed_all<<<320, 64, 0, stream>>>(Wd0, ad0, Wd1, ad1, Wtd, atd, wed0, wed1, wedt);
    wconv<<<288, 256, 0, stream>>>(Ws0, Lw0, Ws1, Lw1, Wts, s0, l0, s1, l1, ts);

    const int gemm_grid = cdiv(N_PANO, 128);

    // ---- layer 0 (fp32 input) ----
    gemm_mfma<128, true, true><<<gemm_grid, 256, 0, stream>>>(
        x_pano, nullptr, s0, l0, hsb, linb, as0, es, wed0, ed, N_PANO);
    agg_pano5<<<cdiv(N_PANO, 4), 256, 0, stream>>>(P, col_u, es, ed, hsb, (const uint_t*)linb,
                                                   b0, Lb0, hh, N_PANO);

    // ---- layer 1 (bf16 input = hh) ----
    gemm_mfma<128, true, false><<<gemm_grid, 256, 0, stream>>>(
        nullptr, (const ushort_t*)hh, s1, l1, hsb, linb, as1, es, wed1, ed, N_PANO);
    agg_pano5<<<cdiv(N_PANO, 4), 256, 0, stream>>>(P, col_u, es, ed, hsb, (const uint_t*)linb,
                                                   b1, Lb1, hh, N_PANO);

    // ---- translate (pano -> footprint); pf ptr = P+50000 (absolute into col_u) ----
    gemm_mfma<64, false, false><<<gemm_grid, 256, 0, stream>>>(
        nullptr, (const ushort_t*)hh, ts, nullptr, hstb, nullptr, ats, es, nullptr, nullptr, N_PANO);
    matvec_k<64><<<cdiv(N_FP, 4), 256, 0, stream>>>(x_fp, wedt, edt, N_FP);
    agg_fp4<<<cdiv(N_FP, 4), 256, 0, stream>>>(P + N_PANO, col_u, es, edt, hstb, bt, out, N_FP);
}

// Round 10
// 282.253 us; speedup vs baseline: 2.8959x; 1.1673x over previous
//
#include <hip/hip_runtime.h>
#include <hip/hip_bf16.h>
#include <math.h>

#define N_PANO 50000
#define N_FP   10000
#define N_UNI  60000   // unified dst id-space: pano [0,50000), fp mapped to 50000+d
#define HID    128
#define OUT_C  64
#define E_PP   800000
#define E_PF   50000
#define E_UNI  850000
#define NBKT   235     // cdiv(N_UNI, 256) coarse buckets
#define EPB    4096    // edges per block in the aggregated coarse scatter

typedef unsigned short ushort_t;
typedef unsigned int uint_t;
typedef __attribute__((ext_vector_type(8))) short short8;
typedef __attribute__((ext_vector_type(4))) float f32x4;

static inline int cdiv(int a, int b) { return (a + b - 1) / b; }

__device__ inline ushort_t f2bf(float x) {
    __hip_bfloat16 h = __float2bfloat16(x);   // RNE
    return *reinterpret_cast<ushort_t*>(&h);
}
__device__ inline float bfu2f(ushort_t u) {
    return __uint_as_float(((uint_t)u) << 16);
}
__device__ inline float bflo(uint_t u) { return __uint_as_float((u & 0xffffu) << 16); }
__device__ inline float bfhi(uint_t u) { return __uint_as_float(u & 0xffff0000u); }
__device__ inline f32x4 mfma16(short8 a, short8 b, f32x4 c) {
    return __builtin_amdgcn_mfma_f32_16x16x32_bf16(a, b, c, 0, 0, 0);
}

// ---------------- CSR build (bucketed, LDS-sorted) ----------------
__global__ __launch_bounds__(256) void zero_i32(int* p, int n) {
    int i = blockIdx.x * 256 + threadIdx.x;
    if (i < n) p[i] = 0;
}

// coarse bucket histogram: LDS per-block, one global atomic per (block,bucket).
// bcnt padded: counter b at bcnt[b*16] (round-6 lesson: same-line cross-XCD
// atomics serialize at ~7ns; padding puts each counter on its own 64-B line).
__global__ __launch_bounds__(256) void bucket_count(const int* __restrict__ pp_dst,
                                                    const int* __restrict__ pf_dst,
                                                    int* __restrict__ bcnt) {
    __shared__ int hist[NBKT];
    const int tid = threadIdx.x;
    const int e0 = blockIdx.x * EPB;
    for (int t = tid; t < NBKT; t += 256) hist[t] = 0;
    __syncthreads();
    #pragma unroll
    for (int u = 0; u < EPB / 256; ++u) {
        int e = e0 + u * 256 + tid;
        int d = -1;
        if (e < E_PP) d = pp_dst[e];
        else if (e < E_UNI) d = N_PANO + pf_dst[e - E_PP];
        if (d >= 0) atomicAdd(&hist[d >> 8], 1);
    }
    __syncthreads();
    for (int t = tid; t < NBKT; t += 256)
        if (hist[t] > 0) atomicAdd(&bcnt[t * 16], hist[t]);
}

// one block: exclusive-scan the 235 bucket counts -> base[236]; init bcur cursors
__global__ __launch_bounds__(256) void bucket_scan(const int* __restrict__ bcnt,
                                                   int* __restrict__ base, int* __restrict__ bcur) {
    __shared__ int wsum[4];
    int tid = threadIdx.x, lane = tid & 63, wid = tid >> 6;
    int v = (tid < NBKT) ? bcnt[tid * 16] : 0;
    int incl = v;
    #pragma unroll
    for (int off = 1; off < 64; off <<= 1) {
        int t = __shfl_up(incl, off, 64);
        if (lane >= off) incl += t;
    }
    if (lane == 63) wsum[wid] = incl;
    __syncthreads();
    if (tid == 0) {
        int run = 0;
        #pragma unroll
        for (int w = 0; w < 4; ++w) { int t = wsum[w]; wsum[w] = run; run += t; }
    }
    __syncthreads();
    int excl = wsum[wid] + incl - v;
    if (tid < NBKT) { base[tid] = excl; bcur[tid * 16] = excl; }
    if (tid == NBKT) base[NBKT] = E_UNI;
}

// block-aggregated coarse scatter over both edge sets into bucket-sorted tmp
__global__ __launch_bounds__(256) void bucket_scatter_uni(const int* __restrict__ pp_src,
                                                          const int* __restrict__ pp_dst,
                                                          const int* __restrict__ pf_src,
                                                          const int* __restrict__ pf_dst,
                                                          int* __restrict__ bcur, int2* __restrict__ tmp) {
    __shared__ int hist[NBKT];
    __shared__ int base[NBKT];
    const int tid = threadIdx.x;
    const int e0 = blockIdx.x * EPB;
    for (int t = tid; t < NBKT; t += 256) hist[t] = 0;
    __syncthreads();
    int d[16], s[16];
    #pragma unroll
    for (int u = 0; u < 16; ++u) {
        int e = e0 + u * 256 + tid;
        if (e < E_PP)       { d[u] = pp_dst[e];                 s[u] = pp_src[e]; }
        else if (e < E_UNI) { d[u] = N_PANO + pf_dst[e - E_PP]; s[u] = pf_src[e - E_PP]; }
        else d[u] = -1;
        if (d[u] >= 0) atomicAdd(&hist[d[u] >> 8], 1);
    }
    __syncthreads();
    for (int t = tid; t < NBKT; t += 256) {
        int c = hist[t];
        base[t] = (c > 0) ? atomicAdd(&bcur[t * 16], c) : 0;
        hist[t] = 0;
    }
    __syncthreads();
    #pragma unroll
    for (int u = 0; u < 16; ++u) {
        if (d[u] >= 0) {
            int b = d[u] >> 8;
            int p = base[b] + atomicAdd(&hist[b], 1);
            tmp[p] = make_int2(s[u], d[u]);
        }
    }
}

// per-bucket counting sort in LDS: emits col (src, dst-sorted) and ptr directly
__global__ __launch_bounds__(256) void bucket_fine_sort(const int2* __restrict__ tmp,
                                                        const int* __restrict__ base,
                                                        int* __restrict__ ptr, int* __restrict__ col) {
    __shared__ int hist[256];
    __shared__ int wsum[4];
    const int b = blockIdx.x, tid = threadIdx.x, lane = tid & 63, wid = tid >> 6;
    const int B0 = base[b], B1 = base[b + 1];
    hist[tid] = 0;
    __syncthreads();
    for (int e = B0 + tid; e < B1; e += 256) atomicAdd(&hist[tmp[e].y & 255], 1);
    __syncthreads();
    int v = hist[tid];
    int incl = v;
    #pragma unroll
    for (int off = 1; off < 64; off <<= 1) {
        int t = __shfl_up(incl, off, 64);
        if (lane >= off) incl += t;
    }
    if (lane == 63) wsum[wid] = incl;
    __syncthreads();
    if (tid == 0) {
        int run = 0;
        #pragma unroll
        for (int w = 0; w < 4; ++w) { int t = wsum[w]; wsum[w] = run; run += t; }
    }
    __syncthreads();
    int excl = wsum[wid] + incl - v;
    int dg = b * 256 + tid;
    if (dg < N_UNI) ptr[dg] = B0 + excl;
    if (b == NBKT - 1 && tid == 0) ptr[N_UNI] = E_UNI;
    hist[tid] = excl;          // each thread rewrites only its own slot
    __syncthreads();
    for (int e = B0 + tid; e < B1; e += 256) {
        int2 ed = tmp[e];
        int p = B0 + atomicAdd(&hist[ed.y & 255], 1);
        col[p] = ed.x;
    }
}

// ---------------- wed[i] = sum_j W[i][j]*a[j] for all three layers ----------------
__global__ __launch_bounds__(64) void wed_all(const float* __restrict__ Wd0, const float* __restrict__ ad0,
                                              const float* __restrict__ Wd1, const float* __restrict__ ad1,
                                              const float* __restrict__ Wtd, const float* __restrict__ atd,
                                              float* __restrict__ o0, float* __restrict__ o1,
                                              float* __restrict__ ot) {
    int bid = blockIdx.x, lane = threadIdx.x;
    const float* W; const float* a; float* o; int r, C;
    if (bid < 128)      { W = Wd0; a = ad0; o = o0; r = bid;       C = 128; }
    else if (bid < 256) { W = Wd1; a = ad1; o = o1; r = bid - 128; C = 128; }
    else                { W = Wtd; a = atd; o = ot; r = bid - 256; C = 64;  }
    float s = 0.f;
    for (int j = lane; j < C; j += 64) s += W[r * C + j] * a[j];
    #pragma unroll
    for (int off = 32; off; off >>= 1) s += __shfl_down(s, off, 64);
    if (lane == 0) o[r] = s;
}

// ---------------- weight -> bf16, permuted to MFMA B-fragment order ----------------
__global__ __launch_bounds__(256) void wconv(const float* __restrict__ Ws0, const float* __restrict__ Lw0,
                                             const float* __restrict__ Ws1, const float* __restrict__ Lw1,
                                             const float* __restrict__ Wts,
                                             ushort_t* s0, ushort_t* l0, ushort_t* s1, ushort_t* l1,
                                             ushort_t* ts) {
    int i = blockIdx.x * 256 + threadIdx.x;
    const float* W; ushort_t* oh;
    int d, NIc, Cc;
    if (i < 65536) {
        int m = i >> 14; d = i & 16383;
        W = (m == 0) ? Ws0 : (m == 1) ? Lw0 : (m == 2) ? Ws1 : Lw1;
        oh = (m == 0) ? s0 : (m == 1) ? l0 : (m == 2) ? s1 : l1;
        NIc = 8; Cc = 128;
    } else if (i < 73728) {
        d = i - 65536; W = Wts; oh = ts;
        NIc = 4; Cc = 64;
    } else return;
    int j = d & 7, l = (d >> 3) & 63;
    int kcl = (d >> 9) & 1;
    int ni = (d >> 10) & (NIc - 1);
    int p = d >> (10 + (NIc == 8 ? 3 : 2));
    int kc = p * 2 + kcl;
    int n = ni * 16 + (l & 15);
    int k = kc * 32 + (l >> 4) * 8 + j;
    oh[d] = f2bf(W[k * Cc + n]);
}

// ---------------- bf16 MFMA GEMM, LDS-staged fragment-order weights ----------------
template <int CN, bool DUAL, bool FP32IN>
__global__ __launch_bounds__(256, 2) void gemm_mfma(const float* __restrict__ Xf,
                                                 const ushort_t* __restrict__ Xh,
                                                 const ushort_t* __restrict__ W1, const ushort_t* __restrict__ W2,
                                                 ushort_t* __restrict__ Y1, ushort_t* __restrict__ Y2,
                                                 const float* __restrict__ avec, float* __restrict__ evec,
                                                 const float* __restrict__ wed, float* __restrict__ edv,
                                                 int N) {
    constexpr int NI = CN / 16;
    constexpr int NMAT = DUAL ? 2 : 1;
    constexpr int SLAB = NI * 1024;          // ushorts per matrix per phase
    __shared__ ushort_t Bsh[NMAT * SLAB];    // 32 KB dual / 8 KB single
    const int tid = threadIdx.x;
    const int w = tid >> 6, l = tid & 63;
    const int col = l & 15, q = l >> 4;
    const int row0 = blockIdx.x * 128 + w * 32;
    f32x4 acc1[2][NI];
    f32x4 acc2[2][DUAL ? NI : 1];
    #pragma unroll
    for (int m = 0; m < 2; ++m)
        #pragma unroll
        for (int ni = 0; ni < NI; ++ni)
            #pragma unroll
            for (int r = 0; r < 4; ++r) acc1[m][ni][r] = 0.f;
    if (DUAL) {
        #pragma unroll
        for (int m = 0; m < 2; ++m)
            #pragma unroll
            for (int ni = 0; ni < NI; ++ni)
                #pragma unroll
                for (int r = 0; r < 4; ++r) acc2[m][ni][r] = 0.f;
    }
    float ped[2] = {0.f, 0.f};

    #pragma unroll
    for (int p = 0; p < 2; ++p) {
        if (p) __syncthreads();
        {
            const uint4* src1 = (const uint4*)W1 + p * (SLAB / 8);
            uint4* dst1 = (uint4*)&Bsh[0];
            #pragma unroll
            for (int f = tid; f < SLAB / 8; f += 256) dst1[f] = src1[f];
            if (DUAL) {
                const uint4* src2 = (const uint4*)W2 + p * (SLAB / 8);
                uint4* dst2 = (uint4*)&Bsh[SLAB];
                #pragma unroll
                for (int f = tid; f < SLAB / 8; f += 256) dst2[f] = src2[f];
            }
        }
        __syncthreads();
        #pragma unroll
        for (int kcl = 0; kcl < 2; ++kcl) {
            const int kc = p * 2 + kcl;
            const int k0 = kc * 32 + q * 8;
            short8 Ah[2];
            #pragma unroll
            for (int m = 0; m < 2; ++m) {
                const int arow = row0 + m * 16 + col;
                if (FP32IN) {
                    float xv[8];
                    if (arow < N) {
                        float4 a0 = *(const float4*)&Xf[(size_t)arow * 128 + k0];
                        float4 a1 = *(const float4*)&Xf[(size_t)arow * 128 + k0 + 4];
                        xv[0] = a0.x; xv[1] = a0.y; xv[2] = a0.z; xv[3] = a0.w;
                        xv[4] = a1.x; xv[5] = a1.y; xv[6] = a1.z; xv[7] = a1.w;
                    } else {
                        #pragma unroll
                        for (int j = 0; j < 8; ++j) xv[j] = 0.f;
                    }
                    #pragma unroll
                    for (int j = 0; j < 8; ++j) Ah[m][j] = (short)f2bf(xv[j]);
                    if (wed) {
                        float4 w0 = *(const float4*)&wed[k0];
                        float4 w1 = *(const float4*)&wed[k0 + 4];
                        ped[m] += xv[0] * w0.x + xv[1] * w0.y + xv[2] * w0.z + xv[3] * w0.w
                                + xv[4] * w1.x + xv[5] * w1.y + xv[6] * w1.z + xv[7] * w1.w;
                    }
                } else {
                    if (arow < N) {
                        Ah[m] = *(const short8*)&Xh[(size_t)arow * 128 + k0];
                    } else {
                        #pragma unroll
                        for (int j = 0; j < 8; ++j) Ah[m][j] = 0;
                    }
                    if (wed) {
                        float4 w0 = *(const float4*)&wed[k0];
                        float4 w1 = *(const float4*)&wed[k0 + 4];
                        float wv[8] = {w0.x, w0.y, w0.z, w0.w, w1.x, w1.y, w1.z, w1.w};
                        #pragma unroll
                        for (int j = 0; j < 8; ++j)
                            ped[m] += bfu2f((ushort_t)Ah[m][j]) * wv[j];
                    }
                }
            }
            #pragma unroll
            for (int ni = 0; ni < NI; ++ni) {
                const int lb = ((ni * 2 + kcl) * 64 + l) * 8;
                short8 B1 = *(const short8*)&Bsh[lb];
                #pragma unroll
                for (int m = 0; m < 2; ++m) acc1[m][ni] = mfma16(Ah[m], B1, acc1[m][ni]);
                if (DUAL) {
                    short8 B2 = *(const short8*)&Bsh[SLAB + lb];
                    #pragma unroll
                    for (int m = 0; m < 2; ++m) acc2[m][ni] = mfma16(Ah[m], B2, acc2[m][ni]);
                }
            }
        }
    }

    #pragma unroll
    for (int m = 0; m < 2; ++m) {
        #pragma unroll
        for (int ni = 0; ni < NI; ++ni) {
            #pragma unroll
            for (int r = 0; r < 4; ++r) {
                int mrow = row0 + m * 16 + q * 4 + r;
                if (mrow < N) {
                    Y1[(size_t)mrow * CN + ni * 16 + col] = f2bf(acc1[m][ni][r]);
                    if (DUAL) Y2[(size_t)mrow * CN + ni * 16 + col] = f2bf(acc2[m][ni][r]);
                }
            }
        }
    }
    float av[NI];
    #pragma unroll
    for (int ni = 0; ni < NI; ++ni) av[ni] = avec[ni * 16 + col];
    #pragma unroll
    for (int m = 0; m < 2; ++m) {
        #pragma unroll
        for (int r = 0; r < 4; ++r) {
            float pp = 0.f;
            #pragma unroll
            for (int ni = 0; ni < NI; ++ni) pp += acc1[m][ni][r] * av[ni];
            pp += __shfl_xor(pp, 1, 64);
            pp += __shfl_xor(pp, 2, 64);
            pp += __shfl_xor(pp, 4, 64);
            pp += __shfl_xor(pp, 8, 64);
            int mrow = row0 + m * 16 + q * 4 + r;
            if (col == 0 && mrow < N) evec[mrow] = pp;
        }
    }
    if (wed) {
        #pragma unroll
        for (int m = 0; m < 2; ++m) {
            ped[m] += __shfl_xor(ped[m], 16, 64);
            ped[m] += __shfl_xor(ped[m], 32, 64);
            int arow = row0 + m * 16 + col;
            if (q == 0 && arow < N) edv[arow] = ped[m];
        }
    }
}

// ---------------- matvec (x_fp @ wedt), one wave per row ----------------
template <int K>
__global__ __launch_bounds__(256) void matvec_k(const float* __restrict__ X, const float* __restrict__ v,
                                                float* __restrict__ y, int N) {
    int lane = threadIdx.x & 63, wid = threadIdx.x >> 6;
    int node = blockIdx.x * 4 + wid;
    if (node >= N) return;
    float s = X[node * K + lane] * v[lane];
    if (K > 64) s += X[node * K + 64 + lane] * v[64 + lane];
    #pragma unroll
    for (int off = 32; off; off >>= 1) s += __shfl_down(s, off, 64);
    if (lane == 0) y[node] = s;
}

// ---------------- GAT aggregate (pano): pair-packed phase-split ----------------
// Half-wave per edge: lanes 0-31 even edges, 32-63 odd edges; each lane covers
// 4 channels via one uint2 (8B) load -> 1 VMEM instr per 2 edges (512B utilized).
__global__ __launch_bounds__(256) void agg_pano6(const int* __restrict__ ptr, const int* __restrict__ col,
                                                 const float* __restrict__ es, const float* __restrict__ ed,
                                                 const ushort_t* __restrict__ hsb, const ushort_t* __restrict__ linb,
                                                 const float* __restrict__ b, const float* __restrict__ Lb,
                                                 uint_t* __restrict__ hh, int N) {
    int lane = threadIdx.x & 63, wid = threadIdx.x >> 6;
    int node = blockIdx.x * 4 + wid;
    if (node >= N) return;
    int beg = ptr[node], end = ptr[node + 1];
    float edn = ed[node];
    const int half = lane >> 5, hl = lane & 31;
    float a0 = 0.f, a1 = 0.f, a2 = 0.f, a3 = 0.f, denp = 0.f;
    for (int base = beg; base < end; base += 64) {
        int m = min(64, end - base);
        int s = 0;
        float wgt = 0.f;
        if (lane < m) {
            s = col[base + lane];
            float e = es[s] + edn;
            e = fmaxf(e, 0.2f * e);
            wgt = __expf(e);
        }
        denp += wgt;
        int mp = (m + 1) & ~1;
        int t = 0;
        for (; t + 8 <= mp; t += 8) {   // 4 pairs in flight; max shfl idx t+6+half <= mp-1 <= 63
            int i0 = t + half, i1 = t + 2 + half, i2 = t + 4 + half, i3 = t + 6 + half;
            int s0 = __shfl(s, i0, 64), s1 = __shfl(s, i1, 64);
            int s2 = __shfl(s, i2, 64), s3 = __shfl(s, i3, 64);
            float w0 = __shfl(wgt, i0, 64), w1 = __shfl(wgt, i1, 64);
            float w2 = __shfl(wgt, i2, 64), w3 = __shfl(wgt, i3, 64);
            uint2 h0 = *(const uint2*)&hsb[(size_t)s0 * 128 + hl * 4];
            uint2 h1 = *(const uint2*)&hsb[(size_t)s1 * 128 + hl * 4];
            uint2 h2 = *(const uint2*)&hsb[(size_t)s2 * 128 + hl * 4];
            uint2 h3 = *(const uint2*)&hsb[(size_t)s3 * 128 + hl * 4];
            a0 += w0 * bflo(h0.x) + w1 * bflo(h1.x) + w2 * bflo(h2.x) + w3 * bflo(h3.x);
            a1 += w0 * bfhi(h0.x) + w1 * bfhi(h1.x) + w2 * bfhi(h2.x) + w3 * bfhi(h3.x);
            a2 += w0 * bflo(h0.y) + w1 * bflo(h1.y) + w2 * bflo(h2.y) + w3 * bflo(h3.y);
            a3 += w0 * bfhi(h0.y) + w1 * bfhi(h1.y) + w2 * bfhi(h2.y) + w3 * bfhi(h3.y);
        }
        for (; t < mp; t += 2) {
            int i0 = t + half;
            int s0 = __shfl(s, i0, 64);
            float w0 = __shfl(wgt, i0, 64);
            uint2 h0 = *(const uint2*)&hsb[(size_t)s0 * 128 + hl * 4];
            a0 += w0 * bflo(h0.x);
            a1 += w0 * bfhi(h0.x);
            a2 += w0 * bflo(h0.y);
            a3 += w0 * bfhi(h0.y);
        }
    }
    // combine halves (even-edge + odd-edge partial sums live in opposite halves)
    a0 += __shfl_xor(a0, 32, 64);
    a1 += __shfl_xor(a1, 32, 64);
    a2 += __shfl_xor(a2, 32, 64);
    a3 += __shfl_xor(a3, 32, 64);
    float den = denp;
    #pragma unroll
    for (int off = 1; off < 64; off <<= 1) den += __shfl_xor(den, off, 64);
    float inv = (end > beg) ? (1.f / den) : 0.f;
    if (half == 0) {
        const ushort_t* lrow = linb + (size_t)node * 128;
        uint2 lv = *(const uint2*)&lrow[hl * 4];
        float4 bb = *(const float4*)&b[hl * 4];
        float4 lb4 = *(const float4*)&Lb[hl * 4];
        float o0 = fmaxf(a0 * inv + bb.x + bflo(lv.x) + lb4.x, 0.f);
        float o1 = fmaxf(a1 * inv + bb.y + bfhi(lv.x) + lb4.y, 0.f);
        float o2 = fmaxf(a2 * inv + bb.z + bflo(lv.y) + lb4.z, 0.f);
        float o3 = fmaxf(a3 * inv + bb.w + bfhi(lv.y) + lb4.w, 0.f);
        uint2 ov;
        ov.x = (uint_t)f2bf(o0) | ((uint_t)f2bf(o1) << 16);
        ov.y = (uint_t)f2bf(o2) | ((uint_t)f2bf(o3) << 16);
        *(uint2*)&hh[(size_t)node * 64 + hl * 2] = ov;
    }
}

// ---------------- translate aggregate (C=64), phase-split; ptr/col absolute ----------------
__global__ __launch_bounds__(256) void agg_fp4(const int* __restrict__ ptr, const int* __restrict__ col,
                                               const float* __restrict__ es, const float* __restrict__ ed,
                                               const ushort_t* __restrict__ hsb, const float* __restrict__ bt,
                                               float* __restrict__ out, int N) {
    int lane = threadIdx.x & 63, wid = threadIdx.x >> 6;
    int node = blockIdx.x * 4 + wid;
    if (node >= N) return;
    int beg = ptr[node], end = ptr[node + 1];
    float edn = ed[node];
    float acc = 0.f, denp = 0.f;
    for (int base = beg; base < end; base += 64) {
        int m = min(64, end - base);
        int s = 0;
        float wgt = 0.f;
        if (lane < m) {
            s = col[base + lane];
            float e = es[s] + edn;
            e = fmaxf(e, 0.2f * e);
            wgt = __expf(e);
        }
        denp += wgt;
        int u = 0;
        for (; u + 4 <= m; u += 4) {
            int s0 = __shfl(s, u, 64), s1 = __shfl(s, u + 1, 64);
            int s2 = __shfl(s, u + 2, 64), s3 = __shfl(s, u + 3, 64);
            float w0 = __shfl(wgt, u, 64), w1 = __shfl(wgt, u + 1, 64);
            float w2 = __shfl(wgt, u + 2, 64), w3 = __shfl(wgt, u + 3, 64);
            float h0 = bfu2f(hsb[(size_t)s0 * 64 + lane]);
            float h1 = bfu2f(hsb[(size_t)s1 * 64 + lane]);
            float h2 = bfu2f(hsb[(size_t)s2 * 64 + lane]);
            float h3 = bfu2f(hsb[(size_t)s3 * 64 + lane]);
            acc += w0 * h0 + w1 * h1 + w2 * h2 + w3 * h3;
        }
        for (; u < m; ++u) {
            int su = __shfl(s, u, 64);
            float wu = __shfl(wgt, u, 64);
            acc += wu * bfu2f(hsb[(size_t)su * 64 + lane]);
        }
    }
    float den = denp;
    #pragma unroll
    for (int off = 1; off < 64; off <<= 1) den += __shfl_xor(den, off, 64);
    float inv = (end > beg) ? (1.f / den) : 0.f;
    out[(size_t)node * 64 + lane] = acc * inv + bt[lane];
}

extern "C" void kernel_launch(void* const* d_in, const int* in_sizes, int n_in,
                              void* d_out, int out_size, void* d_ws, size_t ws_size,
                              hipStream_t stream) {
    const float* x_pano = (const float*)d_in[0];
    const float* x_fp   = (const float*)d_in[1];
    const float* Ws0 = (const float*)d_in[2];
    const float* Wd0 = (const float*)d_in[3];
    const float* as0 = (const float*)d_in[4];
    const float* ad0 = (const float*)d_in[5];
    const float* b0  = (const float*)d_in[6];
    const float* Lw0 = (const float*)d_in[7];
    const float* Lb0 = (const float*)d_in[8];
    const float* Ws1 = (const float*)d_in[9];
    const float* Wd1 = (const float*)d_in[10];
    const float* as1 = (const float*)d_in[11];
    const float* ad1 = (const float*)d_in[12];
    const float* b1  = (const float*)d_in[13];
    const float* Lw1 = (const float*)d_in[14];
    const float* Lb1 = (const float*)d_in[15];
    const float* Wts = (const float*)d_in[16];
    const float* Wtd = (const float*)d_in[17];
    const float* ats = (const float*)d_in[18];
    const float* atd = (const float*)d_in[19];
    const float* bt  = (const float*)d_in[20];
    const int* edge_pp = (const int*)d_in[21];
    const int* pf_src  = (const int*)d_in[22];
    const int* pf_dst  = (const int*)d_in[23];
    float* out = (float*)d_out;

    char* wsp = (char*)d_ws;
    size_t off = 0;
    auto alloc = [&](size_t bytes) -> char* {
        char* p = wsp + off;
        off += (bytes + 255) & ~(size_t)255;
        return p;
    };
    ushort_t* hsb  = (ushort_t*)alloc(sizeof(ushort_t) * N_PANO * HID);   // 12.8 MB
    ushort_t* linb = (ushort_t*)alloc(sizeof(ushort_t) * N_PANO * HID);   // 12.8 MB
    uint_t* hh     = (uint_t*)alloc(sizeof(uint_t) * N_PANO * 64);        // 12.8 MB (bf16 h)
    ushort_t* hstb = (ushort_t*)alloc(sizeof(ushort_t) * N_PANO * OUT_C); // 6.4 MB
    int2* tmp_e    = (int2*)alloc(sizeof(int2) * E_UNI);                  // 6.8 MB
    float* es   = (float*)alloc(sizeof(float) * N_PANO);
    float* ed   = (float*)alloc(sizeof(float) * N_PANO);
    float* edt  = (float*)alloc(sizeof(float) * N_FP);
    float* wed0 = (float*)alloc(sizeof(float) * HID);
    float* wed1 = (float*)alloc(sizeof(float) * HID);
    float* wedt = (float*)alloc(sizeof(float) * OUT_C);
    ushort_t* s0 = (ushort_t*)alloc(sizeof(ushort_t) * 128 * 128);
    ushort_t* l0 = (ushort_t*)alloc(sizeof(ushort_t) * 128 * 128);
    ushort_t* s1 = (ushort_t*)alloc(sizeof(ushort_t) * 128 * 128);
    ushort_t* l1 = (ushort_t*)alloc(sizeof(ushort_t) * 128 * 128);
    ushort_t* ts = (ushort_t*)alloc(sizeof(ushort_t) * 64 * 128);
    int* bcnt   = (int*)alloc(sizeof(int) * NBKT * 16);   // padded counters
    int* bcur   = (int*)alloc(sizeof(int) * NBKT * 16);   // padded cursors
    int* bbase  = (int*)alloc(sizeof(int) * (NBKT + 1));
    int* P      = (int*)alloc(sizeof(int) * (N_UNI + 1)); // unified row_ptr
    int* col_u  = (int*)alloc(sizeof(int) * E_UNI);

    const int* pp_src = edge_pp;
    const int* pp_dst = edge_pp + E_PP;

    // ---- unified CSR build: coarse count -> scan -> bucket scatter -> LDS fine sort ----
    zero_i32<<<cdiv(NBKT * 16, 256), 256, 0, stream>>>(bcnt, NBKT * 16);
    bucket_count<<<cdiv(E_UNI, EPB), 256, 0, stream>>>(pp_dst, pf_dst, bcnt);
    bucket_scan<<<1, 256, 0, stream>>>(bcnt, bbase, bcur);
    bucket_scatter_uni<<<cdiv(E_UNI, EPB), 256, 0, stream>>>(pp_src, pp_dst, pf_src, pf_dst, bcur, tmp_e);
    bucket_fine_sort<<<NBKT, 256, 0, stream>>>(tmp_e, bbase, P, col_u);

    // ---- fold Wd @ a_d ; convert weights to bf16 fragment order ----
    wed_all<<<320, 64, 0, stream>>>(Wd0, ad0, Wd1, ad1, Wtd, atd, wed0, wed1, wedt);
    wconv<<<288, 256, 0, stream>>>(Ws0, Lw0, Ws1, Lw1, Wts, s0, l0, s1, l1, ts);

    const int gemm_grid = cdiv(N_PANO, 128);

    // ---- layer 0 (fp32 input) ----
    gemm_mfma<128, true, true><<<gemm_grid, 256, 0, stream>>>(
        x_pano, nullptr, s0, l0, hsb, linb, as0, es, wed0, ed, N_PANO);
    agg_pano6<<<cdiv(N_PANO, 4), 256, 0, stream>>>(P, col_u, es, ed, hsb, linb, b0, Lb0, hh, N_PANO);

    // ---- layer 1 (bf16 input = hh) ----
    gemm_mfma<128, true, false><<<gemm_grid, 256, 0, stream>>>(
        nullptr, (const ushort_t*)hh, s1, l1, hsb, linb, as1, es, wed1, ed, N_PANO);
    agg_pano6<<<cdiv(N_PANO, 4), 256, 0, stream>>>(P, col_u, es, ed, hsb, linb, b1, Lb1, hh, N_PANO);

    // ---- translate (pano -> footprint); pf ptr = P+50000 (absolute into col_u) ----
    gemm_mfma<64, false, false><<<gemm_grid, 256, 0, stream>>>(
        nullptr, (const ushort_t*)hh, ts, nullptr, hstb, nullptr, ats, es, nullptr, nullptr, N_PANO);
    matvec_k<64><<<cdiv(N_FP, 4), 256, 0, stream>>>(x_fp, wedt, edt, N_FP);
    agg_fp4<<<cdiv(N_FP, 4), 256, 0, stream>>>(P + N_PANO, col_u, es, edt, hstb, bt, out, N_FP);
}

// Round 11
// 277.838 us; speedup vs baseline: 2.9420x; 1.0159x over previous
//
#include <hip/hip_runtime.h>
#include <hip/hip_bf16.h>
#include <math.h>

#define N_PANO 50000
#define N_FP   10000
#define N_UNI  60000   // unified dst id-space: pano [0,50000), fp mapped to 50000+d
#define HID    128
#define OUT_C  64
#define E_PP   800000
#define E_PF   50000
#define E_UNI  850000
#define NBKT   235     // cdiv(N_UNI, 256) coarse buckets
#define EPB    4096    // edges per block in the aggregated coarse scatter

typedef unsigned short ushort_t;
typedef unsigned int uint_t;
typedef __attribute__((ext_vector_type(8))) short short8;
typedef __attribute__((ext_vector_type(4))) float f32x4;

static inline int cdiv(int a, int b) { return (a + b - 1) / b; }

__device__ inline ushort_t f2bf(float x) {
    __hip_bfloat16 h = __float2bfloat16(x);   // RNE
    return *reinterpret_cast<ushort_t*>(&h);
}
__device__ inline float bfu2f(ushort_t u) {
    return __uint_as_float(((uint_t)u) << 16);
}
__device__ inline float bflo(uint_t u) { return __uint_as_float((u & 0xffffu) << 16); }
__device__ inline float bfhi(uint_t u) { return __uint_as_float(u & 0xffff0000u); }
__device__ inline f32x4 mfma16(short8 a, short8 b, f32x4 c) {
    return __builtin_amdgcn_mfma_f32_16x16x32_bf16(a, b, c, 0, 0, 0);
}

// ---------------- CSR build (bucketed, LDS-sorted) ----------------
__global__ __launch_bounds__(256) void zero_i32(int* p, int n) {
    int i = blockIdx.x * 256 + threadIdx.x;
    if (i < n) p[i] = 0;
}

// coarse bucket histogram: LDS per-block, one global atomic per (block,bucket).
// bcnt padded: counter b at bcnt[b*16] (round-6 lesson: same-line cross-XCD
// atomics serialize at ~7ns; padding puts each counter on its own 64-B line).
__global__ __launch_bounds__(256) void bucket_count(const int* __restrict__ pp_dst,
                                                    const int* __restrict__ pf_dst,
                                                    int* __restrict__ bcnt) {
    __shared__ int hist[NBKT];
    const int tid = threadIdx.x;
    const int e0 = blockIdx.x * EPB;
    for (int t = tid; t < NBKT; t += 256) hist[t] = 0;
    __syncthreads();
    #pragma unroll
    for (int u = 0; u < EPB / 256; ++u) {
        int e = e0 + u * 256 + tid;
        int d = -1;
        if (e < E_PP) d = pp_dst[e];
        else if (e < E_UNI) d = N_PANO + pf_dst[e - E_PP];
        if (d >= 0) atomicAdd(&hist[d >> 8], 1);
    }
    __syncthreads();
    for (int t = tid; t < NBKT; t += 256)
        if (hist[t] > 0) atomicAdd(&bcnt[t * 16], hist[t]);
}

// one block: exclusive-scan the 235 bucket counts -> base[236]; init bcur cursors
__global__ __launch_bounds__(256) void bucket_scan(const int* __restrict__ bcnt,
                                                   int* __restrict__ base, int* __restrict__ bcur) {
    __shared__ int wsum[4];
    int tid = threadIdx.x, lane = tid & 63, wid = tid >> 6;
    int v = (tid < NBKT) ? bcnt[tid * 16] : 0;
    int incl = v;
    #pragma unroll
    for (int off = 1; off < 64; off <<= 1) {
        int t = __shfl_up(incl, off, 64);
        if (lane >= off) incl += t;
    }
    if (lane == 63) wsum[wid] = incl;
    __syncthreads();
    if (tid == 0) {
        int run = 0;
        #pragma unroll
        for (int w = 0; w < 4; ++w) { int t = wsum[w]; wsum[w] = run; run += t; }
    }
    __syncthreads();
    int excl = wsum[wid] + incl - v;
    if (tid < NBKT) { base[tid] = excl; bcur[tid * 16] = excl; }
    if (tid == NBKT) base[NBKT] = E_UNI;
}

// block-aggregated coarse scatter over both edge sets into bucket-sorted tmp
__global__ __launch_bounds__(256) void bucket_scatter_uni(const int* __restrict__ pp_src,
                                                          const int* __restrict__ pp_dst,
                                                          const int* __restrict__ pf_src,
                                                          const int* __restrict__ pf_dst,
                                                          int* __restrict__ bcur, int2* __restrict__ tmp) {
    __shared__ int hist[NBKT];
    __shared__ int base[NBKT];
    const int tid = threadIdx.x;
    const int e0 = blockIdx.x * EPB;
    for (int t = tid; t < NBKT; t += 256) hist[t] = 0;
    __syncthreads();
    int d[16], s[16];
    #pragma unroll
    for (int u = 0; u < 16; ++u) {
        int e = e0 + u * 256 + tid;
        if (e < E_PP)       { d[u] = pp_dst[e];                 s[u] = pp_src[e]; }
        else if (e < E_UNI) { d[u] = N_PANO + pf_dst[e - E_PP]; s[u] = pf_src[e - E_PP]; }
        else d[u] = -1;
        if (d[u] >= 0) atomicAdd(&hist[d[u] >> 8], 1);
    }
    __syncthreads();
    for (int t = tid; t < NBKT; t += 256) {
        int c = hist[t];
        base[t] = (c > 0) ? atomicAdd(&bcur[t * 16], c) : 0;
        hist[t] = 0;
    }
    __syncthreads();
    #pragma unroll
    for (int u = 0; u < 16; ++u) {
        if (d[u] >= 0) {
            int b = d[u] >> 8;
            int p = base[b] + atomicAdd(&hist[b], 1);
            tmp[p] = make_int2(s[u], d[u]);
        }
    }
}

// per-bucket counting sort in LDS: emits col (src, dst-sorted) and ptr directly
__global__ __launch_bounds__(256) void bucket_fine_sort(const int2* __restrict__ tmp,
                                                        const int* __restrict__ base,
                                                        int* __restrict__ ptr, int* __restrict__ col) {
    __shared__ int hist[256];
    __shared__ int wsum[4];
    const int b = blockIdx.x, tid = threadIdx.x, lane = tid & 63, wid = tid >> 6;
    const int B0 = base[b], B1 = base[b + 1];
    hist[tid] = 0;
    __syncthreads();
    for (int e = B0 + tid; e < B1; e += 256) atomicAdd(&hist[tmp[e].y & 255], 1);
    __syncthreads();
    int v = hist[tid];
    int incl = v;
    #pragma unroll
    for (int off = 1; off < 64; off <<= 1) {
        int t = __shfl_up(incl, off, 64);
        if (lane >= off) incl += t;
    }
    if (lane == 63) wsum[wid] = incl;
    __syncthreads();
    if (tid == 0) {
        int run = 0;
        #pragma unroll
        for (int w = 0; w < 4; ++w) { int t = wsum[w]; wsum[w] = run; run += t; }
    }
    __syncthreads();
    int excl = wsum[wid] + incl - v;
    int dg = b * 256 + tid;
    if (dg < N_UNI) ptr[dg] = B0 + excl;
    if (b == NBKT - 1 && tid == 0) ptr[N_UNI] = E_UNI;
    hist[tid] = excl;          // each thread rewrites only its own slot
    __syncthreads();
    for (int e = B0 + tid; e < B1; e += 256) {
        int2 ed = tmp[e];
        int p = B0 + atomicAdd(&hist[ed.y & 255], 1);
        col[p] = ed.x;
    }
}

// ---------------- fused prep: weight bf16 fragment-permute + wed matvecs ----------------
__global__ __launch_bounds__(256) void prep_k(const float* __restrict__ Ws0, const float* __restrict__ Lw0,
                                              const float* __restrict__ Ws1, const float* __restrict__ Lw1,
                                              const float* __restrict__ Wts,
                                              const float* __restrict__ Wd0, const float* __restrict__ ad0,
                                              const float* __restrict__ Wd1, const float* __restrict__ ad1,
                                              const float* __restrict__ Wtd, const float* __restrict__ atd,
                                              ushort_t* s0, ushort_t* l0, ushort_t* s1, ushort_t* l1,
                                              ushort_t* ts,
                                              float* wed0, float* wed1, float* wedt) {
    const int blk = blockIdx.x, tid = threadIdx.x;
    if (blk < 288) {
        // wconv: W[k][C] -> bf16 in MFMA B-fragment order
        int i = blk * 256 + tid;
        const float* W; ushort_t* oh;
        int d, NIc, Cc;
        if (i < 65536) {
            int m = i >> 14; d = i & 16383;
            W = (m == 0) ? Ws0 : (m == 1) ? Lw0 : (m == 2) ? Ws1 : Lw1;
            oh = (m == 0) ? s0 : (m == 1) ? l0 : (m == 2) ? s1 : l1;
            NIc = 8; Cc = 128;
        } else if (i < 73728) {
            d = i - 65536; W = Wts; oh = ts;
            NIc = 4; Cc = 64;
        } else return;
        int j = d & 7, l = (d >> 3) & 63;
        int kcl = (d >> 9) & 1;
        int ni = (d >> 10) & (NIc - 1);
        int p = d >> (10 + (NIc == 8 ? 3 : 2));
        int kc = p * 2 + kcl;
        int n = ni * 16 + (l & 15);
        int k = kc * 32 + (l >> 4) * 8 + j;
        oh[d] = f2bf(W[k * Cc + n]);
    } else {
        // wed: one wave per row, 4 rows per block
        int r = (blk - 288) * 4 + (tid >> 6);
        int lane = tid & 63;
        const float* W; const float* a; float* o; int rr, C;
        if (r < 128)      { W = Wd0; a = ad0; o = wed0; rr = r;       C = 128; }
        else if (r < 256) { W = Wd1; a = ad1; o = wed1; rr = r - 128; C = 128; }
        else if (r < 320) { W = Wtd; a = atd; o = wedt; rr = r - 256; C = 64;  }
        else return;
        float s = 0.f;
        for (int j = lane; j < C; j += 64) s += W[rr * C + j] * a[j];
        #pragma unroll
        for (int off = 32; off; off >>= 1) s += __shfl_down(s, off, 64);
        if (lane == 0) o[rr] = s;
    }
}

// ---------------- bf16 MFMA GEMM, LDS-staged fragment-order weights ----------------
template <int CN, bool DUAL, bool FP32IN>
__global__ __launch_bounds__(256, 2) void gemm_mfma(const float* __restrict__ Xf,
                                                 const ushort_t* __restrict__ Xh,
                                                 const ushort_t* __restrict__ W1, const ushort_t* __restrict__ W2,
                                                 ushort_t* __restrict__ Y1, ushort_t* __restrict__ Y2,
                                                 const float* __restrict__ avec, float* __restrict__ evec,
                                                 const float* __restrict__ wed, float* __restrict__ edv,
                                                 int N) {
    constexpr int NI = CN / 16;
    constexpr int NMAT = DUAL ? 2 : 1;
    constexpr int SLAB = NI * 1024;          // ushorts per matrix per phase
    __shared__ ushort_t Bsh[NMAT * SLAB];    // 32 KB dual / 8 KB single
    const int tid = threadIdx.x;
    const int w = tid >> 6, l = tid & 63;
    const int col = l & 15, q = l >> 4;
    const int row0 = blockIdx.x * 128 + w * 32;
    f32x4 acc1[2][NI];
    f32x4 acc2[2][DUAL ? NI : 1];
    #pragma unroll
    for (int m = 0; m < 2; ++m)
        #pragma unroll
        for (int ni = 0; ni < NI; ++ni)
            #pragma unroll
            for (int r = 0; r < 4; ++r) acc1[m][ni][r] = 0.f;
    if (DUAL) {
        #pragma unroll
        for (int m = 0; m < 2; ++m)
            #pragma unroll
            for (int ni = 0; ni < NI; ++ni)
                #pragma unroll
                for (int r = 0; r < 4; ++r) acc2[m][ni][r] = 0.f;
    }
    float ped[2] = {0.f, 0.f};

    #pragma unroll
    for (int p = 0; p < 2; ++p) {
        if (p) __syncthreads();
        {
            const uint4* src1 = (const uint4*)W1 + p * (SLAB / 8);
            uint4* dst1 = (uint4*)&Bsh[0];
            #pragma unroll
            for (int f = tid; f < SLAB / 8; f += 256) dst1[f] = src1[f];
            if (DUAL) {
                const uint4* src2 = (const uint4*)W2 + p * (SLAB / 8);
                uint4* dst2 = (uint4*)&Bsh[SLAB];
                #pragma unroll
                for (int f = tid; f < SLAB / 8; f += 256) dst2[f] = src2[f];
            }
        }
        __syncthreads();
        #pragma unroll
        for (int kcl = 0; kcl < 2; ++kcl) {
            const int kc = p * 2 + kcl;
            const int k0 = kc * 32 + q * 8;
            short8 Ah[2];
            #pragma unroll
            for (int m = 0; m < 2; ++m) {
                const int arow = row0 + m * 16 + col;
                if (FP32IN) {
                    float xv[8];
                    if (arow < N) {
                        float4 a0 = *(const float4*)&Xf[(size_t)arow * 128 + k0];
                        float4 a1 = *(const float4*)&Xf[(size_t)arow * 128 + k0 + 4];
                        xv[0] = a0.x; xv[1] = a0.y; xv[2] = a0.z; xv[3] = a0.w;
                        xv[4] = a1.x; xv[5] = a1.y; xv[6] = a1.z; xv[7] = a1.w;
                    } else {
                        #pragma unroll
                        for (int j = 0; j < 8; ++j) xv[j] = 0.f;
                    }
                    #pragma unroll
                    for (int j = 0; j < 8; ++j) Ah[m][j] = (short)f2bf(xv[j]);
                    if (wed) {
                        float4 w0 = *(const float4*)&wed[k0];
                        float4 w1 = *(const float4*)&wed[k0 + 4];
                        ped[m] += xv[0] * w0.x + xv[1] * w0.y + xv[2] * w0.z + xv[3] * w0.w
                                + xv[4] * w1.x + xv[5] * w1.y + xv[6] * w1.z + xv[7] * w1.w;
                    }
                } else {
                    if (arow < N) {
                        Ah[m] = *(const short8*)&Xh[(size_t)arow * 128 + k0];
                    } else {
                        #pragma unroll
                        for (int j = 0; j < 8; ++j) Ah[m][j] = 0;
                    }
                    if (wed) {
                        float4 w0 = *(const float4*)&wed[k0];
                        float4 w1 = *(const float4*)&wed[k0 + 4];
                        float wv[8] = {w0.x, w0.y, w0.z, w0.w, w1.x, w1.y, w1.z, w1.w};
                        #pragma unroll
                        for (int j = 0; j < 8; ++j)
                            ped[m] += bfu2f((ushort_t)Ah[m][j]) * wv[j];
                    }
                }
            }
            #pragma unroll
            for (int ni = 0; ni < NI; ++ni) {
                const int lb = ((ni * 2 + kcl) * 64 + l) * 8;
                short8 B1 = *(const short8*)&Bsh[lb];
                #pragma unroll
                for (int m = 0; m < 2; ++m) acc1[m][ni] = mfma16(Ah[m], B1, acc1[m][ni]);
                if (DUAL) {
                    short8 B2 = *(const short8*)&Bsh[SLAB + lb];
                    #pragma unroll
                    for (int m = 0; m < 2; ++m) acc2[m][ni] = mfma16(Ah[m], B2, acc2[m][ni]);
                }
            }
        }
    }

    #pragma unroll
    for (int m = 0; m < 2; ++m) {
        #pragma unroll
        for (int ni = 0; ni < NI; ++ni) {
            #pragma unroll
            for (int r = 0; r < 4; ++r) {
                int mrow = row0 + m * 16 + q * 4 + r;
                if (mrow < N) {
                    Y1[(size_t)mrow * CN + ni * 16 + col] = f2bf(acc1[m][ni][r]);
                    if (DUAL) Y2[(size_t)mrow * CN + ni * 16 + col] = f2bf(acc2[m][ni][r]);
                }
            }
        }
    }
    float av[NI];
    #pragma unroll
    for (int ni = 0; ni < NI; ++ni) av[ni] = avec[ni * 16 + col];
    #pragma unroll
    for (int m = 0; m < 2; ++m) {
        #pragma unroll
        for (int r = 0; r < 4; ++r) {
            float pp = 0.f;
            #pragma unroll
            for (int ni = 0; ni < NI; ++ni) pp += acc1[m][ni][r] * av[ni];
            pp += __shfl_xor(pp, 1, 64);
            pp += __shfl_xor(pp, 2, 64);
            pp += __shfl_xor(pp, 4, 64);
            pp += __shfl_xor(pp, 8, 64);
            int mrow = row0 + m * 16 + q * 4 + r;
            if (col == 0 && mrow < N) evec[mrow] = pp;
        }
    }
    if (wed) {
        #pragma unroll
        for (int m = 0; m < 2; ++m) {
            ped[m] += __shfl_xor(ped[m], 16, 64);
            ped[m] += __shfl_xor(ped[m], 32, 64);
            int arow = row0 + m * 16 + col;
            if (q == 0 && arow < N) edv[arow] = ped[m];
        }
    }
}

// ---------------- GAT aggregate (pano): two nodes per wave, pair-packed ----------------
// Wave handles nodes A=blk*8+wid*2 and B=A+1 (interleaved chains -> 2x MLP).
// Phase 1 (per node): weights for up to 64 edges lane-parallel. Phase 2: half-wave
// per edge, uint2 (4-ch) loads. Epilogue: half 0 stores node A, half 1 node B.
__global__ __launch_bounds__(256) void agg_pano7(const int* __restrict__ ptr, const int* __restrict__ col,
                                                 const float* __restrict__ es, const float* __restrict__ ed,
                                                 const ushort_t* __restrict__ hsb, const ushort_t* __restrict__ linb,
                                                 const float* __restrict__ b, const float* __restrict__ Lb,
                                                 uint_t* __restrict__ hh, int N) {
    int lane = threadIdx.x & 63, wid = threadIdx.x >> 6;
    int nodeA = blockIdx.x * 8 + wid * 2;
    if (nodeA >= N) return;
    int nodeB = nodeA + 1;
    bool hasB = nodeB < N;
    int begA = ptr[nodeA], endA = ptr[nodeA + 1];
    int endB = hasB ? ptr[nodeB + 1] : endA;
    int begB = endA;   // nodeB = nodeA+1 -> contiguous CSR
    float ednA = ed[nodeA];
    float ednB = hasB ? ed[nodeB] : 0.f;
    const int half = lane >> 5, hl = lane & 31;
    float aA0 = 0.f, aA1 = 0.f, aA2 = 0.f, aA3 = 0.f, dA = 0.f;
    float aB0 = 0.f, aB1 = 0.f, aB2 = 0.f, aB3 = 0.f, dB = 0.f;
    int baseA = begA, baseB = begB;
    while (baseA < endA || baseB < endB) {
        int mA = endA - baseA; mA = mA < 0 ? 0 : (mA > 64 ? 64 : mA);
        int mB = endB - baseB; mB = mB < 0 ? 0 : (mB > 64 ? 64 : mB);
        int sA = 0, sB = 0;
        float wA = 0.f, wB = 0.f;
        if (lane < mA) {
            sA = col[baseA + lane];
            float e = es[sA] + ednA;
            e = fmaxf(e, 0.2f * e);
            wA = __expf(e);
        }
        if (lane < mB) {
            sB = col[baseB + lane];
            float e = es[sB] + ednB;
            e = fmaxf(e, 0.2f * e);
            wB = __expf(e);
        }
        dA += wA; dB += wB;
        // phase 2 A
        {
            int mp = (mA + 1) & ~1;
            int t = 0;
            for (; t + 8 <= mp; t += 8) {
                int i0 = t + half, i1 = t + 2 + half, i2 = t + 4 + half, i3 = t + 6 + half;
                int s0 = __shfl(sA, i0, 64), s1 = __shfl(sA, i1, 64);
                int s2 = __shfl(sA, i2, 64), s3 = __shfl(sA, i3, 64);
                float w0 = __shfl(wA, i0, 64), w1 = __shfl(wA, i1, 64);
                float w2 = __shfl(wA, i2, 64), w3 = __shfl(wA, i3, 64);
                uint2 h0 = *(const uint2*)&hsb[(size_t)s0 * 128 + hl * 4];
                uint2 h1 = *(const uint2*)&hsb[(size_t)s1 * 128 + hl * 4];
                uint2 h2 = *(const uint2*)&hsb[(size_t)s2 * 128 + hl * 4];
                uint2 h3 = *(const uint2*)&hsb[(size_t)s3 * 128 + hl * 4];
                aA0 += w0 * bflo(h0.x) + w1 * bflo(h1.x) + w2 * bflo(h2.x) + w3 * bflo(h3.x);
                aA1 += w0 * bfhi(h0.x) + w1 * bfhi(h1.x) + w2 * bfhi(h2.x) + w3 * bfhi(h3.x);
                aA2 += w0 * bflo(h0.y) + w1 * bflo(h1.y) + w2 * bflo(h2.y) + w3 * bflo(h3.y);
                aA3 += w0 * bfhi(h0.y) + w1 * bfhi(h1.y) + w2 * bfhi(h2.y) + w3 * bfhi(h3.y);
            }
            for (; t < mp; t += 2) {
                int i0 = t + half;
                int s0 = __shfl(sA, i0, 64);
                float w0 = __shfl(wA, i0, 64);
                uint2 h0 = *(const uint2*)&hsb[(size_t)s0 * 128 + hl * 4];
                aA0 += w0 * bflo(h0.x);
                aA1 += w0 * bfhi(h0.x);
                aA2 += w0 * bflo(h0.y);
                aA3 += w0 * bfhi(h0.y);
            }
        }
        // phase 2 B
        {
            int mp = (mB + 1) & ~1;
            int t = 0;
            for (; t + 8 <= mp; t += 8) {
                int i0 = t + half, i1 = t + 2 + half, i2 = t + 4 + half, i3 = t + 6 + half;
                int s0 = __shfl(sB, i0, 64), s1 = __shfl(sB, i1, 64);
                int s2 = __shfl(sB, i2, 64), s3 = __shfl(sB, i3, 64);
                float w0 = __shfl(wB, i0, 64), w1 = __shfl(wB, i1, 64);
                float w2 = __shfl(wB, i2, 64), w3 = __shfl(wB, i3, 64);
                uint2 h0 = *(const uint2*)&hsb[(size_t)s0 * 128 + hl * 4];
                uint2 h1 = *(const uint2*)&hsb[(size_t)s1 * 128 + hl * 4];
                uint2 h2 = *(const uint2*)&hsb[(size_t)s2 * 128 + hl * 4];
                uint2 h3 = *(const uint2*)&hsb[(size_t)s3 * 128 + hl * 4];
                aB0 += w0 * bflo(h0.x) + w1 * bflo(h1.x) + w2 * bflo(h2.x) + w3 * bflo(h3.x);
                aB1 += w0 * bfhi(h0.x) + w1 * bfhi(h1.x) + w2 * bfhi(h2.x) + w3 * bfhi(h3.x);
                aB2 += w0 * bflo(h0.y) + w1 * bflo(h1.y) + w2 * bflo(h2.y) + w3 * bflo(h3.y);
                aB3 += w0 * bfhi(h0.y) + w1 * bfhi(h1.y) + w2 * bfhi(h2.y) + w3 * bfhi(h3.y);
            }
            for (; t < mp; t += 2) {
                int i0 = t + half;
                int s0 = __shfl(sB, i0, 64);
                float w0 = __shfl(wB, i0, 64);
                uint2 h0 = *(const uint2*)&hsb[(size_t)s0 * 128 + hl * 4];
                aB0 += w0 * bflo(h0.x);
                aB1 += w0 * bfhi(h0.x);
                aB2 += w0 * bflo(h0.y);
                aB3 += w0 * bfhi(h0.y);
            }
        }
        baseA += 64; baseB += 64;
    }
    // combine halves (even/odd-edge partials live in opposite halves)
    aA0 += __shfl_xor(aA0, 32, 64); aA1 += __shfl_xor(aA1, 32, 64);
    aA2 += __shfl_xor(aA2, 32, 64); aA3 += __shfl_xor(aA3, 32, 64);
    aB0 += __shfl_xor(aB0, 32, 64); aB1 += __shfl_xor(aB1, 32, 64);
    aB2 += __shfl_xor(aB2, 32, 64); aB3 += __shfl_xor(aB3, 32, 64);
    #pragma unroll
    for (int off = 1; off < 64; off <<= 1) dA += __shfl_xor(dA, off, 64);
    #pragma unroll
    for (int off = 1; off < 64; off <<= 1) dB += __shfl_xor(dB, off, 64);
    float invA = (endA > begA) ? (1.f / dA) : 0.f;
    float invB = (endB > begB) ? (1.f / dB) : 0.f;
    // epilogue: half 0 stores node A, half 1 stores node B
    int node = half ? nodeB : nodeA;
    if (half == 0 || hasB) {
        float v0 = half ? aB0 : aA0, v1 = half ? aB1 : aA1;
        float v2 = half ? aB2 : aA2, v3 = half ? aB3 : aA3;
        float inv = half ? invB : invA;
        uint2 lv = *(const uint2*)&linb[(size_t)node * 128 + hl * 4];
        float4 bb = *(const float4*)&b[hl * 4];
        float4 lb4 = *(const float4*)&Lb[hl * 4];
        float o0 = fmaxf(v0 * inv + bb.x + bflo(lv.x) + lb4.x, 0.f);
        float o1 = fmaxf(v1 * inv + bb.y + bfhi(lv.x) + lb4.y, 0.f);
        float o2 = fmaxf(v2 * inv + bb.z + bflo(lv.y) + lb4.z, 0.f);
        float o3 = fmaxf(v3 * inv + bb.w + bfhi(lv.y) + lb4.w, 0.f);
        uint2 ov;
        ov.x = (uint_t)f2bf(o0) | ((uint_t)f2bf(o1) << 16);
        ov.y = (uint_t)f2bf(o2) | ((uint_t)f2bf(o3) << 16);
        *(uint2*)&hh[(size_t)node * 64 + hl * 2] = ov;
    }
}

// ---------------- translate aggregate (C=64), fused ed matvec; ptr/col absolute ----------------
__global__ __launch_bounds__(256) void agg_fp5(const int* __restrict__ ptr, const int* __restrict__ col,
                                               const float* __restrict__ es, const float* __restrict__ x_fp,
                                               const float* __restrict__ wedt,
                                               const ushort_t* __restrict__ hsb, const float* __restrict__ bt,
                                               float* __restrict__ out, int N) {
    int lane = threadIdx.x & 63, wid = threadIdx.x >> 6;
    int node = blockIdx.x * 4 + wid;
    if (node >= N) return;
    int beg = ptr[node], end = ptr[node + 1];
    // fused ed = x_fp[node,:] . wedt  (butterfly -> all lanes)
    float edn = x_fp[(size_t)node * 64 + lane] * wedt[lane];
    #pragma unroll
    for (int off = 1; off < 64; off <<= 1) edn += __shfl_xor(edn, off, 64);
    float acc = 0.f, denp = 0.f;
    for (int base = beg; base < end; base += 64) {
        int m = min(64, end - base);
        int s = 0;
        float wgt = 0.f;
        if (lane < m) {
            s = col[base + lane];
            float e = es[s] + edn;
            e = fmaxf(e, 0.2f * e);
            wgt = __expf(e);
        }
        denp += wgt;
        int u = 0;
        for (; u + 4 <= m; u += 4) {
            int s0 = __shfl(s, u, 64), s1 = __shfl(s, u + 1, 64);
            int s2 = __shfl(s, u + 2, 64), s3 = __shfl(s, u + 3, 64);
            float w0 = __shfl(wgt, u, 64), w1 = __shfl(wgt, u + 1, 64);
            float w2 = __shfl(wgt, u + 2, 64), w3 = __shfl(wgt, u + 3, 64);
            float h0 = bfu2f(hsb[(size_t)s0 * 64 + lane]);
            float h1 = bfu2f(hsb[(size_t)s1 * 64 + lane]);
            float h2 = bfu2f(hsb[(size_t)s2 * 64 + lane]);
            float h3 = bfu2f(hsb[(size_t)s3 * 64 + lane]);
            acc += w0 * h0 + w1 * h1 + w2 * h2 + w3 * h3;
        }
        for (; u < m; ++u) {
            int su = __shfl(s, u, 64);
            float wu = __shfl(wgt, u, 64);
            acc += wu * bfu2f(hsb[(size_t)su * 64 + lane]);
        }
    }
    float den = denp;
    #pragma unroll
    for (int off = 1; off < 64; off <<= 1) den += __shfl_xor(den, off, 64);
    float inv = (end > beg) ? (1.f / den) : 0.f;
    out[(size_t)node * 64 + lane] = acc * inv + bt[lane];
}

extern "C" void kernel_launch(void* const* d_in, const int* in_sizes, int n_in,
                              void* d_out, int out_size, void* d_ws, size_t ws_size,
                              hipStream_t stream) {
    const float* x_pano = (const float*)d_in[0];
    const float* x_fp   = (const float*)d_in[1];
    const float* Ws0 = (const float*)d_in[2];
    const float* Wd0 = (const float*)d_in[3];
    const float* as0 = (const float*)d_in[4];
    const float* ad0 = (const float*)d_in[5];
    const float* b0  = (const float*)d_in[6];
    const float* Lw0 = (const float*)d_in[7];
    const float* Lb0 = (const float*)d_in[8];
    const float* Ws1 = (const float*)d_in[9];
    const float* Wd1 = (const float*)d_in[10];
    const float* as1 = (const float*)d_in[11];
    const float* ad1 = (const float*)d_in[12];
    const float* b1  = (const float*)d_in[13];
    const float* Lw1 = (const float*)d_in[14];
    const float* Lb1 = (const float*)d_in[15];
    const float* Wts = (const float*)d_in[16];
    const float* Wtd = (const float*)d_in[17];
    const float* ats = (const float*)d_in[18];
    const float* atd = (const float*)d_in[19];
    const float* bt  = (const float*)d_in[20];
    const int* edge_pp = (const int*)d_in[21];
    const int* pf_src  = (const int*)d_in[22];
    const int* pf_dst  = (const int*)d_in[23];
    float* out = (float*)d_out;

    char* wsp = (char*)d_ws;
    size_t off = 0;
    auto alloc = [&](size_t bytes) -> char* {
        char* p = wsp + off;
        off += (bytes + 255) & ~(size_t)255;
        return p;
    };
    ushort_t* hsb  = (ushort_t*)alloc(sizeof(ushort_t) * N_PANO * HID);   // 12.8 MB
    ushort_t* linb = (ushort_t*)alloc(sizeof(ushort_t) * N_PANO * HID);   // 12.8 MB
    uint_t* hh     = (uint_t*)alloc(sizeof(uint_t) * N_PANO * 64);        // 12.8 MB (bf16 h)
    ushort_t* hstb = (ushort_t*)alloc(sizeof(ushort_t) * N_PANO * OUT_C); // 6.4 MB
    int2* tmp_e    = (int2*)alloc(sizeof(int2) * E_UNI);                  // 6.8 MB
    float* es   = (float*)alloc(sizeof(float) * N_PANO);
    float* ed   = (float*)alloc(sizeof(float) * N_PANO);
    float* wed0 = (float*)alloc(sizeof(float) * HID);
    float* wed1 = (float*)alloc(sizeof(float) * HID);
    float* wedt = (float*)alloc(sizeof(float) * OUT_C);
    ushort_t* s0 = (ushort_t*)alloc(sizeof(ushort_t) * 128 * 128);
    ushort_t* l0 = (ushort_t*)alloc(sizeof(ushort_t) * 128 * 128);
    ushort_t* s1 = (ushort_t*)alloc(sizeof(ushort_t) * 128 * 128);
    ushort_t* l1 = (ushort_t*)alloc(sizeof(ushort_t) * 128 * 128);
    ushort_t* ts = (ushort_t*)alloc(sizeof(ushort_t) * 64 * 128);
    int* bcnt   = (int*)alloc(sizeof(int) * NBKT * 16);   // padded counters
    int* bcur   = (int*)alloc(sizeof(int) * NBKT * 16);   // padded cursors
    int* bbase  = (int*)alloc(sizeof(int) * (NBKT + 1));
    int* P      = (int*)alloc(sizeof(int) * (N_UNI + 1)); // unified row_ptr
    int* col_u  = (int*)alloc(sizeof(int) * E_UNI);

    const int* pp_src = edge_pp;
    const int* pp_dst = edge_pp + E_PP;

    // ---- unified CSR build: coarse count -> scan -> bucket scatter -> LDS fine sort ----
    zero_i32<<<cdiv(NBKT * 16, 256), 256, 0, stream>>>(bcnt, NBKT * 16);
    bucket_count<<<cdiv(E_UNI, EPB), 256, 0, stream>>>(pp_dst, pf_dst, bcnt);
    bucket_scan<<<1, 256, 0, stream>>>(bcnt, bbase, bcur);
    bucket_scatter_uni<<<cdiv(E_UNI, EPB), 256, 0, stream>>>(pp_src, pp_dst, pf_src, pf_dst, bcur, tmp_e);
    bucket_fine_sort<<<NBKT, 256, 0, stream>>>(tmp_e, bbase, P, col_u);

    // ---- fused prep: weight fragment-permute + wed matvecs ----
    prep_k<<<368, 256, 0, stream>>>(Ws0, Lw0, Ws1, Lw1, Wts, Wd0, ad0, Wd1, ad1, Wtd, atd,
                                    s0, l0, s1, l1, ts, wed0, wed1, wedt);

    const int gemm_grid = cdiv(N_PANO, 128);

    // ---- layer 0 (fp32 input) ----
    gemm_mfma<128, true, true><<<gemm_grid, 256, 0, stream>>>(
        x_pano, nullptr, s0, l0, hsb, linb, as0, es, wed0, ed, N_PANO);
    agg_pano7<<<cdiv(N_PANO, 8), 256, 0, stream>>>(P, col_u, es, ed, hsb, linb, b0, Lb0, hh, N_PANO);

    // ---- layer 1 (bf16 input = hh) ----
    gemm_mfma<128, true, false><<<gemm_grid, 256, 0, stream>>>(
        nullptr, (const ushort_t*)hh, s1, l1, hsb, linb, as1, es, wed1, ed, N_PANO);
    agg_pano7<<<cdiv(N_PANO, 8), 256, 0, stream>>>(P, col_u, es, ed, hsb, linb, b1, Lb1, hh, N_PANO);

    // ---- translate (pano -> footprint); pf ptr = P+50000 (absolute into col_u) ----
    gemm_mfma<64, false, false><<<gemm_grid, 256, 0, stream>>>(
        nullptr, (const ushort_t*)hh, ts, nullptr, hstb, nullptr, ats, es, nullptr, nullptr, N_PANO);
    agg_fp5<<<cdiv(N_FP, 4), 256, 0, stream>>>(P + N_PANO, col_u, es, x_fp, wedt, hstb, bt, out, N_FP);
}

// Round 14
// 267.438 us; speedup vs baseline: 3.0564x; 1.0389x over previous
//
#include <hip/hip_runtime.h>
#include <hip/hip_bf16.h>
#include <math.h>

#define N_PANO 50000
#define N_FP   10000
#define N_UNI  60000   // unified dst id-space: pano [0,50000), fp mapped to 50000+d
#define HID    128
#define OUT_C  64
#define E_PP   800000
#define E_PF   50000
#define E_UNI  850000
#define NBKT   235     // cdiv(N_UNI, 256) coarse buckets
#define EPB    4096    // edges per tile in count/scatter
#define NT_CNT 208     // cdiv(E_UNI, EPB)

typedef unsigned short ushort_t;
typedef unsigned int uint_t;
typedef __attribute__((ext_vector_type(8))) short short8;
typedef __attribute__((ext_vector_type(4))) float f32x4;

static inline int cdiv(int a, int b) { return (a + b - 1) / b; }

__device__ inline ushort_t f2bf(float x) {
    __hip_bfloat16 h = __float2bfloat16(x);   // RNE
    return *reinterpret_cast<ushort_t*>(&h);
}
__device__ inline float bfu2f(ushort_t u) {
    return __uint_as_float(((uint_t)u) << 16);
}
__device__ inline float bflo(uint_t u) { return __uint_as_float((u & 0xffffu) << 16); }
__device__ inline float bfhi(uint_t u) { return __uint_as_float(u & 0xffff0000u); }
__device__ inline f32x4 mfma16(short8 a, short8 b, f32x4 c) {
    return __builtin_amdgcn_mfma_f32_16x16x32_bf16(a, b, c, 0, 0, 0);
}

// ---------------- CSR stage 1: per-tile partial counts + weight prep (merged) ----------------
// tiles 0..207: per-tile bucket histogram -> pcnt[b][tile]  (no atomics, no pre-zero)
// tiles 208..495: weight -> bf16 fragment-permute; tiles 496..575: wed matvecs
__global__ __launch_bounds__(256) void csr_count_prep(
        const int* __restrict__ pp_dst, const int* __restrict__ pf_dst,
        int* __restrict__ pcnt,
        const float* __restrict__ Ws0, const float* __restrict__ Lw0,
        const float* __restrict__ Ws1, const float* __restrict__ Lw1,
        const float* __restrict__ Wts,
        const float* __restrict__ Wd0, const float* __restrict__ ad0,
        const float* __restrict__ Wd1, const float* __restrict__ ad1,
        const float* __restrict__ Wtd, const float* __restrict__ atd,
        ushort_t* s0, ushort_t* l0, ushort_t* s1, ushort_t* l1, ushort_t* ts,
        float* wed0, float* wed1, float* wedt) {
    __shared__ int hist[NBKT];
    const int tile = blockIdx.x, tid = threadIdx.x;
    if (tile < NT_CNT) {
        for (int t = tid; t < NBKT; t += 256) hist[t] = 0;
        __syncthreads();
        const int e0 = tile * EPB;
        #pragma unroll
        for (int u = 0; u < 16; ++u) {
            int e = e0 + u * 256 + tid;
            int d = -1;
            if (e < E_PP) d = pp_dst[e];
            else if (e < E_UNI) d = N_PANO + pf_dst[e - E_PP];
            if (d >= 0) atomicAdd(&hist[d >> 8], 1);
        }
        __syncthreads();
        for (int t = tid; t < NBKT; t += 256) pcnt[t * NT_CNT + tile] = hist[t];
    } else if (tile < NT_CNT + 288) {
        int i = (tile - NT_CNT) * 256 + tid;
        const float* W; ushort_t* oh;
        int d, NIc, Cc;
        if (i < 65536) {
            int m = i >> 14; d = i & 16383;
            W = (m == 0) ? Ws0 : (m == 1) ? Lw0 : (m == 2) ? Ws1 : Lw1;
            oh = (m == 0) ? s0 : (m == 1) ? l0 : (m == 2) ? s1 : l1;
            NIc = 8; Cc = 128;
        } else if (i < 73728) {
            d = i - 65536; W = Wts; oh = ts;
            NIc = 4; Cc = 64;
        } else return;
        int j = d & 7, l = (d >> 3) & 63;
        int kcl = (d >> 9) & 1;
        int ni = (d >> 10) & (NIc - 1);
        int p = d >> (10 + (NIc == 8 ? 3 : 2));
        int kc = p * 2 + kcl;
        int n = ni * 16 + (l & 15);
        int k = kc * 32 + (l >> 4) * 8 + j;
        oh[d] = f2bf(W[k * Cc + n]);
    } else {
        int r = (tile - NT_CNT - 288) * 4 + (tid >> 6);
        int lane = tid & 63;
        const float* W; const float* a; float* o; int rr, C;
        if (r < 128)      { W = Wd0; a = ad0; o = wed0; rr = r;       C = 128; }
        else if (r < 256) { W = Wd1; a = ad1; o = wed1; rr = r - 128; C = 128; }
        else if (r < 320) { W = Wtd; a = atd; o = wedt; rr = r - 256; C = 64;  }
        else return;
        float s = 0.f;
        for (int j = lane; j < C; j += 64) s += W[rr * C + j] * a[j];
        #pragma unroll
        for (int off = 32; off; off >>= 1) s += __shfl_down(s, off, 64);
        if (lane == 0) o[rr] = s;
    }
}

// ---------------- CSR stage 2: per-bucket exclusive scan over tile-partials ----------------
__global__ __launch_bounds__(256) void csr_scan(const int* __restrict__ pcnt,
                                                int* __restrict__ pexc, int* __restrict__ btot) {
    __shared__ int wsum[4];
    const int b = blockIdx.x, tid = threadIdx.x, lane = tid & 63, wv = tid >> 6;
    int v = (tid < NT_CNT) ? pcnt[b * NT_CNT + tid] : 0;
    int incl = v;
    #pragma unroll
    for (int off = 1; off < 64; off <<= 1) {
        int t = __shfl_up(incl, off, 64);
        if (lane >= off) incl += t;
    }
    if (lane == 63) wsum[wv] = incl;
    __syncthreads();
    if (tid == 0) {
        int run = 0;
        #pragma unroll
        for (int w = 0; w < 4; ++w) { int t = wsum[w]; wsum[w] = run; run += t; }
    }
    __syncthreads();
    int excl = wsum[wv] + incl - v;
    if (tid < NT_CNT) pexc[b * NT_CNT + tid] = excl;
    if (tid == 255) btot[b] = excl;   // v==0 for tid>=208 -> excl(255)=bucket total
}

// ---------------- CSR stage 3: coarse scatter (globally atomic-free) ----------------
// Each block locally scans btot -> bbase, takes its tile's disjoint range per bucket
// (bbase[b]+pexc[b][tile]), places edges via LDS cursors. Block 0 publishes bbase.
__global__ __launch_bounds__(256) void csr_scatter(const int* __restrict__ pp_src,
                                                   const int* __restrict__ pp_dst,
                                                   const int* __restrict__ pf_src,
                                                   const int* __restrict__ pf_dst,
                                                   const int* __restrict__ pexc,
                                                   const int* __restrict__ btot,
                                                   int* __restrict__ bbase_out,
                                                   int2* __restrict__ tmp) {
    __shared__ int base2[NBKT];
    __shared__ int cur[NBKT];
    __shared__ int wsum[4];
    const int tile = blockIdx.x, tid = threadIdx.x, lane = tid & 63, wv = tid >> 6;
    // local exclusive scan of btot -> bbase
    int v = (tid < NBKT) ? btot[tid] : 0;
    int incl = v;
    #pragma unroll
    for (int off = 1; off < 64; off <<= 1) {
        int t = __shfl_up(incl, off, 64);
        if (lane >= off) incl += t;
    }
    if (lane == 63) wsum[wv] = incl;
    __syncthreads();
    if (tid == 0) {
        int run = 0;
        #pragma unroll
        for (int w = 0; w < 4; ++w) { int t = wsum[w]; wsum[w] = run; run += t; }
    }
    __syncthreads();
    int excl = wsum[wv] + incl - v;
    if (tid < NBKT) {
        base2[tid] = excl + pexc[tid * NT_CNT + tile];
        cur[tid] = 0;
        if (tile == 0) bbase_out[tid] = excl;
    }
    if (tile == 0 && tid == 0) bbase_out[NBKT] = E_UNI;
    __syncthreads();
    const int e0 = tile * EPB;
    #pragma unroll
    for (int u = 0; u < 16; ++u) {
        int e = e0 + u * 256 + tid;
        int d = -1, s = 0;
        if (e < E_PP)       { d = pp_dst[e];                 s = pp_src[e]; }
        else if (e < E_UNI) { d = N_PANO + pf_dst[e - E_PP]; s = pf_src[e - E_PP]; }
        if (d >= 0) {
            int b = d >> 8;
            int p = base2[b] + atomicAdd(&cur[b], 1);
            tmp[p] = make_int2(s, d);
        }
    }
}

// ---------------- CSR stage 4: per-bucket counting sort in LDS -> P, col ----------------
__global__ __launch_bounds__(256) void csr_sort(const int2* __restrict__ tmp,
                                                const int* __restrict__ bbase,
                                                int* __restrict__ ptr, int* __restrict__ col) {
    __shared__ int hist[256];
    __shared__ int wsum[4];
    const int b = blockIdx.x, tid = threadIdx.x, lane = tid & 63, wv = tid >> 6;
    const int B0 = bbase[b], B1 = bbase[b + 1];
    hist[tid] = 0;
    __syncthreads();
    for (int e = B0 + tid; e < B1; e += 256) atomicAdd(&hist[tmp[e].y & 255], 1);
    __syncthreads();
    int v = hist[tid];
    int incl = v;
    #pragma unroll
    for (int off = 1; off < 64; off <<= 1) {
        int t = __shfl_up(incl, off, 64);
        if (lane >= off) incl += t;
    }
    if (lane == 63) wsum[wv] = incl;
    __syncthreads();
    if (tid == 0) {
        int run = 0;
        #pragma unroll
        for (int w = 0; w < 4; ++w) { int t = wsum[w]; wsum[w] = run; run += t; }
    }
    __syncthreads();
    int excl = wsum[wv] + incl - v;
    int dg = b * 256 + tid;
    if (dg < N_UNI) ptr[dg] = B0 + excl;
    if (b == NBKT - 1 && tid == 0) ptr[N_UNI] = E_UNI;
    hist[tid] = excl;
    __syncthreads();
    for (int e = B0 + tid; e < B1; e += 256) {
        int2 ed2 = tmp[e];
        int p = B0 + atomicAdd(&hist[ed2.y & 255], 1);
        col[p] = ed2.x;
    }
}

// ---------------- bf16 MFMA GEMM, LDS-staged fragment-order weights (R11, verified) ----------------
template <int CN, bool DUAL, bool FP32IN>
__global__ __launch_bounds__(256, 2) void gemm_mfma(const float* __restrict__ Xf,
                                                 const ushort_t* __restrict__ Xh,
                                                 const ushort_t* __restrict__ W1, const ushort_t* __restrict__ W2,
                                                 ushort_t* __restrict__ Y1, ushort_t* __restrict__ Y2,
                                                 const float* __restrict__ avec, float* __restrict__ evec,
                                                 const float* __restrict__ wed, float* __restrict__ edv,
                                                 int N) {
    constexpr int NI = CN / 16;
    constexpr int NMAT = DUAL ? 2 : 1;
    constexpr int SLAB = NI * 1024;
    __shared__ ushort_t Bsh[NMAT * SLAB];
    const int tid = threadIdx.x;
    const int w = tid >> 6, l = tid & 63;
    const int col = l & 15, q = l >> 4;
    const int row0 = blockIdx.x * 128 + w * 32;
    f32x4 acc1[2][NI];
    f32x4 acc2[2][DUAL ? NI : 1];
    #pragma unroll
    for (int m = 0; m < 2; ++m)
        #pragma unroll
        for (int ni = 0; ni < NI; ++ni)
            #pragma unroll
            for (int r = 0; r < 4; ++r) acc1[m][ni][r] = 0.f;
    if (DUAL) {
        #pragma unroll
        for (int m = 0; m < 2; ++m)
            #pragma unroll
            for (int ni = 0; ni < NI; ++ni)
                #pragma unroll
                for (int r = 0; r < 4; ++r) acc2[m][ni][r] = 0.f;
    }
    float ped[2] = {0.f, 0.f};

    #pragma unroll
    for (int p = 0; p < 2; ++p) {
        if (p) __syncthreads();
        {
            const uint4* src1 = (const uint4*)W1 + p * (SLAB / 8);
            uint4* dst1 = (uint4*)&Bsh[0];
            #pragma unroll
            for (int f = tid; f < SLAB / 8; f += 256) dst1[f] = src1[f];
            if (DUAL) {
                const uint4* src2 = (const uint4*)W2 + p * (SLAB / 8);
                uint4* dst2 = (uint4*)&Bsh[SLAB];
                #pragma unroll
                for (int f = tid; f < SLAB / 8; f += 256) dst2[f] = src2[f];
            }
        }
        __syncthreads();
        #pragma unroll
        for (int kcl = 0; kcl < 2; ++kcl) {
            const int kc = p * 2 + kcl;
            const int k0 = kc * 32 + q * 8;
            short8 Ah[2];
            #pragma unroll
            for (int m = 0; m < 2; ++m) {
                const int arow = row0 + m * 16 + col;
                if (FP32IN) {
                    float xv[8];
                    if (arow < N) {
                        float4 a0 = *(const float4*)&Xf[(size_t)arow * 128 + k0];
                        float4 a1 = *(const float4*)&Xf[(size_t)arow * 128 + k0 + 4];
                        xv[0] = a0.x; xv[1] = a0.y; xv[2] = a0.z; xv[3] = a0.w;
                        xv[4] = a1.x; xv[5] = a1.y; xv[6] = a1.z; xv[7] = a1.w;
                    } else {
                        #pragma unroll
                        for (int j = 0; j < 8; ++j) xv[j] = 0.f;
                    }
                    #pragma unroll
                    for (int j = 0; j < 8; ++j) Ah[m][j] = (short)f2bf(xv[j]);
                    if (wed) {
                        float4 w0 = *(const float4*)&wed[k0];
                        float4 w1 = *(const float4*)&wed[k0 + 4];
                        ped[m] += xv[0] * w0.x + xv[1] * w0.y + xv[2] * w0.z + xv[3] * w0.w
                                + xv[4] * w1.x + xv[5] * w1.y + xv[6] * w1.z + xv[7] * w1.w;
                    }
                } else {
                    if (arow < N) {
                        Ah[m] = *(const short8*)&Xh[(size_t)arow * 128 + k0];
                    } else {
                        #pragma unroll
                        for (int j = 0; j < 8; ++j) Ah[m][j] = 0;
                    }
                    if (wed) {
                        float4 w0 = *(const float4*)&wed[k0];
                        float4 w1 = *(const float4*)&wed[k0 + 4];
                        float wv[8] = {w0.x, w0.y, w0.z, w0.w, w1.x, w1.y, w1.z, w1.w};
                        #pragma unroll
                        for (int j = 0; j < 8; ++j)
                            ped[m] += bfu2f((ushort_t)Ah[m][j]) * wv[j];
                    }
                }
            }
            #pragma unroll
            for (int ni = 0; ni < NI; ++ni) {
                const int lb = ((ni * 2 + kcl) * 64 + l) * 8;
                short8 B1 = *(const short8*)&Bsh[lb];
                #pragma unroll
                for (int m = 0; m < 2; ++m) acc1[m][ni] = mfma16(Ah[m], B1, acc1[m][ni]);
                if (DUAL) {
                    short8 B2 = *(const short8*)&Bsh[SLAB + lb];
                    #pragma unroll
                    for (int m = 0; m < 2; ++m) acc2[m][ni] = mfma16(Ah[m], B2, acc2[m][ni]);
                }
            }
        }
    }

    #pragma unroll
    for (int m = 0; m < 2; ++m) {
        #pragma unroll
        for (int ni = 0; ni < NI; ++ni) {
            #pragma unroll
            for (int r = 0; r < 4; ++r) {
                int mrow = row0 + m * 16 + q * 4 + r;
                if (mrow < N) {
                    Y1[(size_t)mrow * CN + ni * 16 + col] = f2bf(acc1[m][ni][r]);
                    if (DUAL) Y2[(size_t)mrow * CN + ni * 16 + col] = f2bf(acc2[m][ni][r]);
                }
            }
        }
    }
    float av[NI];
    #pragma unroll
    for (int ni = 0; ni < NI; ++ni) av[ni] = avec[ni * 16 + col];
    #pragma unroll
    for (int m = 0; m < 2; ++m) {
        #pragma unroll
        for (int r = 0; r < 4; ++r) {
            float pp = 0.f;
            #pragma unroll
            for (int ni = 0; ni < NI; ++ni) pp += acc1[m][ni][r] * av[ni];
            pp += __shfl_xor(pp, 1, 64);
            pp += __shfl_xor(pp, 2, 64);
            pp += __shfl_xor(pp, 4, 64);
            pp += __shfl_xor(pp, 8, 64);
            int mrow = row0 + m * 16 + q * 4 + r;
            if (col == 0 && mrow < N) evec[mrow] = pp;
        }
    }
    if (wed) {
        #pragma unroll
        for (int m = 0; m < 2; ++m) {
            ped[m] += __shfl_xor(ped[m], 16, 64);
            ped[m] += __shfl_xor(ped[m], 32, 64);
            int arow = row0 + m * 16 + col;
            if (q == 0 && arow < N) edv[arow] = ped[m];
        }
    }
}

// ---------------- GAT aggregate (pano): two nodes per wave, pair-packed (R11, verified) ----------------
__global__ __launch_bounds__(256) void agg_pano7(const int* __restrict__ ptr, const int* __restrict__ col,
                                                 const float* __restrict__ es, const float* __restrict__ ed,
                                                 const ushort_t* __restrict__ hsb, const ushort_t* __restrict__ linb,
                                                 const float* __restrict__ b, const float* __restrict__ Lb,
                                                 uint_t* __restrict__ hh, int N) {
    int lane = threadIdx.x & 63, wid = threadIdx.x >> 6;
    int nodeA = blockIdx.x * 8 + wid * 2;
    if (nodeA >= N) return;
    int nodeB = nodeA + 1;
    bool hasB = nodeB < N;
    int begA = ptr[nodeA], endA = ptr[nodeA + 1];
    int endB = hasB ? ptr[nodeB + 1] : endA;
    int begB = endA;   // contiguous CSR
    float ednA = ed[nodeA];
    float ednB = hasB ? ed[nodeB] : 0.f;
    const int half = lane >> 5, hl = lane & 31;
    float aA0 = 0.f, aA1 = 0.f, aA2 = 0.f, aA3 = 0.f, dA = 0.f;
    float aB0 = 0.f, aB1 = 0.f, aB2 = 0.f, aB3 = 0.f, dB = 0.f;
    int baseA = begA, baseB = begB;
    while (baseA < endA || baseB < endB) {
        int mA = endA - baseA; mA = mA < 0 ? 0 : (mA > 64 ? 64 : mA);
        int mB = endB - baseB; mB = mB < 0 ? 0 : (mB > 64 ? 64 : mB);
        int sA = 0, sB = 0;
        float wA = 0.f, wB = 0.f;
        if (lane < mA) {
            sA = col[baseA + lane];
            float e = es[sA] + ednA;
            e = fmaxf(e, 0.2f * e);
            wA = __expf(e);
        }
        if (lane < mB) {
            sB = col[baseB + lane];
            float e = es[sB] + ednB;
            e = fmaxf(e, 0.2f * e);
            wB = __expf(e);
        }
        dA += wA; dB += wB;
        {
            int mp = (mA + 1) & ~1;
            int t = 0;
            for (; t + 8 <= mp; t += 8) {
                int i0 = t + half, i1 = t + 2 + half, i2 = t + 4 + half, i3 = t + 6 + half;
                int s0 = __shfl(sA, i0, 64), s1 = __shfl(sA, i1, 64);
                int s2 = __shfl(sA, i2, 64), s3 = __shfl(sA, i3, 64);
                float w0 = __shfl(wA, i0, 64), w1 = __shfl(wA, i1, 64);
                float w2 = __shfl(wA, i2, 64), w3 = __shfl(wA, i3, 64);
                uint2 h0 = *(const uint2*)&hsb[(size_t)s0 * 128 + hl * 4];
                uint2 h1 = *(const uint2*)&hsb[(size_t)s1 * 128 + hl * 4];
                uint2 h2 = *(const uint2*)&hsb[(size_t)s2 * 128 + hl * 4];
                uint2 h3 = *(const uint2*)&hsb[(size_t)s3 * 128 + hl * 4];
                aA0 += w0 * bflo(h0.x) + w1 * bflo(h1.x) + w2 * bflo(h2.x) + w3 * bflo(h3.x);
                aA1 += w0 * bfhi(h0.x) + w1 * bfhi(h1.x) + w2 * bfhi(h2.x) + w3 * bfhi(h3.x);
                aA2 += w0 * bflo(h0.y) + w1 * bflo(h1.y) + w2 * bflo(h2.y) + w3 * bflo(h3.y);
                aA3 += w0 * bfhi(h0.y) + w1 * bfhi(h1.y) + w2 * bfhi(h2.y) + w3 * bfhi(h3.y);
            }
            for (; t < mp; t += 2) {
                int i0 = t + half;
                int s0 = __shfl(sA, i0, 64);
                float w0 = __shfl(wA, i0, 64);
                uint2 h0 = *(const uint2*)&hsb[(size_t)s0 * 128 + hl * 4];
                aA0 += w0 * bflo(h0.x);
                aA1 += w0 * bfhi(h0.x);
                aA2 += w0 * bflo(h0.y);
                aA3 += w0 * bfhi(h0.y);
            }
        }
        {
            int mp = (mB + 1) & ~1;
            int t = 0;
            for (; t + 8 <= mp; t += 8) {
                int i0 = t + half, i1 = t + 2 + half, i2 = t + 4 + half, i3 = t + 6 + half;
                int s0 = __shfl(sB, i0, 64), s1 = __shfl(sB, i1, 64);
                int s2 = __shfl(sB, i2, 64), s3 = __shfl(sB, i3, 64);
                float w0 = __shfl(wB, i0, 64), w1 = __shfl(wB, i1, 64);
                float w2 = __shfl(wB, i2, 64), w3 = __shfl(wB, i3, 64);
                uint2 h0 = *(const uint2*)&hsb[(size_t)s0 * 128 + hl * 4];
                uint2 h1 = *(const uint2*)&hsb[(size_t)s1 * 128 + hl * 4];
                uint2 h2 = *(const uint2*)&hsb[(size_t)s2 * 128 + hl * 4];
                uint2 h3 = *(const uint2*)&hsb[(size_t)s3 * 128 + hl * 4];
                aB0 += w0 * bflo(h0.x) + w1 * bflo(h1.x) + w2 * bflo(h2.x) + w3 * bflo(h3.x);
                aB1 += w0 * bfhi(h0.x) + w1 * bfhi(h1.x) + w2 * bfhi(h2.x) + w3 * bfhi(h3.x);
                aB2 += w0 * bflo(h0.y) + w1 * bflo(h1.y) + w2 * bflo(h2.y) + w3 * bflo(h3.y);
                aB3 += w0 * bfhi(h0.y) + w1 * bfhi(h1.y) + w2 * bfhi(h2.y) + w3 * bfhi(h3.y);
            }
            for (; t < mp; t += 2) {
                int i0 = t + half;
                int s0 = __shfl(sB, i0, 64);
                float w0 = __shfl(wB, i0, 64);
                uint2 h0 = *(const uint2*)&hsb[(size_t)s0 * 128 + hl * 4];
                aB0 += w0 * bflo(h0.x);
                aB1 += w0 * bfhi(h0.x);
                aB2 += w0 * bflo(h0.y);
                aB3 += w0 * bfhi(h0.y);
            }
        }
        baseA += 64; baseB += 64;
    }
    aA0 += __shfl_xor(aA0, 32, 64); aA1 += __shfl_xor(aA1, 32, 64);
    aA2 += __shfl_xor(aA2, 32, 64); aA3 += __shfl_xor(aA3, 32, 64);
    aB0 += __shfl_xor(aB0, 32, 64); aB1 += __shfl_xor(aB1, 32, 64);
    aB2 += __shfl_xor(aB2, 32, 64); aB3 += __shfl_xor(aB3, 32, 64);
    #pragma unroll
    for (int off = 1; off < 64; off <<= 1) dA += __shfl_xor(dA, off, 64);
    #pragma unroll
    for (int off = 1; off < 64; off <<= 1) dB += __shfl_xor(dB, off, 64);
    float invA = (endA > begA) ? (1.f / dA) : 0.f;
    float invB = (endB > begB) ? (1.f / dB) : 0.f;
    int node = half ? nodeB : nodeA;
    if (half == 0 || hasB) {
        float v0 = half ? aB0 : aA0, v1 = half ? aB1 : aA1;
        float v2 = half ? aB2 : aA2, v3 = half ? aB3 : aA3;
        float inv = half ? invB : invA;
        uint2 lv = *(const uint2*)&linb[(size_t)node * 128 + hl * 4];
        float4 bb = *(const float4*)&b[hl * 4];
        float4 lb4 = *(const float4*)&Lb[hl * 4];
        float o0 = fmaxf(v0 * inv + bb.x + bflo(lv.x) + lb4.x, 0.f);
        float o1 = fmaxf(v1 * inv + bb.y + bfhi(lv.x) + lb4.y, 0.f);
        float o2 = fmaxf(v2 * inv + bb.z + bflo(lv.y) + lb4.z, 0.f);
        float o3 = fmaxf(v3 * inv + bb.w + bfhi(lv.y) + lb4.w, 0.f);
        uint2 ov;
        ov.x = (uint_t)f2bf(o0) | ((uint_t)f2bf(o1) << 16);
        ov.y = (uint_t)f2bf(o2) | ((uint_t)f2bf(o3) << 16);
        *(uint2*)&hh[(size_t)node * 64 + hl * 2] = ov;
    }
}

// ---------------- translate aggregate (C=64), fused ed matvec (R11, verified) ----------------
__global__ __launch_bounds__(256) void agg_fp5(const int* __restrict__ ptr, const int* __restrict__ col,
                                               const float* __restrict__ es, const float* __restrict__ x_fp,
                                               const float* __restrict__ wedt,
                                               const ushort_t* __restrict__ hsb, const float* __restrict__ bt,
                                               float* __restrict__ out, int N) {
    int lane = threadIdx.x & 63, wid = threadIdx.x >> 6;
    int node = blockIdx.x * 4 + wid;
    if (node >= N) return;
    int beg = ptr[node], end = ptr[node + 1];
    float edn = x_fp[(size_t)node * 64 + lane] * wedt[lane];
    #pragma unroll
    for (int off = 1; off < 64; off <<= 1) edn += __shfl_xor(edn, off, 64);
    float acc = 0.f, denp = 0.f;
    for (int base = beg; base < end; base += 64) {
        int m = min(64, end - base);
        int s = 0;
        float wgt = 0.f;
        if (lane < m) {
            s = col[base + lane];
            float e = es[s] + edn;
            e = fmaxf(e, 0.2f * e);
            wgt = __expf(e);
        }
        denp += wgt;
        int u = 0;
        for (; u + 4 <= m; u += 4) {
            int s0 = __shfl(s, u, 64), s1 = __shfl(s, u + 1, 64);
            int s2 = __shfl(s, u + 2, 64), s3 = __shfl(s, u + 3, 64);
            float w0 = __shfl(wgt, u, 64), w1 = __shfl(wgt, u + 1, 64);
            float w2 = __shfl(wgt, u + 2, 64), w3 = __shfl(wgt, u + 3, 64);
            float h0 = bfu2f(hsb[(size_t)s0 * 64 + lane]);
            float h1 = bfu2f(hsb[(size_t)s1 * 64 + lane]);
            float h2 = bfu2f(hsb[(size_t)s2 * 64 + lane]);
            float h3 = bfu2f(hsb[(size_t)s3 * 64 + lane]);
            acc += w0 * h0 + w1 * h1 + w2 * h2 + w3 * h3;
        }
        for (; u < m; ++u) {
            int su = __shfl(s, u, 64);
            float wu = __shfl(wgt, u, 64);
            acc += wu * bfu2f(hsb[(size_t)su * 64 + lane]);
        }
    }
    float den = denp;
    #pragma unroll
    for (int off = 1; off < 64; off <<= 1) den += __shfl_xor(den, off, 64);
    float inv = (end > beg) ? (1.f / den) : 0.f;
    out[(size_t)node * 64 + lane] = acc * inv + bt[lane];
}

extern "C" void kernel_launch(void* const* d_in, const int* in_sizes, int n_in,
                              void* d_out, int out_size, void* d_ws, size_t ws_size,
                              hipStream_t stream) {
    const float* x_pano = (const float*)d_in[0];
    const float* x_fp   = (const float*)d_in[1];
    const float* Ws0 = (const float*)d_in[2];
    const float* Wd0 = (const float*)d_in[3];
    const float* as0 = (const float*)d_in[4];
    const float* ad0 = (const float*)d_in[5];
    const float* b0  = (const float*)d_in[6];
    const float* Lw0 = (const float*)d_in[7];
    const float* Lb0 = (const float*)d_in[8];
    const float* Ws1 = (const float*)d_in[9];
    const float* Wd1 = (const float*)d_in[10];
    const float* as1 = (const float*)d_in[11];
    const float* ad1 = (const float*)d_in[12];
    const float* b1  = (const float*)d_in[13];
    const float* Lw1 = (const float*)d_in[14];
    const float* Lb1 = (const float*)d_in[15];
    const float* Wts = (const float*)d_in[16];
    const float* Wtd = (const float*)d_in[17];
    const float* ats = (const float*)d_in[18];
    const float* atd = (const float*)d_in[19];
    const float* bt  = (const float*)d_in[20];
    const int* pp_src = (const int*)d_in[21];
    const int* pp_dst = (const int*)d_in[21] + E_PP;
    const int* pf_src = (const int*)d_in[22];
    const int* pf_dst = (const int*)d_in[23];
    float* out = (float*)d_out;

    char* wsp = (char*)d_ws;
    size_t off = 0;
    auto alloc = [&](size_t bytes) -> char* {
        char* p = wsp + off;
        off += (bytes + 255) & ~(size_t)255;
        return p;
    };
    ushort_t* hsb  = (ushort_t*)alloc(sizeof(ushort_t) * N_PANO * HID);
    ushort_t* linb = (ushort_t*)alloc(sizeof(ushort_t) * N_PANO * HID);
    uint_t* hh     = (uint_t*)alloc(sizeof(uint_t) * N_PANO * 64);
    ushort_t* hstb = (ushort_t*)alloc(sizeof(ushort_t) * N_PANO * OUT_C);
    int2* tmp_e    = (int2*)alloc(sizeof(int2) * E_UNI);
    float* es   = (float*)alloc(sizeof(float) * N_PANO);
    float* ed   = (float*)alloc(sizeof(float) * N_PANO);
    float* wed0 = (float*)alloc(sizeof(float) * HID);
    float* wed1 = (float*)alloc(sizeof(float) * HID);
    float* wedt = (float*)alloc(sizeof(float) * OUT_C);
    ushort_t* s0 = (ushort_t*)alloc(sizeof(ushort_t) * 128 * 128);
    ushort_t* l0 = (ushort_t*)alloc(sizeof(ushort_t) * 128 * 128);
    ushort_t* s1 = (ushort_t*)alloc(sizeof(ushort_t) * 128 * 128);
    ushort_t* l1 = (ushort_t*)alloc(sizeof(ushort_t) * 128 * 128);
    ushort_t* ts = (ushort_t*)alloc(sizeof(ushort_t) * 64 * 128);
    int* pcnt  = (int*)alloc(sizeof(int) * NBKT * NT_CNT);
    int* pexc  = (int*)alloc(sizeof(int) * NBKT * NT_CNT);
    int* btot  = (int*)alloc(sizeof(int) * NBKT);
    int* bbase = (int*)alloc(sizeof(int) * (NBKT + 1));
    int* P     = (int*)alloc(sizeof(int) * (N_UNI + 1));
    int* col_u = (int*)alloc(sizeof(int) * E_UNI);

    // ---- CSR build (atomic-free at global scope) + weight prep, 4 launches ----
    csr_count_prep<<<NT_CNT + 288 + 80, 256, 0, stream>>>(
        pp_dst, pf_dst, pcnt, Ws0, Lw0, Ws1, Lw1, Wts,
        Wd0, ad0, Wd1, ad1, Wtd, atd, s0, l0, s1, l1, ts, wed0, wed1, wedt);
    csr_scan<<<NBKT, 256, 0, stream>>>(pcnt, pexc, btot);
    csr_scatter<<<NT_CNT, 256, 0, stream>>>(pp_src, pp_dst, pf_src, pf_dst, pexc, btot, bbase, tmp_e);
    csr_sort<<<NBKT, 256, 0, stream>>>(tmp_e, bbase, P, col_u);

    const int gemm_grid = cdiv(N_PANO, 128);

    // ---- layer 0 (fp32 input) ----
    gemm_mfma<128, true, true><<<gemm_grid, 256, 0, stream>>>(
        x_pano, nullptr, s0, l0, hsb, linb, as0, es, wed0, ed, N_PANO);
    agg_pano7<<<cdiv(N_PANO, 8), 256, 0, stream>>>(P, col_u, es, ed, hsb, linb, b0, Lb0, hh, N_PANO);

    // ---- layer 1 (bf16 input = hh) ----
    gemm_mfma<128, true, false><<<gemm_grid, 256, 0, stream>>>(
        nullptr, (const ushort_t*)hh, s1, l1, hsb, linb, as1, es, wed1, ed, N_PANO);
    agg_pano7<<<cdiv(N_PANO, 8), 256, 0, stream>>>(P, col_u, es, ed, hsb, linb, b1, Lb1, hh, N_PANO);

    // ---- translate (pano -> footprint); pf ptr = P+50000 (absolute into col_u) ----
    gemm_mfma<64, false, false><<<gemm_grid, 256, 0, stream>>>(
        nullptr, (const ushort_t*)hh, ts, nullptr, hstb, nullptr, ats, es, nullptr, nullptr, N_PANO);
    agg_fp5<<<cdiv(N_FP, 4), 256, 0, stream>>>(P + N_PANO, col_u, es, x_fp, wedt, hstb, bt, out, N_FP);
}

// Round 15
// 266.081 us; speedup vs baseline: 3.0720x; 1.0051x over previous
//
#include <hip/hip_runtime.h>
#include <hip/hip_bf16.h>
#include <math.h>

#define N_PANO 50000
#define N_FP   10000
#define N_UNI  60000   // unified dst id-space: pano [0,50000), fp mapped to 50000+d
#define HID    128
#define OUT_C  64
#define E_PP   800000
#define E_PF   50000
#define E_UNI  850000
#define NBKT   235     // cdiv(N_UNI, 256) coarse buckets
#define EPB    4096    // edges per tile in count/scatter
#define NT_CNT 208     // cdiv(E_UNI, EPB)
#define NT_GEMM 391    // cdiv(N_PANO, 128)

typedef unsigned short ushort_t;
typedef unsigned int uint_t;
typedef __attribute__((ext_vector_type(8))) short short8;
typedef __attribute__((ext_vector_type(4))) float f32x4;

static inline int cdiv(int a, int b) { return (a + b - 1) / b; }

__device__ inline ushort_t f2bf(float x) {
    __hip_bfloat16 h = __float2bfloat16(x);   // RNE
    return *reinterpret_cast<ushort_t*>(&h);
}
__device__ inline float bfu2f(ushort_t u) {
    return __uint_as_float(((uint_t)u) << 16);
}
__device__ inline float bflo(uint_t u) { return __uint_as_float((u & 0xffffu) << 16); }
__device__ inline float bfhi(uint_t u) { return __uint_as_float(u & 0xffff0000u); }
__device__ inline f32x4 mfma16(short8 a, short8 b, f32x4 c) {
    return __builtin_amdgcn_mfma_f32_16x16x32_bf16(a, b, c, 0, 0, 0);
}

// ---------------- CSR stage 1: per-tile partial counts + weight prep (merged) ----------------
__global__ __launch_bounds__(256) void csr_count_prep(
        const int* __restrict__ pp_dst, const int* __restrict__ pf_dst,
        int* __restrict__ pcnt,
        const float* __restrict__ Ws0, const float* __restrict__ Lw0,
        const float* __restrict__ Ws1, const float* __restrict__ Lw1,
        const float* __restrict__ Wts,
        const float* __restrict__ Wd0, const float* __restrict__ ad0,
        const float* __restrict__ Wd1, const float* __restrict__ ad1,
        const float* __restrict__ Wtd, const float* __restrict__ atd,
        ushort_t* s0, ushort_t* l0, ushort_t* s1, ushort_t* l1, ushort_t* ts,
        float* wed0, float* wed1, float* wedt) {
    __shared__ int hist[NBKT];
    const int tile = blockIdx.x, tid = threadIdx.x;
    if (tile < NT_CNT) {
        for (int t = tid; t < NBKT; t += 256) hist[t] = 0;
        __syncthreads();
        const int e0 = tile * EPB;
        #pragma unroll
        for (int u = 0; u < 16; ++u) {
            int e = e0 + u * 256 + tid;
            int d = -1;
            if (e < E_PP) d = pp_dst[e];
            else if (e < E_UNI) d = N_PANO + pf_dst[e - E_PP];
            if (d >= 0) atomicAdd(&hist[d >> 8], 1);
        }
        __syncthreads();
        for (int t = tid; t < NBKT; t += 256) pcnt[t * NT_CNT + tile] = hist[t];
    } else if (tile < NT_CNT + 288) {
        int i = (tile - NT_CNT) * 256 + tid;
        const float* W; ushort_t* oh;
        int d, NIc, Cc;
        if (i < 65536) {
            int m = i >> 14; d = i & 16383;
            W = (m == 0) ? Ws0 : (m == 1) ? Lw0 : (m == 2) ? Ws1 : Lw1;
            oh = (m == 0) ? s0 : (m == 1) ? l0 : (m == 2) ? s1 : l1;
            NIc = 8; Cc = 128;
        } else if (i < 73728) {
            d = i - 65536; W = Wts; oh = ts;
            NIc = 4; Cc = 64;
        } else return;
        int j = d & 7, l = (d >> 3) & 63;
        int kcl = (d >> 9) & 1;
        int ni = (d >> 10) & (NIc - 1);
        int p = d >> (10 + (NIc == 8 ? 3 : 2));
        int kc = p * 2 + kcl;
        int n = ni * 16 + (l & 15);
        int k = kc * 32 + (l >> 4) * 8 + j;
        oh[d] = f2bf(W[k * Cc + n]);
    } else {
        int r = (tile - NT_CNT - 288) * 4 + (tid >> 6);
        int lane = tid & 63;
        const float* W; const float* a; float* o; int rr, C;
        if (r < 128)      { W = Wd0; a = ad0; o = wed0; rr = r;       C = 128; }
        else if (r < 256) { W = Wd1; a = ad1; o = wed1; rr = r - 128; C = 128; }
        else if (r < 320) { W = Wtd; a = atd; o = wedt; rr = r - 256; C = 64;  }
        else return;
        float s = 0.f;
        for (int j = lane; j < C; j += 64) s += W[rr * C + j] * a[j];
        #pragma unroll
        for (int off = 32; off; off >>= 1) s += __shfl_down(s, off, 64);
        if (lane == 0) o[rr] = s;
    }
}

// ---------------- GEMM body (bf16 MFMA, LDS-staged fragment-order weights) ----------------
template <int CN, bool DUAL, bool FP32IN>
__device__ void gemm_body(int tile, char* smem,
                          const float* __restrict__ Xf, const ushort_t* __restrict__ Xh,
                          const ushort_t* __restrict__ W1, const ushort_t* __restrict__ W2,
                          ushort_t* __restrict__ Y1, ushort_t* __restrict__ Y2,
                          const float* __restrict__ avec, float* __restrict__ evec,
                          const float* __restrict__ wed, float* __restrict__ edv, int N) {
    constexpr int NI = CN / 16;
    constexpr int SLAB = NI * 1024;
    ushort_t* Bsh = (ushort_t*)smem;
    const int tid = threadIdx.x;
    const int w = tid >> 6, l = tid & 63;
    const int col = l & 15, q = l >> 4;
    const int row0 = tile * 128 + w * 32;
    f32x4 acc1[2][NI];
    f32x4 acc2[2][DUAL ? NI : 1];
    #pragma unroll
    for (int m = 0; m < 2; ++m)
        #pragma unroll
        for (int ni = 0; ni < NI; ++ni)
            #pragma unroll
            for (int r = 0; r < 4; ++r) acc1[m][ni][r] = 0.f;
    if (DUAL) {
        #pragma unroll
        for (int m = 0; m < 2; ++m)
            #pragma unroll
            for (int ni = 0; ni < NI; ++ni)
                #pragma unroll
                for (int r = 0; r < 4; ++r) acc2[m][ni][r] = 0.f;
    }
    float ped[2] = {0.f, 0.f};

    #pragma unroll
    for (int p = 0; p < 2; ++p) {
        if (p) __syncthreads();
        {
            const uint4* src1 = (const uint4*)W1 + p * (SLAB / 8);
            uint4* dst1 = (uint4*)&Bsh[0];
            #pragma unroll
            for (int f = tid; f < SLAB / 8; f += 256) dst1[f] = src1[f];
            if (DUAL) {
                const uint4* src2 = (const uint4*)W2 + p * (SLAB / 8);
                uint4* dst2 = (uint4*)&Bsh[SLAB];
                #pragma unroll
                for (int f = tid; f < SLAB / 8; f += 256) dst2[f] = src2[f];
            }
        }
        __syncthreads();
        #pragma unroll
        for (int kcl = 0; kcl < 2; ++kcl) {
            const int kc = p * 2 + kcl;
            const int k0 = kc * 32 + q * 8;
            short8 Ah[2];
            #pragma unroll
            for (int m = 0; m < 2; ++m) {
                const int arow = row0 + m * 16 + col;
                if (FP32IN) {
                    float xv[8];
                    if (arow < N) {
                        float4 a0 = *(const float4*)&Xf[(size_t)arow * 128 + k0];
                        float4 a1 = *(const float4*)&Xf[(size_t)arow * 128 + k0 + 4];
                        xv[0] = a0.x; xv[1] = a0.y; xv[2] = a0.z; xv[3] = a0.w;
                        xv[4] = a1.x; xv[5] = a1.y; xv[6] = a1.z; xv[7] = a1.w;
                    } else {
                        #pragma unroll
                        for (int j = 0; j < 8; ++j) xv[j] = 0.f;
                    }
                    #pragma unroll
                    for (int j = 0; j < 8; ++j) Ah[m][j] = (short)f2bf(xv[j]);
                    if (wed) {
                        float4 w0 = *(const float4*)&wed[k0];
                        float4 w1 = *(const float4*)&wed[k0 + 4];
                        ped[m] += xv[0] * w0.x + xv[1] * w0.y + xv[2] * w0.z + xv[3] * w0.w
                                + xv[4] * w1.x + xv[5] * w1.y + xv[6] * w1.z + xv[7] * w1.w;
                    }
                } else {
                    if (arow < N) {
                        Ah[m] = *(const short8*)&Xh[(size_t)arow * 128 + k0];
                    } else {
                        #pragma unroll
                        for (int j = 0; j < 8; ++j) Ah[m][j] = 0;
                    }
                    if (wed) {
                        float4 w0 = *(const float4*)&wed[k0];
                        float4 w1 = *(const float4*)&wed[k0 + 4];
                        float wv[8] = {w0.x, w0.y, w0.z, w0.w, w1.x, w1.y, w1.z, w1.w};
                        #pragma unroll
                        for (int j = 0; j < 8; ++j)
                            ped[m] += bfu2f((ushort_t)Ah[m][j]) * wv[j];
                    }
                }
            }
            #pragma unroll
            for (int ni = 0; ni < NI; ++ni) {
                const int lb = ((ni * 2 + kcl) * 64 + l) * 8;
                short8 B1 = *(const short8*)&Bsh[lb];
                #pragma unroll
                for (int m = 0; m < 2; ++m) acc1[m][ni] = mfma16(Ah[m], B1, acc1[m][ni]);
                if (DUAL) {
                    short8 B2 = *(const short8*)&Bsh[SLAB + lb];
                    #pragma unroll
                    for (int m = 0; m < 2; ++m) acc2[m][ni] = mfma16(Ah[m], B2, acc2[m][ni]);
                }
            }
        }
    }

    #pragma unroll
    for (int m = 0; m < 2; ++m) {
        #pragma unroll
        for (int ni = 0; ni < NI; ++ni) {
            #pragma unroll
            for (int r = 0; r < 4; ++r) {
                int mrow = row0 + m * 16 + q * 4 + r;
                if (mrow < N) {
                    Y1[(size_t)mrow * CN + ni * 16 + col] = f2bf(acc1[m][ni][r]);
                    if (DUAL) Y2[(size_t)mrow * CN + ni * 16 + col] = f2bf(acc2[m][ni][r]);
                }
            }
        }
    }
    float av[NI];
    #pragma unroll
    for (int ni = 0; ni < NI; ++ni) av[ni] = avec[ni * 16 + col];
    #pragma unroll
    for (int m = 0; m < 2; ++m) {
        #pragma unroll
        for (int r = 0; r < 4; ++r) {
            float pp = 0.f;
            #pragma unroll
            for (int ni = 0; ni < NI; ++ni) pp += acc1[m][ni][r] * av[ni];
            pp += __shfl_xor(pp, 1, 64);
            pp += __shfl_xor(pp, 2, 64);
            pp += __shfl_xor(pp, 4, 64);
            pp += __shfl_xor(pp, 8, 64);
            int mrow = row0 + m * 16 + q * 4 + r;
            if (col == 0 && mrow < N) evec[mrow] = pp;
        }
    }
    if (wed) {
        #pragma unroll
        for (int m = 0; m < 2; ++m) {
            ped[m] += __shfl_xor(ped[m], 16, 64);
            ped[m] += __shfl_xor(ped[m], 32, 64);
            int arow = row0 + m * 16 + col;
            if (q == 0 && arow < N) edv[arow] = ped[m];
        }
    }
}

// ---------------- scatter body: inline 2D prefix (no pexc roundtrip, no global atomics) ----------------
__device__ void scatter_body(int tile, char* smem,
                             const int* __restrict__ pp_src, const int* __restrict__ pp_dst,
                             const int* __restrict__ pf_src, const int* __restrict__ pf_dst,
                             const int* __restrict__ pcnt, int* __restrict__ bbase_out,
                             int2* __restrict__ tmp) {
    int* base2 = (int*)smem;            // [NBKT]
    int* cur   = base2 + NBKT;          // [NBKT]
    int* wsum  = cur + NBKT;            // [4]
    const int tid = threadIdx.x, lane = tid & 63, wv = tid >> 6;
    // thread tid owns bucket tid: rowsum over all tiles + prefix over tiles < tile
    int rowsum = 0, myprefix = 0;
    if (tid < NBKT) {
        const int* row = pcnt + tid * NT_CNT;
        for (int t = 0; t < NT_CNT; ++t) {
            int c = row[t];
            rowsum += c;
            if (t < tile) myprefix += c;
        }
    }
    // exclusive scan of rowsum over buckets -> bucket base
    int v = (tid < NBKT) ? rowsum : 0;
    int incl = v;
    #pragma unroll
    for (int off = 1; off < 64; off <<= 1) {
        int t = __shfl_up(incl, off, 64);
        if (lane >= off) incl += t;
    }
    if (lane == 63) wsum[wv] = incl;
    __syncthreads();
    if (tid == 0) {
        int run = 0;
        #pragma unroll
        for (int w = 0; w < 4; ++w) { int t = wsum[w]; wsum[w] = run; run += t; }
    }
    __syncthreads();
    int bexcl = wsum[wv] + incl - v;
    if (tid < NBKT) {
        base2[tid] = bexcl + myprefix;
        cur[tid] = 0;
        if (tile == 0) bbase_out[tid] = bexcl;
    }
    if (tile == 0 && tid == 0) bbase_out[NBKT] = E_UNI;
    __syncthreads();
    const int e0 = tile * EPB;
    #pragma unroll
    for (int u = 0; u < 16; ++u) {
        int e = e0 + u * 256 + tid;
        int d = -1, s = 0;
        if (e < E_PP)       { d = pp_dst[e];                 s = pp_src[e]; }
        else if (e < E_UNI) { d = N_PANO + pf_dst[e - E_PP]; s = pf_src[e - E_PP]; }
        if (d >= 0) {
            int b = d >> 8;
            int p = base2[b] + atomicAdd(&cur[b], 1);
            tmp[p] = make_int2(s, d);
        }
    }
}

// ---------------- merged launch: scatter (tiles 0..207) || layer-0 dual GEMM ----------------
__global__ __launch_bounds__(256, 2) void scatter_gemm0(
        const int* __restrict__ pp_src, const int* __restrict__ pp_dst,
        const int* __restrict__ pf_src, const int* __restrict__ pf_dst,
        const int* __restrict__ pcnt, int* __restrict__ bbase_out, int2* __restrict__ tmp,
        const float* __restrict__ x_pano,
        const ushort_t* __restrict__ s0, const ushort_t* __restrict__ l0,
        ushort_t* __restrict__ hsb, ushort_t* __restrict__ linb,
        const float* __restrict__ as0, float* __restrict__ es,
        const float* __restrict__ wed0, float* __restrict__ ed) {
    __shared__ __align__(16) char smem[32768];
    if (blockIdx.x < NT_CNT)
        scatter_body(blockIdx.x, smem, pp_src, pp_dst, pf_src, pf_dst, pcnt, bbase_out, tmp);
    else
        gemm_body<128, true, true>(blockIdx.x - NT_CNT, smem, x_pano, nullptr, s0, l0,
                                   hsb, linb, as0, es, wed0, ed, N_PANO);
}

// ---------------- standalone GEMM kernel (layers 1 and translate) ----------------
template <int CN, bool DUAL, bool FP32IN>
__global__ __launch_bounds__(256, 2) void gemm_mfma(const float* __restrict__ Xf,
                                                 const ushort_t* __restrict__ Xh,
                                                 const ushort_t* __restrict__ W1, const ushort_t* __restrict__ W2,
                                                 ushort_t* __restrict__ Y1, ushort_t* __restrict__ Y2,
                                                 const float* __restrict__ avec, float* __restrict__ evec,
                                                 const float* __restrict__ wed, float* __restrict__ edv,
                                                 int N) {
    __shared__ __align__(16) char smem[(DUAL ? 2 : 1) * (CN / 16) * 2048];
    gemm_body<CN, DUAL, FP32IN>(blockIdx.x, smem, Xf, Xh, W1, W2, Y1, Y2, avec, evec, wed, edv, N);
}

// ---------------- CSR stage 4: per-bucket counting sort in LDS -> P, col ----------------
__global__ __launch_bounds__(256) void csr_sort(const int2* __restrict__ tmp,
                                                const int* __restrict__ bbase,
                                                int* __restrict__ ptr, int* __restrict__ col) {
    __shared__ int hist[256];
    __shared__ int wsum[4];
    const int b = blockIdx.x, tid = threadIdx.x, lane = tid & 63, wv = tid >> 6;
    const int B0 = bbase[b], B1 = bbase[b + 1];
    hist[tid] = 0;
    __syncthreads();
    for (int e = B0 + tid; e < B1; e += 256) atomicAdd(&hist[tmp[e].y & 255], 1);
    __syncthreads();
    int v = hist[tid];
    int incl = v;
    #pragma unroll
    for (int off = 1; off < 64; off <<= 1) {
        int t = __shfl_up(incl, off, 64);
        if (lane >= off) incl += t;
    }
    if (lane == 63) wsum[wv] = incl;
    __syncthreads();
    if (tid == 0) {
        int run = 0;
        #pragma unroll
        for (int w = 0; w < 4; ++w) { int t = wsum[w]; wsum[w] = run; run += t; }
    }
    __syncthreads();
    int excl = wsum[wv] + incl - v;
    int dg = b * 256 + tid;
    if (dg < N_UNI) ptr[dg] = B0 + excl;
    if (b == NBKT - 1 && tid == 0) ptr[N_UNI] = E_UNI;
    hist[tid] = excl;
    __syncthreads();
    for (int e = B0 + tid; e < B1; e += 256) {
        int2 ed2 = tmp[e];
        int p = B0 + atomicAdd(&hist[ed2.y & 255], 1);
        col[p] = ed2.x;
    }
}

// ---------------- GAT aggregate (pano): two nodes per wave, pair-packed ----------------
__global__ __launch_bounds__(256) void agg_pano7(const int* __restrict__ ptr, const int* __restrict__ col,
                                                 const float* __restrict__ es, const float* __restrict__ ed,
                                                 const ushort_t* __restrict__ hsb, const ushort_t* __restrict__ linb,
                                                 const float* __restrict__ b, const float* __restrict__ Lb,
                                                 uint_t* __restrict__ hh, int N) {
    int lane = threadIdx.x & 63, wid = threadIdx.x >> 6;
    int nodeA = blockIdx.x * 8 + wid * 2;
    if (nodeA >= N) return;
    int nodeB = nodeA + 1;
    bool hasB = nodeB < N;
    int begA = ptr[nodeA], endA = ptr[nodeA + 1];
    int endB = hasB ? ptr[nodeB + 1] : endA;
    int begB = endA;   // contiguous CSR
    float ednA = ed[nodeA];
    float ednB = hasB ? ed[nodeB] : 0.f;
    const int half = lane >> 5, hl = lane & 31;
    float aA0 = 0.f, aA1 = 0.f, aA2 = 0.f, aA3 = 0.f, dA = 0.f;
    float aB0 = 0.f, aB1 = 0.f, aB2 = 0.f, aB3 = 0.f, dB = 0.f;
    int baseA = begA, baseB = begB;
    while (baseA < endA || baseB < endB) {
        int mA = endA - baseA; mA = mA < 0 ? 0 : (mA > 64 ? 64 : mA);
        int mB = endB - baseB; mB = mB < 0 ? 0 : (mB > 64 ? 64 : mB);
        int sA = 0, sB = 0;
        float wA = 0.f, wB = 0.f;
        if (lane < mA) {
            sA = col[baseA + lane];
            float e = es[sA] + ednA;
            e = fmaxf(e, 0.2f * e);
            wA = __expf(e);
        }
        if (lane < mB) {
            sB = col[baseB + lane];
            float e = es[sB] + ednB;
            e = fmaxf(e, 0.2f * e);
            wB = __expf(e);
        }
        dA += wA; dB += wB;
        {
            int mp = (mA + 1) & ~1;
            int t = 0;
            for (; t + 8 <= mp; t += 8) {
                int i0 = t + half, i1 = t + 2 + half, i2 = t + 4 + half, i3 = t + 6 + half;
                int s0 = __shfl(sA, i0, 64), s1 = __shfl(sA, i1, 64);
                int s2 = __shfl(sA, i2, 64), s3 = __shfl(sA, i3, 64);
                float w0 = __shfl(wA, i0, 64), w1 = __shfl(wA, i1, 64);
                float w2 = __shfl(wA, i2, 64), w3 = __shfl(wA, i3, 64);
                uint2 h0 = *(const uint2*)&hsb[(size_t)s0 * 128 + hl * 4];
                uint2 h1 = *(const uint2*)&hsb[(size_t)s1 * 128 + hl * 4];
                uint2 h2 = *(const uint2*)&hsb[(size_t)s2 * 128 + hl * 4];
                uint2 h3 = *(const uint2*)&hsb[(size_t)s3 * 128 + hl * 4];
                aA0 += w0 * bflo(h0.x) + w1 * bflo(h1.x) + w2 * bflo(h2.x) + w3 * bflo(h3.x);
                aA1 += w0 * bfhi(h0.x) + w1 * bfhi(h1.x) + w2 * bfhi(h2.x) + w3 * bfhi(h3.x);
                aA2 += w0 * bflo(h0.y) + w1 * bflo(h1.y) + w2 * bflo(h2.y) + w3 * bflo(h3.y);
                aA3 += w0 * bfhi(h0.y) + w1 * bfhi(h1.y) + w2 * bfhi(h2.y) + w3 * bfhi(h3.y);
            }
            for (; t < mp; t += 2) {
                int i0 = t + half;
                int s0 = __shfl(sA, i0, 64);
                float w0 = __shfl(wA, i0, 64);
                uint2 h0 = *(const uint2*)&hsb[(size_t)s0 * 128 + hl * 4];
                aA0 += w0 * bflo(h0.x);
                aA1 += w0 * bfhi(h0.x);
                aA2 += w0 * bflo(h0.y);
                aA3 += w0 * bfhi(h0.y);
            }
        }
        {
            int mp = (mB + 1) & ~1;
            int t = 0;
            for (; t + 8 <= mp; t += 8) {
                int i0 = t + half, i1 = t + 2 + half, i2 = t + 4 + half, i3 = t + 6 + half;
                int s0 = __shfl(sB, i0, 64), s1 = __shfl(sB, i1, 64);
                int s2 = __shfl(sB, i2, 64), s3 = __shfl(sB, i3, 64);
                float w0 = __shfl(wB, i0, 64), w1 = __shfl(wB, i1, 64);
                float w2 = __shfl(wB, i2, 64), w3 = __shfl(wB, i3, 64);
                uint2 h0 = *(const uint2*)&hsb[(size_t)s0 * 128 + hl * 4];
                uint2 h1 = *(const uint2*)&hsb[(size_t)s1 * 128 + hl * 4];
                uint2 h2 = *(const uint2*)&hsb[(size_t)s2 * 128 + hl * 4];
                uint2 h3 = *(const uint2*)&hsb[(size_t)s3 * 128 + hl * 4];
                aB0 += w0 * bflo(h0.x) + w1 * bflo(h1.x) + w2 * bflo(h2.x) + w3 * bflo(h3.x);
                aB1 += w0 * bfhi(h0.x) + w1 * bfhi(h1.x) + w2 * bfhi(h2.x) + w3 * bfhi(h3.x);
                aB2 += w0 * bflo(h0.y) + w1 * bflo(h1.y) + w2 * bflo(h2.y) + w3 * bflo(h3.y);
                aB3 += w0 * bfhi(h0.y) + w1 * bfhi(h1.y) + w2 * bfhi(h2.y) + w3 * bfhi(h3.y);
            }
            for (; t < mp; t += 2) {
                int i0 = t + half;
                int s0 = __shfl(sB, i0, 64);
                float w0 = __shfl(wB, i0, 64);
                uint2 h0 = *(const uint2*)&hsb[(size_t)s0 * 128 + hl * 4];
                aB0 += w0 * bflo(h0.x);
                aB1 += w0 * bfhi(h0.x);
                aB2 += w0 * bflo(h0.y);
                aB3 += w0 * bfhi(h0.y);
            }
        }
        baseA += 64; baseB += 64;
    }
    aA0 += __shfl_xor(aA0, 32, 64); aA1 += __shfl_xor(aA1, 32, 64);
    aA2 += __shfl_xor(aA2, 32, 64); aA3 += __shfl_xor(aA3, 32, 64);
    aB0 += __shfl_xor(aB0, 32, 64); aB1 += __shfl_xor(aB1, 32, 64);
    aB2 += __shfl_xor(aB2, 32, 64); aB3 += __shfl_xor(aB3, 32, 64);
    #pragma unroll
    for (int off = 1; off < 64; off <<= 1) dA += __shfl_xor(dA, off, 64);
    #pragma unroll
    for (int off = 1; off < 64; off <<= 1) dB += __shfl_xor(dB, off, 64);
    float invA = (endA > begA) ? (1.f / dA) : 0.f;
    float invB = (endB > begB) ? (1.f / dB) : 0.f;
    int node = half ? nodeB : nodeA;
    if (half == 0 || hasB) {
        float v0 = half ? aB0 : aA0, v1 = half ? aB1 : aA1;
        float v2 = half ? aB2 : aA2, v3 = half ? aB3 : aA3;
        float inv = half ? invB : invA;
        uint2 lv = *(const uint2*)&linb[(size_t)node * 128 + hl * 4];
        float4 bb = *(const float4*)&b[hl * 4];
        float4 lb4 = *(const float4*)&Lb[hl * 4];
        float o0 = fmaxf(v0 * inv + bb.x + bflo(lv.x) + lb4.x, 0.f);
        float o1 = fmaxf(v1 * inv + bb.y + bfhi(lv.x) + lb4.y, 0.f);
        float o2 = fmaxf(v2 * inv + bb.z + bflo(lv.y) + lb4.z, 0.f);
        float o3 = fmaxf(v3 * inv + bb.w + bfhi(lv.y) + lb4.w, 0.f);
        uint2 ov;
        ov.x = (uint_t)f2bf(o0) | ((uint_t)f2bf(o1) << 16);
        ov.y = (uint_t)f2bf(o2) | ((uint_t)f2bf(o3) << 16);
        *(uint2*)&hh[(size_t)node * 64 + hl * 2] = ov;
    }
}

// ---------------- translate aggregate (C=64), fused ed matvec ----------------
__global__ __launch_bounds__(256) void agg_fp5(const int* __restrict__ ptr, const int* __restrict__ col,
                                               const float* __restrict__ es, const float* __restrict__ x_fp,
                                               const float* __restrict__ wedt,
                                               const ushort_t* __restrict__ hsb, const float* __restrict__ bt,
                                               float* __restrict__ out, int N) {
    int lane = threadIdx.x & 63, wid = threadIdx.x >> 6;
    int node = blockIdx.x * 4 + wid;
    if (node >= N) return;
    int beg = ptr[node], end = ptr[node + 1];
    float edn = x_fp[(size_t)node * 64 + lane] * wedt[lane];
    #pragma unroll
    for (int off = 1; off < 64; off <<= 1) edn += __shfl_xor(edn, off, 64);
    float acc = 0.f, denp = 0.f;
    for (int base = beg; base < end; base += 64) {
        int m = min(64, end - base);
        int s = 0;
        float wgt = 0.f;
        if (lane < m) {
            s = col[base + lane];
            float e = es[s] + edn;
            e = fmaxf(e, 0.2f * e);
            wgt = __expf(e);
        }
        denp += wgt;
        int u = 0;
        for (; u + 4 <= m; u += 4) {
            int s0 = __shfl(s, u, 64), s1 = __shfl(s, u + 1, 64);
            int s2 = __shfl(s, u + 2, 64), s3 = __shfl(s, u + 3, 64);
            float w0 = __shfl(wgt, u, 64), w1 = __shfl(wgt, u + 1, 64);
            float w2 = __shfl(wgt, u + 2, 64), w3 = __shfl(wgt, u + 3, 64);
            float h0 = bfu2f(hsb[(size_t)s0 * 64 + lane]);
            float h1 = bfu2f(hsb[(size_t)s1 * 64 + lane]);
            float h2 = bfu2f(hsb[(size_t)s2 * 64 + lane]);
            float h3 = bfu2f(hsb[(size_t)s3 * 64 + lane]);
            acc += w0 * h0 + w1 * h1 + w2 * h2 + w3 * h3;
        }
        for (; u < m; ++u) {
            int su = __shfl(s, u, 64);
            float wu = __shfl(wgt, u, 64);
            acc += wu * bfu2f(hsb[(size_t)su * 64 + lane]);
        }
    }
    float den = denp;
    #pragma unroll
    for (int off = 1; off < 64; off <<= 1) den += __shfl_xor(den, off, 64);
    float inv = (end > beg) ? (1.f / den) : 0.f;
    out[(size_t)node * 64 + lane] = acc * inv + bt[lane];
}

extern "C" void kernel_launch(void* const* d_in, const int* in_sizes, int n_in,
                              void* d_out, int out_size, void* d_ws, size_t ws_size,
                              hipStream_t stream) {
    const float* x_pano = (const float*)d_in[0];
    const float* x_fp   = (const float*)d_in[1];
    const float* Ws0 = (const float*)d_in[2];
    const float* Wd0 = (const float*)d_in[3];
    const float* as0 = (const float*)d_in[4];
    const float* ad0 = (const float*)d_in[5];
    const float* b0  = (const float*)d_in[6];
    const float* Lw0 = (const float*)d_in[7];
    const float* Lb0 = (const float*)d_in[8];
    const float* Ws1 = (const float*)d_in[9];
    const float* Wd1 = (const float*)d_in[10];
    const float* as1 = (const float*)d_in[11];
    const float* ad1 = (const float*)d_in[12];
    const float* b1  = (const float*)d_in[13];
    const float* Lw1 = (const float*)d_in[14];
    const float* Lb1 = (const float*)d_in[15];
    const float* Wts = (const float*)d_in[16];
    const float* Wtd = (const float*)d_in[17];
    const float* ats = (const float*)d_in[18];
    const float* atd = (const float*)d_in[19];
    const float* bt  = (const float*)d_in[20];
    const int* pp_src = (const int*)d_in[21];
    const int* pp_dst = (const int*)d_in[21] + E_PP;
    const int* pf_src = (const int*)d_in[22];
    const int* pf_dst = (const int*)d_in[23];
    float* out = (float*)d_out;

    char* wsp = (char*)d_ws;
    size_t off = 0;
    auto alloc = [&](size_t bytes) -> char* {
        char* p = wsp + off;
        off += (bytes + 255) & ~(size_t)255;
        return p;
    };
    ushort_t* hsb  = (ushort_t*)alloc(sizeof(ushort_t) * N_PANO * HID);
    ushort_t* linb = (ushort_t*)alloc(sizeof(ushort_t) * N_PANO * HID);
    uint_t* hh     = (uint_t*)alloc(sizeof(uint_t) * N_PANO * 64);
    ushort_t* hstb = (ushort_t*)alloc(sizeof(ushort_t) * N_PANO * OUT_C);
    int2* tmp_e    = (int2*)alloc(sizeof(int2) * E_UNI);
    float* es   = (float*)alloc(sizeof(float) * N_PANO);
    float* ed   = (float*)alloc(sizeof(float) * N_PANO);
    float* wed0 = (float*)alloc(sizeof(float) * HID);
    float* wed1 = (float*)alloc(sizeof(float) * HID);
    float* wedt = (float*)alloc(sizeof(float) * OUT_C);
    ushort_t* s0 = (ushort_t*)alloc(sizeof(ushort_t) * 128 * 128);
    ushort_t* l0 = (ushort_t*)alloc(sizeof(ushort_t) * 128 * 128);
    ushort_t* s1 = (ushort_t*)alloc(sizeof(ushort_t) * 128 * 128);
    ushort_t* l1 = (ushort_t*)alloc(sizeof(ushort_t) * 128 * 128);
    ushort_t* ts = (ushort_t*)alloc(sizeof(ushort_t) * 64 * 128);
    int* pcnt  = (int*)alloc(sizeof(int) * NBKT * NT_CNT);
    int* bbase = (int*)alloc(sizeof(int) * (NBKT + 1));
    int* P     = (int*)alloc(sizeof(int) * (N_UNI + 1));
    int* col_u = (int*)alloc(sizeof(int) * E_UNI);

    // L1: per-tile bucket counts + weight fragment-permute + wed matvecs
    csr_count_prep<<<NT_CNT + 288 + 80, 256, 0, stream>>>(
        pp_dst, pf_dst, pcnt, Ws0, Lw0, Ws1, Lw1, Wts,
        Wd0, ad0, Wd1, ad1, Wtd, atd, s0, l0, s1, l1, ts, wed0, wed1, wedt);

    // L2: coarse scatter (inline 2D prefix) || layer-0 dual GEMM
    scatter_gemm0<<<NT_CNT + NT_GEMM, 256, 0, stream>>>(
        pp_src, pp_dst, pf_src, pf_dst, pcnt, bbase, tmp_e,
        x_pano, s0, l0, hsb, linb, as0, es, wed0, ed);

    // L3: per-bucket counting sort -> P, col
    csr_sort<<<NBKT, 256, 0, stream>>>(tmp_e, bbase, P, col_u);

    // L4: layer-0 aggregate
    agg_pano7<<<cdiv(N_PANO, 8), 256, 0, stream>>>(P, col_u, es, ed, hsb, linb, b0, Lb0, hh, N_PANO);

    // L5: layer-1 dual GEMM (bf16 input = hh)
    gemm_mfma<128, true, false><<<NT_GEMM, 256, 0, stream>>>(
        nullptr, (const ushort_t*)hh, s1, l1, hsb, linb, as1, es, wed1, ed, N_PANO);

    // L6: layer-1 aggregate
    agg_pano7<<<cdiv(N_PANO, 8), 256, 0, stream>>>(P, col_u, es, ed, hsb, linb, b1, Lb1, hh, N_PANO);

    // L7: translate GEMM (C=64)
    gemm_mfma<64, false, false><<<NT_GEMM, 256, 0, stream>>>(
        nullptr, (const ushort_t*)hh, ts, nullptr, hstb, nullptr, ats, es, nullptr, nullptr, N_PANO);

    // L8: translate aggregate (pf ptr = P+50000, absolute into col_u)
    agg_fp5<<<cdiv(N_FP, 4), 256, 0, stream>>>(P + N_PANO, col_u, es, x_fp, wedt, hstb, bt, out, N_FP);
}